// Round 5
// baseline (1414.887 us; speedup 1.0000x reference)
//
#include <hip/hip_runtime.h>
#include <math.h>

#define NN 100000
#define EE 1600000
#define IND 128
#define D64 64    // HEADS*OUT_DIM

#define NBUCK 98      // ceil(NN / 1024)
#define BSHIFT 10     // bucket = dst >> 10 (1024 nodes per bucket)
#define P1_TILE 1536
#define P1_CAP 40
#define P2_PARTS 4    // pass-2 blocks per bucket
#define P2_NODES 256  // nodes owned per pass-2 block

// ---------------------------------------------------------------------------
// Kernel 1: fused Q/K/V projection (register-tiled LDS GEMM).
// W staged TRANSPOSED: wst[col][k] stride 34 -> wv via ds_read_b64, bank-free.
// Epilogue writes Q[node][64] and interleaved KV[node][128] = (k,v) pairs.
// ---------------------------------------------------------------------------
#define XS_STRIDE 36
#define KS 34

__global__ __launch_bounds__(256, 4) void qkv_kernel(
    const float* __restrict__ x,
    const float* __restrict__ Wq, const float* __restrict__ bq,
    const float* __restrict__ Wk, const float* __restrict__ bk,
    const float* __restrict__ Wv, const float* __restrict__ bv,
    float* __restrict__ Qo, float* __restrict__ KVo)
{
    __shared__ float xs[64 * XS_STRIDE];   // 9216 B
    __shared__ float wst[192 * KS];        // 26112 B

    const int t    = threadIdx.x;
    const int tidn = t & 31;
    const int tidm = t >> 5;
    const int nb   = blockIdx.x * 64;

    float acc[6][8];
#pragma unroll
    for (int j = 0; j < 6; ++j)
#pragma unroll
        for (int n = 0; n < 8; ++n) acc[j][n] = 0.f;

    const float* const Wm[3] = { Wq, Wk, Wv };

    for (int kt = 0; kt < 4; ++kt) {
        // stage x tile: 64 nodes x 32 k
#pragma unroll
        for (int i = 0; i < 2; ++i) {
            int idx  = i * 256 + t;
            int node = idx >> 3, k4 = idx & 7;
            float4 v = make_float4(0.f, 0.f, 0.f, 0.f);
            if (nb + node < NN)
                v = *(const float4*)&x[(size_t)(nb + node) * IND + kt * 32 + k4 * 4];
            *(float4*)&xs[node * XS_STRIDE + k4 * 4] = v;
        }
        // stage W transposed: wst[col][k]
#pragma unroll
        for (int m = 0; m < 3; ++m) {
#pragma unroll
            for (int i = 0; i < 2; ++i) {
                int idx = i * 256 + t;
                int k = idx >> 4, c4 = idx & 15;
                float4 w = *(const float4*)&Wm[m][(size_t)(kt * 32 + k) * D64 + c4 * 4];
                int col = m * 64 + c4 * 4;
                wst[(col + 0) * KS + k] = w.x;
                wst[(col + 1) * KS + k] = w.y;
                wst[(col + 2) * KS + k] = w.z;
                wst[(col + 3) * KS + k] = w.w;
            }
        }
        __syncthreads();

#pragma unroll
        for (int k4 = 0; k4 < 8; ++k4) {
            float4 xv[8];
#pragma unroll
            for (int n = 0; n < 8; ++n)
                xv[n] = *(const float4*)&xs[(tidm * 8 + n) * XS_STRIDE + k4 * 4];
            float2 wv[6];
#pragma unroll
            for (int j = 0; j < 6; ++j)
                wv[j] = *(const float2*)&wst[(j * 32 + tidn) * KS + k4 * 4];
#pragma unroll
            for (int j = 0; j < 6; ++j)
#pragma unroll
                for (int n = 0; n < 8; ++n)
                    acc[j][n] = fmaf(xv[n].x, wv[j].x, acc[j][n]);
#pragma unroll
            for (int j = 0; j < 6; ++j)
#pragma unroll
                for (int n = 0; n < 8; ++n)
                    acc[j][n] = fmaf(xv[n].y, wv[j].y, acc[j][n]);
#pragma unroll
            for (int j = 0; j < 6; ++j)
                wv[j] = *(const float2*)&wst[(j * 32 + tidn) * KS + k4 * 4 + 2];
#pragma unroll
            for (int j = 0; j < 6; ++j)
#pragma unroll
                for (int n = 0; n < 8; ++n)
                    acc[j][n] = fmaf(xv[n].z, wv[j].x, acc[j][n]);
#pragma unroll
            for (int j = 0; j < 6; ++j)
#pragma unroll
                for (int n = 0; n < 8; ++n)
                    acc[j][n] = fmaf(xv[n].w, wv[j].y, acc[j][n]);
        }
        __syncthreads();
    }

    // epilogue: Q separate, K/V interleaved as float2
    const float bq0 = bq[tidn],      bq1 = bq[32 + tidn];
    const float bk0 = bk[tidn],      bk1 = bk[32 + tidn];
    const float bv0 = bv[tidn],      bv1 = bv[32 + tidn];
#pragma unroll
    for (int n = 0; n < 8; ++n) {
        int node = nb + tidm * 8 + n;
        if (node >= NN) continue;
        size_t qb = (size_t)node * D64;
        Qo[qb + tidn]      = acc[0][n] + bq0;
        Qo[qb + 32 + tidn] = acc[1][n] + bq1;
        float2* kvp = (float2*)&KVo[(size_t)node * 128];
        kvp[tidn]      = make_float2(acc[2][n] + bk0, acc[4][n] + bv0);
        kvp[32 + tidn] = make_float2(acc[3][n] + bk1, acc[5][n] + bv1);
    }
}

// ---------------------------------------------------------------------------
// Degree count by destination node.
// ---------------------------------------------------------------------------
__global__ __launch_bounds__(256) void count_kernel(const int* __restrict__ ei,
                                                    int* __restrict__ deg)
{
    int e = blockIdx.x * blockDim.x + threadIdx.x;
    if (e < EE) atomicAdd(&deg[ei[EE + e]], 1);
}

// ---------------------------------------------------------------------------
// Exclusive prefix-sum over deg -> off[0..NN]; 3-kernel scan.
// ---------------------------------------------------------------------------
__global__ __launch_bounds__(256) void scanA_kernel(const int* __restrict__ deg,
                                                    int* __restrict__ bsums)
{
    int base = blockIdx.x * 1024 + threadIdx.x * 4;
    int s = 0;
#pragma unroll
    for (int j = 0; j < 4; ++j) {
        int i = base + j;
        s += (i < NN) ? deg[i] : 0;
    }
    for (int o = 32; o > 0; o >>= 1) s += __shfl_xor(s, o);
    __shared__ int ws[4];
    if ((threadIdx.x & 63) == 0) ws[threadIdx.x >> 6] = s;
    __syncthreads();
    if (threadIdx.x == 0) bsums[blockIdx.x] = ws[0] + ws[1] + ws[2] + ws[3];
}

__global__ __launch_bounds__(128) void scanB_kernel(int* __restrict__ bsums, int nb)
{
    __shared__ int sh[128];
    int t = threadIdx.x;
    int v = (t < nb) ? bsums[t] : 0;
    sh[t] = v;
    __syncthreads();
    for (int o = 1; o < 128; o <<= 1) {
        int add = (t >= o) ? sh[t - o] : 0;
        __syncthreads();
        sh[t] += add;
        __syncthreads();
    }
    if (t < nb) bsums[t] = sh[t] - v;   // exclusive
}

__global__ __launch_bounds__(256) void scanC_kernel(const int* __restrict__ deg,
                                                    const int* __restrict__ bsums,
                                                    int* __restrict__ off)
{
    int t = threadIdx.x;
    int base = blockIdx.x * 1024 + t * 4;
    int L[4]; int s = 0;
#pragma unroll
    for (int j = 0; j < 4; ++j) {
        int i = base + j;
        L[j] = (i < NN) ? deg[i] : 0;
        s += L[j];
    }
    int lane = t & 63, w = t >> 6;
    int incl = s;
    for (int o = 1; o < 64; o <<= 1) {
        int v = __shfl_up(incl, o);
        if (lane >= o) incl += v;
    }
    __shared__ int wsum[4];
    if (lane == 63) wsum[w] = incl;
    __syncthreads();
    int wbase = 0;
#pragma unroll
    for (int i = 0; i < 4; ++i) if (i < w) wbase += wsum[i];
    int run = bsums[blockIdx.x] + wbase + incl - s;
#pragma unroll
    for (int j = 0; j < 4; ++j) {
        int i = base + j;
        if (i <= NN) off[i] = run;
        run += L[j];
    }
}

// ---------------------------------------------------------------------------
// Init per-bucket staging cursors: gcur[b] = off[b<<BSHIFT].
// ---------------------------------------------------------------------------
__global__ void initg_kernel(const int* __restrict__ off, int* __restrict__ gcur)
{
    int b = threadIdx.x;
    if (b < NBUCK) gcur[b] = off[b << BSHIFT];
}

// ---------------------------------------------------------------------------
// Pass 1: bucket edges by dst>>10 via LDS staging; flush contiguous chunks
// (dense, full-line writes). Record = { src | dstlocal<<17, attr }.
// ---------------------------------------------------------------------------
__global__ __launch_bounds__(256) void p1_kernel(const int* __restrict__ ei,
                                                 const float* __restrict__ ea,
                                                 int* __restrict__ gcur,
                                                 int2* __restrict__ staging)
{
    __shared__ int  lcnt[NBUCK];
    __shared__ int2 lbuf[NBUCK][P1_CAP];

    const int t = threadIdx.x;
    for (int b = t; b < NBUCK; b += 256) lcnt[b] = 0;
    __syncthreads();

    const int e0 = blockIdx.x * P1_TILE;
#pragma unroll
    for (int j = 0; j < 6; ++j) {
        int e = e0 + j * 256 + t;
        if (e < EE) {
            int s = ei[e];
            int d = ei[EE + e];
            int b = d >> BSHIFT;
            int2 rec = make_int2(s | ((d & 1023) << 17), __float_as_int(ea[e]));
            int slot = atomicAdd(&lcnt[b], 1);
            if (slot < P1_CAP) lbuf[b][slot] = rec;
            else {                       // rare overflow: direct append
                int p = atomicAdd(&gcur[b], 1);
                staging[p] = rec;
            }
        }
    }
    __syncthreads();

    // flush: wave w drains buckets w, w+4, ...
    const int wave = t >> 6, lane = t & 63;
    for (int b = wave; b < NBUCK; b += 4) {
        int cnt = min(lcnt[b], P1_CAP);
        int base = 0;
        if (lane == 0 && cnt > 0) base = atomicAdd(&gcur[b], cnt);
        base = __shfl(base, 0);
        if (lane < cnt) staging[base + lane] = lbuf[b][lane];
    }
}

// ---------------------------------------------------------------------------
// Pass 2: 4 blocks per bucket; each owns 256 nodes EXCLUSIVELY. Scan the
// bucket's staging region, place matches via LDS cursors (no global atomics),
// write final CSR slots dense + exclusive.
// ---------------------------------------------------------------------------
__global__ __launch_bounds__(256) void p2_kernel(const int2* __restrict__ staging,
                                                 const int* __restrict__ off,
                                                 int2* __restrict__ epack)
{
    const int bucket = blockIdx.x >> 2;
    const int part   = blockIdx.x & 3;
    const int t      = threadIdx.x;
    const int n0     = (bucket << BSHIFT) + part * P2_NODES;

    __shared__ int lcur[P2_NODES];
    int node = n0 + t;
    lcur[t] = (node < NN) ? off[node] : 0;
    __syncthreads();

    const int sb = off[bucket << BSHIFT];
    const int se = off[min((bucket + 1) << BSHIFT, NN)];
    const int lo = part * P2_NODES;

    for (int r = sb + t; r < se; r += 256) {
        int2 rec = staging[r];
        int dl = (rec.x >> 17) & 1023;
        int ml = dl - lo;
        if ((unsigned)ml < P2_NODES) {
            int pos = atomicAdd(&lcur[ml], 1);
            epack[pos] = make_int2(rec.x & 0x1FFFF, rec.y);
        }
    }
}

// ---------------------------------------------------------------------------
// Attention: one wave per dst node; lane = h*8+d. Interleaved KV float2
// gather (one load per edge), batched-8 with predicated tail.
// ---------------------------------------------------------------------------
__global__ __launch_bounds__(256) void attn_kernel(
    const float* __restrict__ Q, const float2* __restrict__ KV,
    const int* __restrict__ off, const int2* __restrict__ epack,
    const float* __restrict__ We, const float* __restrict__ be,
    float* __restrict__ out)
{
    const int lane = threadIdx.x & 63;
    const int node = blockIdx.x * 4 + (threadIdx.x >> 6);
    if (node >= NN) return;

    const float we  = We[lane];
    const float beL = be[lane];
    const float q   = Q[node * D64 + lane] * 0.35355339059327373f;  // fold 1/sqrt(8)

    const int i0 = off[node];
    const int i1 = off[node + 1];

    float acc = 0.f, z = 0.f;

    for (int i = i0; i < i1; i += 8) {
        int2 e[8];
#pragma unroll
        for (int u = 0; u < 8; ++u) {
            int idx = i + u;
            e[u] = epack[idx < i1 ? idx : i0];
        }
        float2 kv[8];
#pragma unroll
        for (int u = 0; u < 8; ++u)
            kv[u] = KV[(size_t)e[u].x * D64 + lane];
        float tt[8];
#pragma unroll
        for (int u = 0; u < 8; ++u)
            tt[u] = kv[u].x * q * fmaf(__int_as_float(e[u].y), we, beL);
#pragma unroll
        for (int u = 0; u < 8; ++u) tt[u] += __shfl_xor(tt[u], 1);
#pragma unroll
        for (int u = 0; u < 8; ++u) tt[u] += __shfl_xor(tt[u], 2);
#pragma unroll
        for (int u = 0; u < 8; ++u) tt[u] += __shfl_xor(tt[u], 4);
#pragma unroll
        for (int u = 0; u < 8; ++u) {
            float tc = fminf(fmaxf(tt[u], -5.f), 5.f);
            float sc = __expf(tc);
            sc = (i + u < i1) ? sc : 0.f;
            acc = fmaf(kv[u].y, sc, acc);
            z  += sc;
        }
    }
    out[node * D64 + lane] = acc / (z + 1e-6f);
}

// ---------------------------------------------------------------------------
// Host launcher
// ---------------------------------------------------------------------------
static inline size_t align256(size_t v) { return (v + 255) & ~(size_t)255; }

extern "C" void kernel_launch(void* const* d_in, const int* in_sizes, int n_in,
                              void* d_out, int out_size, void* d_ws, size_t ws_size,
                              hipStream_t stream)
{
    const float* x  = (const float*)d_in[0];
    const float* ea = (const float*)d_in[1];
    const int*   ei = (const int*)  d_in[2];   // [2][EE]: row0=src, row1=dst
    const float* Wq = (const float*)d_in[3];
    const float* bq = (const float*)d_in[4];
    const float* Wk = (const float*)d_in[5];
    const float* bk = (const float*)d_in[6];
    const float* We = (const float*)d_in[7];
    const float* be = (const float*)d_in[8];
    const float* Wv = (const float*)d_in[9];
    const float* bv = (const float*)d_in[10];
    float* out = (float*)d_out;

    char* ws = (char*)d_ws;
    size_t o = 0;
    float* Q     = (float*)(ws + o); o += align256((size_t)NN * D64 * 4);
    float* KV    = (float*)(ws + o); o += align256((size_t)NN * 128 * 4);
    int*   deg   = (int*)  (ws + o); o += align256((size_t)NN * 4);
    int*   off   = (int*)  (ws + o); o += align256((size_t)(NN + 1) * 4);
    int*   bsums = (int*)  (ws + o); o += align256(128 * 4);
    int*   gcur  = (int*)  (ws + o); o += align256(128 * 4);
    int2*  epack = (int2*) (ws + o); o += align256((size_t)EE * 8);
    // staging aliases KV (12.8 MB <= 51.2 MB); qkv runs AFTER pass 2.
    int2*  staging = (int2*)KV;
    (void)ws_size; (void)out_size; (void)in_sizes; (void)n_in;

    const int nbScan = (NN + 1 + 1023) / 1024;   // 98

    (void)hipMemsetAsync(deg, 0, (size_t)NN * 4, stream);

    count_kernel<<<EE / 256, 256, 0, stream>>>(ei, deg);
    scanA_kernel<<<nbScan, 256, 0, stream>>>(deg, bsums);
    scanB_kernel<<<1, 128, 0, stream>>>(bsums, nbScan);
    scanC_kernel<<<nbScan, 256, 0, stream>>>(deg, bsums, off);
    initg_kernel<<<1, 128, 0, stream>>>(off, gcur);
    p1_kernel<<<(EE + P1_TILE - 1) / P1_TILE, 256, 0, stream>>>(ei, ea, gcur, staging);
    p2_kernel<<<NBUCK * P2_PARTS, 256, 0, stream>>>(staging, off, epack);
    qkv_kernel<<<(NN + 63) / 64, 256, 0, stream>>>(x, Wq, bq, Wk, bk, Wv, bv, Q, KV);
    attn_kernel<<<(NN + 3) / 4, 256, 0, stream>>>(Q, (const float2*)KV, off, epack, We, be, out);
}

// Round 6
// 601.200 us; speedup vs baseline: 2.3534x; 2.3534x over previous
//
#include <hip/hip_runtime.h>
#include <math.h>

#define NN 100000
#define EE 1600000
#define IND 128
#define D64 64    // HEADS*OUT_DIM

#define BSHIFT 8          // bucket = dst >> 8 (256 nodes per bucket)
#define NBUCK 391         // ceil(NN / 256)
#define P1_TILE 1536
#define NB_P1 1042        // ceil(EE / P1_TILE)

// ---------------------------------------------------------------------------
// Kernel 1: fused Q/K/V projection (register-tiled LDS GEMM).
// W staged TRANSPOSED: wst[col][k] stride 34 -> wv via ds_read_b64.
// Epilogue writes Q[node][64] and interleaved KV[node][128] = (k,v) pairs.
// ---------------------------------------------------------------------------
#define XS_STRIDE 36
#define KS 34

__global__ __launch_bounds__(256, 4) void qkv_kernel(
    const float* __restrict__ x,
    const float* __restrict__ Wq, const float* __restrict__ bq,
    const float* __restrict__ Wk, const float* __restrict__ bk,
    const float* __restrict__ Wv, const float* __restrict__ bv,
    float* __restrict__ Qo, float* __restrict__ KVo)
{
    __shared__ float xs[64 * XS_STRIDE];
    __shared__ float wst[192 * KS];

    const int t    = threadIdx.x;
    const int tidn = t & 31;
    const int tidm = t >> 5;
    const int nb   = blockIdx.x * 64;

    float acc[6][8];
#pragma unroll
    for (int j = 0; j < 6; ++j)
#pragma unroll
        for (int n = 0; n < 8; ++n) acc[j][n] = 0.f;

    const float* const Wm[3] = { Wq, Wk, Wv };

    for (int kt = 0; kt < 4; ++kt) {
#pragma unroll
        for (int i = 0; i < 2; ++i) {
            int idx  = i * 256 + t;
            int node = idx >> 3, k4 = idx & 7;
            float4 v = make_float4(0.f, 0.f, 0.f, 0.f);
            if (nb + node < NN)
                v = *(const float4*)&x[(size_t)(nb + node) * IND + kt * 32 + k4 * 4];
            *(float4*)&xs[node * XS_STRIDE + k4 * 4] = v;
        }
#pragma unroll
        for (int m = 0; m < 3; ++m) {
#pragma unroll
            for (int i = 0; i < 2; ++i) {
                int idx = i * 256 + t;
                int k = idx >> 4, c4 = idx & 15;
                float4 w = *(const float4*)&Wm[m][(size_t)(kt * 32 + k) * D64 + c4 * 4];
                int col = m * 64 + c4 * 4;
                wst[(col + 0) * KS + k] = w.x;
                wst[(col + 1) * KS + k] = w.y;
                wst[(col + 2) * KS + k] = w.z;
                wst[(col + 3) * KS + k] = w.w;
            }
        }
        __syncthreads();

#pragma unroll
        for (int k4 = 0; k4 < 8; ++k4) {
            float4 xv[8];
#pragma unroll
            for (int n = 0; n < 8; ++n)
                xv[n] = *(const float4*)&xs[(tidm * 8 + n) * XS_STRIDE + k4 * 4];
            float2 wv[6];
#pragma unroll
            for (int j = 0; j < 6; ++j)
                wv[j] = *(const float2*)&wst[(j * 32 + tidn) * KS + k4 * 4];
#pragma unroll
            for (int j = 0; j < 6; ++j)
#pragma unroll
                for (int n = 0; n < 8; ++n)
                    acc[j][n] = fmaf(xv[n].x, wv[j].x, acc[j][n]);
#pragma unroll
            for (int j = 0; j < 6; ++j)
#pragma unroll
                for (int n = 0; n < 8; ++n)
                    acc[j][n] = fmaf(xv[n].y, wv[j].y, acc[j][n]);
#pragma unroll
            for (int j = 0; j < 6; ++j)
                wv[j] = *(const float2*)&wst[(j * 32 + tidn) * KS + k4 * 4 + 2];
#pragma unroll
            for (int j = 0; j < 6; ++j)
#pragma unroll
                for (int n = 0; n < 8; ++n)
                    acc[j][n] = fmaf(xv[n].z, wv[j].x, acc[j][n]);
#pragma unroll
            for (int j = 0; j < 6; ++j)
#pragma unroll
                for (int n = 0; n < 8; ++n)
                    acc[j][n] = fmaf(xv[n].w, wv[j].y, acc[j][n]);
        }
        __syncthreads();
    }

    const float bq0 = bq[tidn], bq1 = bq[32 + tidn];
    const float bk0 = bk[tidn], bk1 = bk[32 + tidn];
    const float bv0 = bv[tidn], bv1 = bv[32 + tidn];
#pragma unroll
    for (int n = 0; n < 8; ++n) {
        int node = nb + tidm * 8 + n;
        if (node >= NN) continue;
        size_t qb = (size_t)node * D64;
        Qo[qb + tidn]      = acc[0][n] + bq0;
        Qo[qb + 32 + tidn] = acc[1][n] + bq1;
        float2* kvp = (float2*)&KVo[(size_t)node * 128];
        kvp[tidn]      = make_float2(acc[2][n] + bk0, acc[4][n] + bv0);
        kvp[32 + tidn] = make_float2(acc[3][n] + bk1, acc[5][n] + bv1);
    }
}

// ---------------------------------------------------------------------------
// p1a: per-block bucket histogram (LDS, no-return atomics) + deg count.
// hist layout: hist[block][bucket] (row-contiguous per block).
// ---------------------------------------------------------------------------
__global__ __launch_bounds__(256) void p1a_kernel(const int* __restrict__ ei,
                                                  int* __restrict__ deg,
                                                  int* __restrict__ hist)
{
    __shared__ int lh[NBUCK];
    const int t = threadIdx.x;
    for (int b = t; b < NBUCK; b += 256) lh[b] = 0;
    __syncthreads();

    const int e0 = blockIdx.x * P1_TILE;
#pragma unroll
    for (int j = 0; j < 6; ++j) {
        int e = e0 + j * 256 + t;
        if (e < EE) {
            int d = ei[EE + e];
            atomicAdd(&lh[d >> BSHIFT], 1);   // LDS, no return
            atomicAdd(&deg[d], 1);            // global, fan-in ~16
        }
    }
    __syncthreads();
    for (int b = t; b < NBUCK; b += 256)
        hist[blockIdx.x * NBUCK + b] = lh[b];
}

// ---------------------------------------------------------------------------
// Exclusive prefix-sum over deg -> off[0..NN]; 3-kernel scan.
// ---------------------------------------------------------------------------
__global__ __launch_bounds__(256) void scanA_kernel(const int* __restrict__ deg,
                                                    int* __restrict__ bsums)
{
    int base = blockIdx.x * 1024 + threadIdx.x * 4;
    int s = 0;
#pragma unroll
    for (int j = 0; j < 4; ++j) {
        int i = base + j;
        s += (i < NN) ? deg[i] : 0;
    }
    for (int o = 32; o > 0; o >>= 1) s += __shfl_xor(s, o);
    __shared__ int ws[4];
    if ((threadIdx.x & 63) == 0) ws[threadIdx.x >> 6] = s;
    __syncthreads();
    if (threadIdx.x == 0) bsums[blockIdx.x] = ws[0] + ws[1] + ws[2] + ws[3];
}

__global__ __launch_bounds__(128) void scanB_kernel(int* __restrict__ bsums, int nb)
{
    __shared__ int sh[128];
    int t = threadIdx.x;
    int v = (t < nb) ? bsums[t] : 0;
    sh[t] = v;
    __syncthreads();
    for (int o = 1; o < 128; o <<= 1) {
        int add = (t >= o) ? sh[t - o] : 0;
        __syncthreads();
        sh[t] += add;
        __syncthreads();
    }
    if (t < nb) bsums[t] = sh[t] - v;   // exclusive
}

__global__ __launch_bounds__(256) void scanC_kernel(const int* __restrict__ deg,
                                                    const int* __restrict__ bsums,
                                                    int* __restrict__ off)
{
    int t = threadIdx.x;
    int base = blockIdx.x * 1024 + t * 4;
    int L[4]; int s = 0;
#pragma unroll
    for (int j = 0; j < 4; ++j) {
        int i = base + j;
        L[j] = (i < NN) ? deg[i] : 0;
        s += L[j];
    }
    int lane = t & 63, w = t >> 6;
    int incl = s;
    for (int o = 1; o < 64; o <<= 1) {
        int v = __shfl_up(incl, o);
        if (lane >= o) incl += v;
    }
    __shared__ int wsum[4];
    if (lane == 63) wsum[w] = incl;
    __syncthreads();
    int wbase = 0;
#pragma unroll
    for (int i = 0; i < 4; ++i) if (i < w) wbase += wsum[i];
    int run = bsums[blockIdx.x] + wbase + incl - s;
#pragma unroll
    for (int j = 0; j < 4; ++j) {
        int i = base + j;
        if (i <= NN) off[i] = run;
        run += L[j];
    }
}

// ---------------------------------------------------------------------------
// hscan: block b = bucket b. Exclusive scan of hist[0..NB_P1-1][b] down the
// block dimension, seeded with off[b<<BSHIFT] -> per-(block,bucket) cursors.
// ---------------------------------------------------------------------------
__global__ __launch_bounds__(256) void hscan_kernel(int* __restrict__ hist,
                                                    const int* __restrict__ off)
{
    const int b = blockIdx.x;
    const int t = threadIdx.x;
    int L[5]; int s = 0;
#pragma unroll
    for (int j = 0; j < 5; ++j) {
        int blk = t * 5 + j;
        L[j] = (blk < NB_P1) ? hist[blk * NBUCK + b] : 0;
        s += L[j];
    }
    int lane = t & 63, w = t >> 6;
    int incl = s;
    for (int o = 1; o < 64; o <<= 1) {
        int v = __shfl_up(incl, o);
        if (lane >= o) incl += v;
    }
    __shared__ int wsum[4];
    if (lane == 63) wsum[w] = incl;
    __syncthreads();
    int wbase = 0;
#pragma unroll
    for (int i = 0; i < 4; ++i) if (i < w) wbase += wsum[i];
    int run = off[b << BSHIFT] + wbase + incl - s;
#pragma unroll
    for (int j = 0; j < 5; ++j) {
        int blk = t * 5 + j;
        if (blk < NB_P1) hist[blk * NBUCK + b] = run;
        run += L[j];
    }
}

// ---------------------------------------------------------------------------
// p1b: re-read edge tile, LDS-atomic rank within (block,bucket), write
// staging record at exact cursor. Zero global atomics.
// Record = { src | dstlocal<<17, attr }.
// ---------------------------------------------------------------------------
__global__ __launch_bounds__(256) void p1b_kernel(const int* __restrict__ ei,
                                                  const float* __restrict__ ea,
                                                  const int* __restrict__ hist,
                                                  int2* __restrict__ staging)
{
    __shared__ int lr[NBUCK];
    const int t = threadIdx.x;
    for (int b = t; b < NBUCK; b += 256)
        lr[b] = hist[blockIdx.x * NBUCK + b];
    __syncthreads();

    const int e0 = blockIdx.x * P1_TILE;
#pragma unroll
    for (int j = 0; j < 6; ++j) {
        int e = e0 + j * 256 + t;
        if (e < EE) {
            int s = ei[e];
            int d = ei[EE + e];
            int pos = atomicAdd(&lr[d >> BSHIFT], 1);
            staging[pos] = make_int2(s | ((d & 255) << 17), __float_as_int(ea[e]));
        }
    }
}

// ---------------------------------------------------------------------------
// p2: one block per bucket (256 nodes). LDS cursors; reads bucket staging
// once; writes exclusive CSR slice. Zero global atomics.
// ---------------------------------------------------------------------------
__global__ __launch_bounds__(256) void p2_kernel(const int2* __restrict__ staging,
                                                 const int* __restrict__ off,
                                                 int2* __restrict__ epack)
{
    const int bucket = blockIdx.x;
    const int t      = threadIdx.x;
    const int n0     = bucket << BSHIFT;

    __shared__ int lcur[256];
    int node = n0 + t;
    lcur[t] = (node < NN) ? off[node] : 0;
    __syncthreads();

    const int sb = off[n0];
    const int se = off[min(n0 + 256, NN)];

    for (int r = sb + t; r < se; r += 256) {
        int2 rec = staging[r];
        int dl = (rec.x >> 17) & 255;
        int pos = atomicAdd(&lcur[dl], 1);
        epack[pos] = make_int2(rec.x & 0x1FFFF, rec.y);
    }
}

// ---------------------------------------------------------------------------
// Attention: one wave per dst node; lane = h*8+d. Interleaved KV float2
// gather (one load per edge), batched-8 with predicated tail.
// ---------------------------------------------------------------------------
__global__ __launch_bounds__(256) void attn_kernel(
    const float* __restrict__ Q, const float2* __restrict__ KV,
    const int* __restrict__ off, const int2* __restrict__ epack,
    const float* __restrict__ We, const float* __restrict__ be,
    float* __restrict__ out)
{
    const int lane = threadIdx.x & 63;
    const int node = blockIdx.x * 4 + (threadIdx.x >> 6);
    if (node >= NN) return;

    const float we  = We[lane];
    const float beL = be[lane];
    const float q   = Q[node * D64 + lane] * 0.35355339059327373f;  // fold 1/sqrt(8)

    const int i0 = off[node];
    const int i1 = off[node + 1];

    float acc = 0.f, z = 0.f;

    for (int i = i0; i < i1; i += 8) {
        int2 e[8];
#pragma unroll
        for (int u = 0; u < 8; ++u) {
            int idx = i + u;
            e[u] = epack[idx < i1 ? idx : i0];
        }
        float2 kv[8];
#pragma unroll
        for (int u = 0; u < 8; ++u)
            kv[u] = KV[(size_t)e[u].x * D64 + lane];
        float tt[8];
#pragma unroll
        for (int u = 0; u < 8; ++u)
            tt[u] = kv[u].x * q * fmaf(__int_as_float(e[u].y), we, beL);
#pragma unroll
        for (int u = 0; u < 8; ++u) tt[u] += __shfl_xor(tt[u], 1);
#pragma unroll
        for (int u = 0; u < 8; ++u) tt[u] += __shfl_xor(tt[u], 2);
#pragma unroll
        for (int u = 0; u < 8; ++u) tt[u] += __shfl_xor(tt[u], 4);
#pragma unroll
        for (int u = 0; u < 8; ++u) {
            float tc = fminf(fmaxf(tt[u], -5.f), 5.f);
            float sc = __expf(tc);
            sc = (i + u < i1) ? sc : 0.f;
            acc = fmaf(kv[u].y, sc, acc);
            z  += sc;
        }
    }
    out[node * D64 + lane] = acc / (z + 1e-6f);
}

// ---------------------------------------------------------------------------
// Host launcher
// ---------------------------------------------------------------------------
static inline size_t align256(size_t v) { return (v + 255) & ~(size_t)255; }

extern "C" void kernel_launch(void* const* d_in, const int* in_sizes, int n_in,
                              void* d_out, int out_size, void* d_ws, size_t ws_size,
                              hipStream_t stream)
{
    const float* x  = (const float*)d_in[0];
    const float* ea = (const float*)d_in[1];
    const int*   ei = (const int*)  d_in[2];   // [2][EE]: row0=src, row1=dst
    const float* Wq = (const float*)d_in[3];
    const float* bq = (const float*)d_in[4];
    const float* Wk = (const float*)d_in[5];
    const float* bk = (const float*)d_in[6];
    const float* We = (const float*)d_in[7];
    const float* be = (const float*)d_in[8];
    const float* Wv = (const float*)d_in[9];
    const float* bv = (const float*)d_in[10];
    float* out = (float*)d_out;

    char* ws = (char*)d_ws;
    size_t o = 0;
    float* Q     = (float*)(ws + o); o += align256((size_t)NN * D64 * 4);
    float* KV    = (float*)(ws + o); o += align256((size_t)NN * 128 * 4);
    int*   deg   = (int*)  (ws + o); o += align256((size_t)NN * 4);
    int*   off   = (int*)  (ws + o); o += align256((size_t)(NN + 1) * 4);
    int*   bsums = (int*)  (ws + o); o += align256(128 * 4);
    int*   hist  = (int*)  (ws + o); o += align256((size_t)NB_P1 * NBUCK * 4);
    int2*  epack = (int2*) (ws + o); o += align256((size_t)EE * 8);
    // staging aliases KV (12.8 MB <= 51.2 MB); qkv runs AFTER p2.
    int2*  staging = (int2*)KV;
    (void)ws_size; (void)out_size; (void)in_sizes; (void)n_in;

    const int nbScan = (NN + 1 + 1023) / 1024;   // 98

    (void)hipMemsetAsync(deg, 0, (size_t)NN * 4, stream);

    p1a_kernel<<<NB_P1, 256, 0, stream>>>(ei, deg, hist);
    scanA_kernel<<<nbScan, 256, 0, stream>>>(deg, bsums);
    scanB_kernel<<<1, 128, 0, stream>>>(bsums, nbScan);
    scanC_kernel<<<nbScan, 256, 0, stream>>>(deg, bsums, off);
    hscan_kernel<<<NBUCK, 256, 0, stream>>>(hist, off);
    p1b_kernel<<<NB_P1, 256, 0, stream>>>(ei, ea, hist, staging);
    p2_kernel<<<NBUCK, 256, 0, stream>>>(staging, off, epack);
    qkv_kernel<<<(NN + 63) / 64, 256, 0, stream>>>(x, Wq, bq, Wk, bk, Wv, bv, Q, KV);
    attn_kernel<<<(NN + 3) / 4, 256, 0, stream>>>(Q, (const float2*)KV, off, epack, We, be, out);
}

// Round 7
// 342.813 us; speedup vs baseline: 4.1273x; 1.7537x over previous
//
#include <hip/hip_runtime.h>
#include <math.h>

#define NN 100000
#define EE 1600000
#define IND 128
#define D64 64    // HEADS*OUT_DIM

#define BSHIFT 8          // bucket = dst >> 8 (256 nodes per bucket)
#define NBUCK 391         // ceil(NN / 256)
#define P1_TILE 1536
#define NB_P1 1042        // ceil(EE / P1_TILE)

// ---------------------------------------------------------------------------
// Kernel 1: fused Q/K/V projection (round-3 proven version, 125us clean).
// C[100000 x 192] = x[100000 x 128] @ [Wq|Wk|Wv][128 x 192]
// Block: 256 threads, BM=64, BN=192, BK=32; thread tile 8 nodes x 6 cols.
// ---------------------------------------------------------------------------
#define XS_STRIDE 36
#define WS_STRIDE 196

__global__ __launch_bounds__(256) void qkv_kernel(
    const float* __restrict__ x,
    const float* __restrict__ Wq, const float* __restrict__ bq,
    const float* __restrict__ Wk, const float* __restrict__ bk,
    const float* __restrict__ Wv, const float* __restrict__ bv,
    float* __restrict__ Qo, float* __restrict__ Ko, float* __restrict__ Vo)
{
    __shared__ float xs[64 * XS_STRIDE];   // [node][k]
    __shared__ float ws[32 * WS_STRIDE];   // [k][col]

    const int t    = threadIdx.x;
    const int tidn = t & 31;
    const int tidm = t >> 5;
    const int nb   = blockIdx.x * 64;

    float acc[6][8];
#pragma unroll
    for (int j = 0; j < 6; ++j)
#pragma unroll
        for (int n = 0; n < 8; ++n) acc[j][n] = 0.f;

    const float* const Wm[3] = { Wq, Wk, Wv };

    for (int kt = 0; kt < 4; ++kt) {
#pragma unroll
        for (int i = 0; i < 2; ++i) {
            int idx  = i * 256 + t;
            int node = idx >> 3, k4 = idx & 7;
            float4 v = make_float4(0.f, 0.f, 0.f, 0.f);
            if (nb + node < NN)
                v = *(const float4*)&x[(size_t)(nb + node) * IND + kt * 32 + k4 * 4];
            *(float4*)&xs[node * XS_STRIDE + k4 * 4] = v;
        }
#pragma unroll
        for (int m = 0; m < 3; ++m) {
#pragma unroll
            for (int i = 0; i < 2; ++i) {
                int idx = i * 256 + t;
                int k = idx >> 4, c4 = idx & 15;
                float4 v = *(const float4*)&Wm[m][(size_t)(kt * 32 + k) * D64 + c4 * 4];
                *(float4*)&ws[k * WS_STRIDE + m * 64 + c4 * 4] = v;
            }
        }
        __syncthreads();

#pragma unroll
        for (int k4 = 0; k4 < 8; ++k4) {
            float4 xv[8];
#pragma unroll
            for (int n = 0; n < 8; ++n)
                xv[n] = *(const float4*)&xs[(tidm * 8 + n) * XS_STRIDE + k4 * 4];
#pragma unroll
            for (int kk = 0; kk < 4; ++kk) {
                float wv[6];
#pragma unroll
                for (int j = 0; j < 6; ++j)
                    wv[j] = ws[(k4 * 4 + kk) * WS_STRIDE + j * 32 + tidn];
#pragma unroll
                for (int j = 0; j < 6; ++j) {
#pragma unroll
                    for (int n = 0; n < 8; ++n) {
                        float xe = (kk == 0) ? xv[n].x : (kk == 1) ? xv[n].y
                                 : (kk == 2) ? xv[n].z : xv[n].w;
                        acc[j][n] = fmaf(xe, wv[j], acc[j][n]);
                    }
                }
            }
        }
        __syncthreads();
    }

#pragma unroll
    for (int j = 0; j < 6; ++j) {
        int col = j * 32 + tidn;
        int m   = col >> 6, lc = col & 63;
        const float* bp = (m == 0) ? bq : (m == 1) ? bk : bv;
        float*       O  = (m == 0) ? Qo : (m == 1) ? Ko : Vo;
        float bias = bp[lc];
#pragma unroll
        for (int n = 0; n < 8; ++n) {
            int node = nb + tidm * 8 + n;
            if (node < NN)
                O[(size_t)node * D64 + lc] = acc[j][n] + bias;
        }
    }
}

// ---------------------------------------------------------------------------
// p1a: per-block bucket histogram (LDS atomics) + deg count.
// ---------------------------------------------------------------------------
__global__ __launch_bounds__(256) void p1a_kernel(const int* __restrict__ ei,
                                                  int* __restrict__ deg,
                                                  int* __restrict__ hist)
{
    __shared__ int lh[NBUCK];
    const int t = threadIdx.x;
    for (int b = t; b < NBUCK; b += 256) lh[b] = 0;
    __syncthreads();

    const int e0 = blockIdx.x * P1_TILE;
#pragma unroll
    for (int j = 0; j < 6; ++j) {
        int e = e0 + j * 256 + t;
        if (e < EE) {
            int d = ei[EE + e];
            atomicAdd(&lh[d >> BSHIFT], 1);
            atomicAdd(&deg[d], 1);
        }
    }
    __syncthreads();
    for (int b = t; b < NBUCK; b += 256)
        hist[blockIdx.x * NBUCK + b] = lh[b];
}

// ---------------------------------------------------------------------------
// Exclusive prefix-sum over deg -> off[0..NN]; 3-kernel scan.
// ---------------------------------------------------------------------------
__global__ __launch_bounds__(256) void scanA_kernel(const int* __restrict__ deg,
                                                    int* __restrict__ bsums)
{
    int base = blockIdx.x * 1024 + threadIdx.x * 4;
    int s = 0;
#pragma unroll
    for (int j = 0; j < 4; ++j) {
        int i = base + j;
        s += (i < NN) ? deg[i] : 0;
    }
    for (int o = 32; o > 0; o >>= 1) s += __shfl_xor(s, o);
    __shared__ int ws[4];
    if ((threadIdx.x & 63) == 0) ws[threadIdx.x >> 6] = s;
    __syncthreads();
    if (threadIdx.x == 0) bsums[blockIdx.x] = ws[0] + ws[1] + ws[2] + ws[3];
}

__global__ __launch_bounds__(128) void scanB_kernel(int* __restrict__ bsums, int nb)
{
    __shared__ int sh[128];
    int t = threadIdx.x;
    int v = (t < nb) ? bsums[t] : 0;
    sh[t] = v;
    __syncthreads();
    for (int o = 1; o < 128; o <<= 1) {
        int add = (t >= o) ? sh[t - o] : 0;
        __syncthreads();
        sh[t] += add;
        __syncthreads();
    }
    if (t < nb) bsums[t] = sh[t] - v;   // exclusive
}

__global__ __launch_bounds__(256) void scanC_kernel(const int* __restrict__ deg,
                                                    const int* __restrict__ bsums,
                                                    int* __restrict__ off)
{
    int t = threadIdx.x;
    int base = blockIdx.x * 1024 + t * 4;
    int L[4]; int s = 0;
#pragma unroll
    for (int j = 0; j < 4; ++j) {
        int i = base + j;
        L[j] = (i < NN) ? deg[i] : 0;
        s += L[j];
    }
    int lane = t & 63, w = t >> 6;
    int incl = s;
    for (int o = 1; o < 64; o <<= 1) {
        int v = __shfl_up(incl, o);
        if (lane >= o) incl += v;
    }
    __shared__ int wsum[4];
    if (lane == 63) wsum[w] = incl;
    __syncthreads();
    int wbase = 0;
#pragma unroll
    for (int i = 0; i < 4; ++i) if (i < w) wbase += wsum[i];
    int run = bsums[blockIdx.x] + wbase + incl - s;
#pragma unroll
    for (int j = 0; j < 4; ++j) {
        int i = base + j;
        if (i <= NN) off[i] = run;
        run += L[j];
    }
}

// ---------------------------------------------------------------------------
// hscan: block b = bucket b; exclusive scan down the block dimension,
// seeded with off[b<<BSHIFT] -> per-(block,bucket) staging cursors.
// ---------------------------------------------------------------------------
__global__ __launch_bounds__(256) void hscan_kernel(int* __restrict__ hist,
                                                    const int* __restrict__ off)
{
    const int b = blockIdx.x;
    const int t = threadIdx.x;
    int L[5]; int s = 0;
#pragma unroll
    for (int j = 0; j < 5; ++j) {
        int blk = t * 5 + j;
        L[j] = (blk < NB_P1) ? hist[blk * NBUCK + b] : 0;
        s += L[j];
    }
    int lane = t & 63, w = t >> 6;
    int incl = s;
    for (int o = 1; o < 64; o <<= 1) {
        int v = __shfl_up(incl, o);
        if (lane >= o) incl += v;
    }
    __shared__ int wsum[4];
    if (lane == 63) wsum[w] = incl;
    __syncthreads();
    int wbase = 0;
#pragma unroll
    for (int i = 0; i < 4; ++i) if (i < w) wbase += wsum[i];
    int run = off[b << BSHIFT] + wbase + incl - s;
#pragma unroll
    for (int j = 0; j < 5; ++j) {
        int blk = t * 5 + j;
        if (blk < NB_P1) hist[blk * NBUCK + b] = run;
        run += L[j];
    }
}

// ---------------------------------------------------------------------------
// p1b: re-read edge tile, LDS-atomic rank within (block,bucket), write
// staging record at exact cursor. Zero global atomics.
// Record = { src | dstlocal<<17, attr }.
// ---------------------------------------------------------------------------
__global__ __launch_bounds__(256) void p1b_kernel(const int* __restrict__ ei,
                                                  const float* __restrict__ ea,
                                                  const int* __restrict__ hist,
                                                  int2* __restrict__ staging)
{
    __shared__ int lr[NBUCK];
    const int t = threadIdx.x;
    for (int b = t; b < NBUCK; b += 256)
        lr[b] = hist[blockIdx.x * NBUCK + b];
    __syncthreads();

    const int e0 = blockIdx.x * P1_TILE;
#pragma unroll
    for (int j = 0; j < 6; ++j) {
        int e = e0 + j * 256 + t;
        if (e < EE) {
            int s = ei[e];
            int d = ei[EE + e];
            int pos = atomicAdd(&lr[d >> BSHIFT], 1);
            staging[pos] = make_int2(s | ((d & 255) << 17), __float_as_int(ea[e]));
        }
    }
}

// ---------------------------------------------------------------------------
// p2: one block per bucket (256 nodes). LDS cursors; reads bucket staging
// once; writes exclusive CSR slice. Zero global atomics.
// ---------------------------------------------------------------------------
__global__ __launch_bounds__(256) void p2_kernel(const int2* __restrict__ staging,
                                                 const int* __restrict__ off,
                                                 int2* __restrict__ epack)
{
    const int bucket = blockIdx.x;
    const int t      = threadIdx.x;
    const int n0     = bucket << BSHIFT;

    __shared__ int lcur[256];
    int node = n0 + t;
    lcur[t] = (node < NN) ? off[node] : 0;
    __syncthreads();

    const int sb = off[n0];
    const int se = off[min(n0 + 256, NN)];

    for (int r = sb + t; r < se; r += 256) {
        int2 rec = staging[r];
        int dl = (rec.x >> 17) & 255;
        int pos = atomicAdd(&lcur[dl], 1);
        epack[pos] = make_int2(rec.x & 0x1FFFF, rec.y);
    }
}

// ---------------------------------------------------------------------------
// Attention: one wave per dst node; lane = h*8+d. Separate K/V gathers,
// batched-8 with predicated tail (16 loads in flight per step).
// ---------------------------------------------------------------------------
__global__ __launch_bounds__(256) void attn_kernel(
    const float* __restrict__ Q, const float* __restrict__ K,
    const float* __restrict__ V,
    const int* __restrict__ off, const int2* __restrict__ epack,
    const float* __restrict__ We, const float* __restrict__ be,
    float* __restrict__ out)
{
    const int lane = threadIdx.x & 63;
    const int node = blockIdx.x * 4 + (threadIdx.x >> 6);
    if (node >= NN) return;

    const float we  = We[lane];
    const float beL = be[lane];
    const float q   = Q[node * D64 + lane] * 0.35355339059327373f;  // fold 1/sqrt(8)

    const int i0 = off[node];
    const int i1 = off[node + 1];

    float acc = 0.f, z = 0.f;

    for (int i = i0; i < i1; i += 8) {
        int2 e[8];
#pragma unroll
        for (int u = 0; u < 8; ++u) {
            int idx = i + u;
            e[u] = epack[idx < i1 ? idx : i0];
        }
        float kk[8], vv[8];
#pragma unroll
        for (int u = 0; u < 8; ++u) {
            size_t b = (size_t)e[u].x * D64 + lane;
            kk[u] = K[b];
            vv[u] = V[b];
        }
        float tt[8];
#pragma unroll
        for (int u = 0; u < 8; ++u)
            tt[u] = kk[u] * q * fmaf(__int_as_float(e[u].y), we, beL);
#pragma unroll
        for (int u = 0; u < 8; ++u) tt[u] += __shfl_xor(tt[u], 1);
#pragma unroll
        for (int u = 0; u < 8; ++u) tt[u] += __shfl_xor(tt[u], 2);
#pragma unroll
        for (int u = 0; u < 8; ++u) tt[u] += __shfl_xor(tt[u], 4);
#pragma unroll
        for (int u = 0; u < 8; ++u) {
            float tc = fminf(fmaxf(tt[u], -5.f), 5.f);
            float sc = __expf(tc);
            sc = (i + u < i1) ? sc : 0.f;
            acc = fmaf(vv[u], sc, acc);
            z  += sc;
        }
    }
    out[node * D64 + lane] = acc / (z + 1e-6f);
}

// ---------------------------------------------------------------------------
// Host launcher
// ---------------------------------------------------------------------------
static inline size_t align256(size_t v) { return (v + 255) & ~(size_t)255; }

extern "C" void kernel_launch(void* const* d_in, const int* in_sizes, int n_in,
                              void* d_out, int out_size, void* d_ws, size_t ws_size,
                              hipStream_t stream)
{
    const float* x  = (const float*)d_in[0];
    const float* ea = (const float*)d_in[1];
    const int*   ei = (const int*)  d_in[2];   // [2][EE]: row0=src, row1=dst
    const float* Wq = (const float*)d_in[3];
    const float* bq = (const float*)d_in[4];
    const float* Wk = (const float*)d_in[5];
    const float* bk = (const float*)d_in[6];
    const float* We = (const float*)d_in[7];
    const float* be = (const float*)d_in[8];
    const float* Wv = (const float*)d_in[9];
    const float* bv = (const float*)d_in[10];
    float* out = (float*)d_out;

    char* ws = (char*)d_ws;
    size_t o = 0;
    float* Q       = (float*)(ws + o); o += align256((size_t)NN * D64 * 4);
    float* K       = (float*)(ws + o); o += align256((size_t)NN * D64 * 4);
    float* V       = (float*)(ws + o); o += align256((size_t)NN * D64 * 4);
    int*   deg     = (int*)  (ws + o); o += align256((size_t)NN * 4);
    int*   off     = (int*)  (ws + o); o += align256((size_t)(NN + 1) * 4);
    int*   bsums   = (int*)  (ws + o); o += align256(128 * 4);
    int*   hist    = (int*)  (ws + o); o += align256((size_t)NB_P1 * NBUCK * 4);
    int2*  staging = (int2*) (ws + o); o += align256((size_t)EE * 8);
    int2*  epack   = (int2*) (ws + o); o += align256((size_t)EE * 8);
    (void)ws_size; (void)out_size; (void)in_sizes; (void)n_in;

    const int nbScan = (NN + 1 + 1023) / 1024;   // 98

    (void)hipMemsetAsync(deg, 0, (size_t)NN * 4, stream);

    qkv_kernel<<<(NN + 63) / 64, 256, 0, stream>>>(x, Wq, bq, Wk, bk, Wv, bv, Q, K, V);
    p1a_kernel<<<NB_P1, 256, 0, stream>>>(ei, deg, hist);
    scanA_kernel<<<nbScan, 256, 0, stream>>>(deg, bsums);
    scanB_kernel<<<1, 128, 0, stream>>>(bsums, nbScan);
    scanC_kernel<<<nbScan, 256, 0, stream>>>(deg, bsums, off);
    hscan_kernel<<<NBUCK, 256, 0, stream>>>(hist, off);
    p1b_kernel<<<NB_P1, 256, 0, stream>>>(ei, ea, hist, staging);
    p2_kernel<<<NBUCK, 256, 0, stream>>>(staging, off, epack);
    attn_kernel<<<(NN + 3) / 4, 256, 0, stream>>>(Q, K, V, off, epack, We, be, out);
}

// Round 8
// 301.993 us; speedup vs baseline: 4.6852x; 1.1352x over previous
//
#include <hip/hip_runtime.h>
#include <math.h>

#define NN 100000
#define EE 1600000
#define IND 128
#define D64 64    // HEADS*OUT_DIM

#define BSHIFT 8          // bucket = dst >> 8 (256 nodes per bucket)
#define NBUCK 391         // ceil(NN / 256)
#define P1_TILE 1536
#define NB_P1 1042        // ceil(EE / P1_TILE)

typedef __attribute__((ext_vector_type(8))) short  short8;
typedef __attribute__((ext_vector_type(4))) float  f32x4;

// ---------------------------------------------------------------------------
// wtrans: one-shot transpose+split of [Wq|Wk|Wv] (128x192 fp32) into
// wt_hi/wt_lo [col 0..191][k 0..127] bf16 (Markidis hi/lo split).
// ---------------------------------------------------------------------------
__device__ __forceinline__ unsigned short bf16_rne(float v) {
    unsigned int u = __float_as_uint(v);
    return (unsigned short)((u + 0x7FFFu + ((u >> 16) & 1u)) >> 16);
}

__global__ __launch_bounds__(256) void wtrans_kernel(
    const float* __restrict__ Wq, const float* __restrict__ Wk,
    const float* __restrict__ Wv,
    unsigned short* __restrict__ wt_hi, unsigned short* __restrict__ wt_lo)
{
    int idx = blockIdx.x * 256 + threadIdx.x;     // 0..24575
    if (idx >= 192 * 128) return;
    int col = idx >> 7, k = idx & 127;
    const float* W = (col < 64) ? Wq : (col < 128) ? Wk : Wv;
    float v = W[(size_t)k * D64 + (col & 63)];
    unsigned short h = bf16_rne(v);
    float hf = __uint_as_float((unsigned int)h << 16);
    unsigned short l = bf16_rne(v - hf);
    wt_hi[idx] = h;
    wt_lo[idx] = l;
}

// ---------------------------------------------------------------------------
// qkv: C[100000 x 192] = x @ [Wq|Wk|Wv] via bf16 MFMA, 2-term split:
// C = xh@Wh + xh@Wl + xl@Wh  (lo*lo dropped, ~2^-18 error).
// Block: 256 thr = 4 waves; BM=64 nodes; wave w owns cols [48w,48w+48).
// B-frags in registers (24 x short8); x staged hi/lo in LDS (1 barrier).
// mfma_f32_16x16x32_bf16: A row=lane&15,k=(lane>>4)*8+j; B col=lane&15;
// C/D col=lane&15, row=(lane>>4)*4+reg.
// ---------------------------------------------------------------------------
#define XP 132   // padded k-stride (ushort) for LDS x tiles

__global__ __launch_bounds__(256) void qkv_kernel(
    const float* __restrict__ x,
    const unsigned short* __restrict__ wt_hi,
    const unsigned short* __restrict__ wt_lo,
    const float* __restrict__ bq, const float* __restrict__ bk,
    const float* __restrict__ bv,
    float* __restrict__ Qo, float* __restrict__ Ko, float* __restrict__ Vo)
{
    __shared__ unsigned short xhi[64 * XP];   // 16.9 KB
    __shared__ unsigned short xlo[64 * XP];   // 16.9 KB

    const int t    = threadIdx.x;
    const int wave = t >> 6;
    const int lane = t & 63;
    const int nb   = blockIdx.x * 64;

    // ---- stage x tile 64x128 fp32 -> hi/lo bf16 in LDS ----
    {
        const int row = t >> 2;          // 0..63
        const int c   = t & 3;           // k-chunk of 32
        const bool rv = (nb + row) < NN;
        const float* xr = x + (size_t)(nb + row) * IND + c * 32;
#pragma unroll
        for (int i = 0; i < 4; ++i) {
            float4 a = rv ? *(const float4*)(xr + i * 8)     : make_float4(0.f,0.f,0.f,0.f);
            float4 b = rv ? *(const float4*)(xr + i * 8 + 4) : make_float4(0.f,0.f,0.f,0.f);
            float vs[8] = { a.x, a.y, a.z, a.w, b.x, b.y, b.z, b.w };
            short8 h, l;
#pragma unroll
            for (int j = 0; j < 8; ++j) {
                unsigned short hb = bf16_rne(vs[j]);
                float hf = __uint_as_float((unsigned int)hb << 16);
                h[j] = (short)hb;
                l[j] = (short)bf16_rne(vs[j] - hf);
            }
            int off = row * XP + c * 32 + i * 8;
            *(short8*)&xhi[off] = h;
            *(short8*)&xlo[off] = l;
        }
    }

    // ---- B fragments from global (L2-hot), held in registers ----
    const int wcol0 = wave * 48;
    short8 bh[3][4], bl[3][4];
#pragma unroll
    for (int ct = 0; ct < 3; ++ct) {
        int col = wcol0 + ct * 16 + (lane & 15);
#pragma unroll
        for (int kt = 0; kt < 4; ++kt) {
            int a = col * 128 + kt * 32 + (lane >> 4) * 8;
            bh[ct][kt] = *(const short8*)&wt_hi[a];
            bl[ct][kt] = *(const short8*)&wt_lo[a];
        }
    }

    f32x4 acc[4][3];
#pragma unroll
    for (int rt = 0; rt < 4; ++rt)
#pragma unroll
        for (int ct = 0; ct < 3; ++ct)
            acc[rt][ct] = (f32x4){0.f, 0.f, 0.f, 0.f};

    __syncthreads();

    // ---- MFMA main: rt pairs -> 6 independent acc chains ----
#pragma unroll
    for (int rtp = 0; rtp < 2; ++rtp) {
        short8 ah[2][4], al[2][4];
#pragma unroll
        for (int h = 0; h < 2; ++h) {
            int r = (rtp * 2 + h) * 16 + (lane & 15);
#pragma unroll
            for (int kt = 0; kt < 4; ++kt) {
                int off = r * XP + kt * 32 + (lane >> 4) * 8;
                ah[h][kt] = *(const short8*)&xhi[off];
                al[h][kt] = *(const short8*)&xlo[off];
            }
        }
#pragma unroll
        for (int kt = 0; kt < 4; ++kt) {
#pragma unroll
            for (int h = 0; h < 2; ++h) {
                int rt = rtp * 2 + h;
#pragma unroll
                for (int ct = 0; ct < 3; ++ct) {
                    acc[rt][ct] = __builtin_amdgcn_mfma_f32_16x16x32_bf16(
                        ah[h][kt], bh[ct][kt], acc[rt][ct], 0, 0, 0);
                    acc[rt][ct] = __builtin_amdgcn_mfma_f32_16x16x32_bf16(
                        ah[h][kt], bl[ct][kt], acc[rt][ct], 0, 0, 0);
                    acc[rt][ct] = __builtin_amdgcn_mfma_f32_16x16x32_bf16(
                        al[h][kt], bh[ct][kt], acc[rt][ct], 0, 0, 0);
                }
            }
        }
    }

    // ---- epilogue: bias + store (wave-uniform target matrix per ct) ----
#pragma unroll
    for (int ct = 0; ct < 3; ++ct) {
        int colbase = wcol0 + ct * 16;
        int m  = colbase >> 6;
        int lc = (colbase & 63) + (lane & 15);
        const float* bp = (m == 0) ? bq : (m == 1) ? bk : bv;
        float*       O  = (m == 0) ? Qo : (m == 1) ? Ko : Vo;
        float bias = bp[lc];
#pragma unroll
        for (int rt = 0; rt < 4; ++rt) {
#pragma unroll
            for (int reg = 0; reg < 4; ++reg) {
                int node = nb + rt * 16 + (lane >> 4) * 4 + reg;
                if (node < NN)
                    O[(size_t)node * D64 + lc] = acc[rt][ct][reg] + bias;
            }
        }
    }
}

// ---------------------------------------------------------------------------
// p1a: per-block bucket histogram (LDS atomics) + deg count.
// ---------------------------------------------------------------------------
__global__ __launch_bounds__(256) void p1a_kernel(const int* __restrict__ ei,
                                                  int* __restrict__ deg,
                                                  int* __restrict__ hist)
{
    __shared__ int lh[NBUCK];
    const int t = threadIdx.x;
    for (int b = t; b < NBUCK; b += 256) lh[b] = 0;
    __syncthreads();

    const int e0 = blockIdx.x * P1_TILE;
#pragma unroll
    for (int j = 0; j < 6; ++j) {
        int e = e0 + j * 256 + t;
        if (e < EE) {
            int d = ei[EE + e];
            atomicAdd(&lh[d >> BSHIFT], 1);
            atomicAdd(&deg[d], 1);
        }
    }
    __syncthreads();
    for (int b = t; b < NBUCK; b += 256)
        hist[blockIdx.x * NBUCK + b] = lh[b];
}

// ---------------------------------------------------------------------------
// Exclusive prefix-sum over deg -> off[0..NN]; 3-kernel scan.
// ---------------------------------------------------------------------------
__global__ __launch_bounds__(256) void scanA_kernel(const int* __restrict__ deg,
                                                    int* __restrict__ bsums)
{
    int base = blockIdx.x * 1024 + threadIdx.x * 4;
    int s = 0;
#pragma unroll
    for (int j = 0; j < 4; ++j) {
        int i = base + j;
        s += (i < NN) ? deg[i] : 0;
    }
    for (int o = 32; o > 0; o >>= 1) s += __shfl_xor(s, o);
    __shared__ int ws[4];
    if ((threadIdx.x & 63) == 0) ws[threadIdx.x >> 6] = s;
    __syncthreads();
    if (threadIdx.x == 0) bsums[blockIdx.x] = ws[0] + ws[1] + ws[2] + ws[3];
}

__global__ __launch_bounds__(128) void scanB_kernel(int* __restrict__ bsums, int nb)
{
    __shared__ int sh[128];
    int t = threadIdx.x;
    int v = (t < nb) ? bsums[t] : 0;
    sh[t] = v;
    __syncthreads();
    for (int o = 1; o < 128; o <<= 1) {
        int add = (t >= o) ? sh[t - o] : 0;
        __syncthreads();
        sh[t] += add;
        __syncthreads();
    }
    if (t < nb) bsums[t] = sh[t] - v;   // exclusive
}

__global__ __launch_bounds__(256) void scanC_kernel(const int* __restrict__ deg,
                                                    const int* __restrict__ bsums,
                                                    int* __restrict__ off)
{
    int t = threadIdx.x;
    int base = blockIdx.x * 1024 + t * 4;
    int L[4]; int s = 0;
#pragma unroll
    for (int j = 0; j < 4; ++j) {
        int i = base + j;
        L[j] = (i < NN) ? deg[i] : 0;
        s += L[j];
    }
    int lane = t & 63, w = t >> 6;
    int incl = s;
    for (int o = 1; o < 64; o <<= 1) {
        int v = __shfl_up(incl, o);
        if (lane >= o) incl += v;
    }
    __shared__ int wsum[4];
    if (lane == 63) wsum[w] = incl;
    __syncthreads();
    int wbase = 0;
#pragma unroll
    for (int i = 0; i < 4; ++i) if (i < w) wbase += wsum[i];
    int run = bsums[blockIdx.x] + wbase + incl - s;
#pragma unroll
    for (int j = 0; j < 4; ++j) {
        int i = base + j;
        if (i <= NN) off[i] = run;
        run += L[j];
    }
}

// ---------------------------------------------------------------------------
// hscan: block b = bucket b; exclusive scan down the block dimension,
// seeded with off[b<<BSHIFT] -> per-(block,bucket) staging cursors.
// ---------------------------------------------------------------------------
__global__ __launch_bounds__(256) void hscan_kernel(int* __restrict__ hist,
                                                    const int* __restrict__ off)
{
    const int b = blockIdx.x;
    const int t = threadIdx.x;
    int L[5]; int s = 0;
#pragma unroll
    for (int j = 0; j < 5; ++j) {
        int blk = t * 5 + j;
        L[j] = (blk < NB_P1) ? hist[blk * NBUCK + b] : 0;
        s += L[j];
    }
    int lane = t & 63, w = t >> 6;
    int incl = s;
    for (int o = 1; o < 64; o <<= 1) {
        int v = __shfl_up(incl, o);
        if (lane >= o) incl += v;
    }
    __shared__ int wsum[4];
    if (lane == 63) wsum[w] = incl;
    __syncthreads();
    int wbase = 0;
#pragma unroll
    for (int i = 0; i < 4; ++i) if (i < w) wbase += wsum[i];
    int run = off[b << BSHIFT] + wbase + incl - s;
#pragma unroll
    for (int j = 0; j < 5; ++j) {
        int blk = t * 5 + j;
        if (blk < NB_P1) hist[blk * NBUCK + b] = run;
        run += L[j];
    }
}

// ---------------------------------------------------------------------------
// p1b: re-read edge tile, LDS-atomic rank within (block,bucket), write
// staging record at exact cursor. Zero global atomics.
// Record = { src | dstlocal<<17, attr }.
// ---------------------------------------------------------------------------
__global__ __launch_bounds__(256) void p1b_kernel(const int* __restrict__ ei,
                                                  const float* __restrict__ ea,
                                                  const int* __restrict__ hist,
                                                  int2* __restrict__ staging)
{
    __shared__ int lr[NBUCK];
    const int t = threadIdx.x;
    for (int b = t; b < NBUCK; b += 256)
        lr[b] = hist[blockIdx.x * NBUCK + b];
    __syncthreads();

    const int e0 = blockIdx.x * P1_TILE;
#pragma unroll
    for (int j = 0; j < 6; ++j) {
        int e = e0 + j * 256 + t;
        if (e < EE) {
            int s = ei[e];
            int d = ei[EE + e];
            int pos = atomicAdd(&lr[d >> BSHIFT], 1);
            staging[pos] = make_int2(s | ((d & 255) << 17), __float_as_int(ea[e]));
        }
    }
}

// ---------------------------------------------------------------------------
// p2: one block per bucket (256 nodes). LDS cursors; reads bucket staging
// once; writes exclusive CSR slice. Zero global atomics.
// ---------------------------------------------------------------------------
__global__ __launch_bounds__(256) void p2_kernel(const int2* __restrict__ staging,
                                                 const int* __restrict__ off,
                                                 int2* __restrict__ epack)
{
    const int bucket = blockIdx.x;
    const int t      = threadIdx.x;
    const int n0     = bucket << BSHIFT;

    __shared__ int lcur[256];
    int node = n0 + t;
    lcur[t] = (node < NN) ? off[node] : 0;
    __syncthreads();

    const int sb = off[n0];
    const int se = off[min(n0 + 256, NN)];

    for (int r = sb + t; r < se; r += 256) {
        int2 rec = staging[r];
        int dl = (rec.x >> 17) & 255;
        int pos = atomicAdd(&lcur[dl], 1);
        epack[pos] = make_int2(rec.x & 0x1FFFF, rec.y);
    }
}

// ---------------------------------------------------------------------------
// Attention: one wave per dst node; lane = h*8+d. Separate K/V gathers,
// batched-8 with predicated tail (16 loads in flight per step).
// ---------------------------------------------------------------------------
__global__ __launch_bounds__(256) void attn_kernel(
    const float* __restrict__ Q, const float* __restrict__ K,
    const float* __restrict__ V,
    const int* __restrict__ off, const int2* __restrict__ epack,
    const float* __restrict__ We, const float* __restrict__ be,
    float* __restrict__ out)
{
    const int lane = threadIdx.x & 63;
    const int node = blockIdx.x * 4 + (threadIdx.x >> 6);
    if (node >= NN) return;

    const float we  = We[lane];
    const float beL = be[lane];
    const float q   = Q[node * D64 + lane] * 0.35355339059327373f;  // fold 1/sqrt(8)

    const int i0 = off[node];
    const int i1 = off[node + 1];

    float acc = 0.f, z = 0.f;

    for (int i = i0; i < i1; i += 8) {
        int2 e[8];
#pragma unroll
        for (int u = 0; u < 8; ++u) {
            int idx = i + u;
            e[u] = epack[idx < i1 ? idx : i0];
        }
        float kk[8], vv[8];
#pragma unroll
        for (int u = 0; u < 8; ++u) {
            size_t b = (size_t)e[u].x * D64 + lane;
            kk[u] = K[b];
            vv[u] = V[b];
        }
        float tt[8];
#pragma unroll
        for (int u = 0; u < 8; ++u)
            tt[u] = kk[u] * q * fmaf(__int_as_float(e[u].y), we, beL);
#pragma unroll
        for (int u = 0; u < 8; ++u) tt[u] += __shfl_xor(tt[u], 1);
#pragma unroll
        for (int u = 0; u < 8; ++u) tt[u] += __shfl_xor(tt[u], 2);
#pragma unroll
        for (int u = 0; u < 8; ++u) tt[u] += __shfl_xor(tt[u], 4);
#pragma unroll
        for (int u = 0; u < 8; ++u) {
            float tc = fminf(fmaxf(tt[u], -5.f), 5.f);
            float sc = __expf(tc);
            sc = (i + u < i1) ? sc : 0.f;
            acc = fmaf(vv[u], sc, acc);
            z  += sc;
        }
    }
    out[node * D64 + lane] = acc / (z + 1e-6f);
}

// ---------------------------------------------------------------------------
// Host launcher
// ---------------------------------------------------------------------------
static inline size_t align256(size_t v) { return (v + 255) & ~(size_t)255; }

extern "C" void kernel_launch(void* const* d_in, const int* in_sizes, int n_in,
                              void* d_out, int out_size, void* d_ws, size_t ws_size,
                              hipStream_t stream)
{
    const float* x  = (const float*)d_in[0];
    const float* ea = (const float*)d_in[1];
    const int*   ei = (const int*)  d_in[2];   // [2][EE]: row0=src, row1=dst
    const float* Wq = (const float*)d_in[3];
    const float* bq = (const float*)d_in[4];
    const float* Wk = (const float*)d_in[5];
    const float* bk = (const float*)d_in[6];
    const float* We = (const float*)d_in[7];
    const float* be = (const float*)d_in[8];
    const float* Wv = (const float*)d_in[9];
    const float* bv = (const float*)d_in[10];
    float* out = (float*)d_out;

    char* ws = (char*)d_ws;
    size_t o = 0;
    float*          Q       = (float*)(ws + o);          o += align256((size_t)NN * D64 * 4);
    float*          K       = (float*)(ws + o);          o += align256((size_t)NN * D64 * 4);
    float*          V       = (float*)(ws + o);          o += align256((size_t)NN * D64 * 4);
    int*            deg     = (int*)(ws + o);            o += align256((size_t)NN * 4);
    int*            off     = (int*)(ws + o);            o += align256((size_t)(NN + 1) * 4);
    int*            bsums   = (int*)(ws + o);            o += align256(128 * 4);
    unsigned short* wt_hi   = (unsigned short*)(ws + o); o += align256((size_t)192 * 128 * 2);
    unsigned short* wt_lo   = (unsigned short*)(ws + o); o += align256((size_t)192 * 128 * 2);
    int*            hist    = (int*)(ws + o);            o += align256((size_t)NB_P1 * NBUCK * 4);
    int2*           staging = (int2*)(ws + o);           o += align256((size_t)EE * 8);
    int2*           epack   = (int2*)(ws + o);           o += align256((size_t)EE * 8);
    (void)ws_size; (void)out_size; (void)in_sizes; (void)n_in;

    const int nbScan = (NN + 1 + 1023) / 1024;   // 98

    (void)hipMemsetAsync(deg, 0, (size_t)NN * 4, stream);

    wtrans_kernel<<<96, 256, 0, stream>>>(Wq, Wk, Wv, wt_hi, wt_lo);
    qkv_kernel<<<(NN + 63) / 64, 256, 0, stream>>>(x, wt_hi, wt_lo, bq, bk, bv, Q, K, V);
    p1a_kernel<<<NB_P1, 256, 0, stream>>>(ei, deg, hist);
    scanA_kernel<<<nbScan, 256, 0, stream>>>(deg, bsums);
    scanB_kernel<<<1, 128, 0, stream>>>(bsums, nbScan);
    scanC_kernel<<<nbScan, 256, 0, stream>>>(deg, bsums, off);
    hscan_kernel<<<NBUCK, 256, 0, stream>>>(hist, off);
    p1b_kernel<<<NB_P1, 256, 0, stream>>>(ei, ea, hist, staging);
    p2_kernel<<<NBUCK, 256, 0, stream>>>(staging, off, epack);
    attn_kernel<<<(NN + 3) / 4, 256, 0, stream>>>(Q, K, V, off, epack, We, be, out);
}

// Round 9
// 272.319 us; speedup vs baseline: 5.1957x; 1.1090x over previous
//
#include <hip/hip_runtime.h>
#include <math.h>

#define NN 100000
#define EE 1600000
#define IND 128
#define D64 64    // HEADS*OUT_DIM

#define BSHIFT 8          // bucket = dst >> 8 (256 nodes per bucket)
#define NBUCK 391         // ceil(NN / 256)
#define P1_TILE 1536
#define NB_P1 1042        // ceil(EE / P1_TILE)

typedef __attribute__((ext_vector_type(8))) short  short8;
typedef __attribute__((ext_vector_type(4))) float  f32x4;

// ---------------------------------------------------------------------------
// wtrans: one-shot transpose+split of [Wq|Wk|Wv] (128x192 fp32) into
// wt_hi/wt_lo [col 0..191][k 0..127] bf16 (Markidis hi/lo split).
// ---------------------------------------------------------------------------
__device__ __forceinline__ unsigned short bf16_rne(float v) {
    unsigned int u = __float_as_uint(v);
    return (unsigned short)((u + 0x7FFFu + ((u >> 16) & 1u)) >> 16);
}

__global__ __launch_bounds__(256) void wtrans_kernel(
    const float* __restrict__ Wq, const float* __restrict__ Wk,
    const float* __restrict__ Wv,
    unsigned short* __restrict__ wt_hi, unsigned short* __restrict__ wt_lo)
{
    int idx = blockIdx.x * 256 + threadIdx.x;     // 0..24575
    if (idx >= 192 * 128) return;
    int col = idx >> 7, k = idx & 127;
    const float* W = (col < 64) ? Wq : (col < 128) ? Wk : Wv;
    float v = W[(size_t)k * D64 + (col & 63)];
    unsigned short h = bf16_rne(v);
    float hf = __uint_as_float((unsigned int)h << 16);
    unsigned short l = bf16_rne(v - hf);
    wt_hi[idx] = h;
    wt_lo[idx] = l;
}

// ---------------------------------------------------------------------------
// qkv: C[100000 x 192] = x @ [Wq|Wk|Wv] via bf16 MFMA, 2-term split:
// C = xh@Wh + xh@Wl + xl@Wh  (lo*lo dropped).
// Q written fp32; K/V written PACKED bf16 into KVb: uint = (K<<16)|V.
// Block: 256 thr = 4 waves; BM=64 nodes; wave w owns cols [48w,48w+48).
// ---------------------------------------------------------------------------
#define XP 132   // padded k-stride (ushort) for LDS x tiles

__global__ __launch_bounds__(256) void qkv_kernel(
    const float* __restrict__ x,
    const unsigned short* __restrict__ wt_hi,
    const unsigned short* __restrict__ wt_lo,
    const float* __restrict__ bq, const float* __restrict__ bk,
    const float* __restrict__ bv,
    float* __restrict__ Qo, unsigned int* __restrict__ KVb)
{
    __shared__ unsigned short xhi[64 * XP];   // 16.9 KB
    __shared__ unsigned short xlo[64 * XP];   // 16.9 KB

    const int t    = threadIdx.x;
    const int wave = t >> 6;
    const int lane = t & 63;
    const int nb   = blockIdx.x * 64;

    // ---- stage x tile 64x128 fp32 -> hi/lo bf16 in LDS ----
    {
        const int row = t >> 2;          // 0..63
        const int c   = t & 3;           // k-chunk of 32
        const bool rv = (nb + row) < NN;
        const float* xr = x + (size_t)(nb + row) * IND + c * 32;
#pragma unroll
        for (int i = 0; i < 4; ++i) {
            float4 a = rv ? *(const float4*)(xr + i * 8)     : make_float4(0.f,0.f,0.f,0.f);
            float4 b = rv ? *(const float4*)(xr + i * 8 + 4) : make_float4(0.f,0.f,0.f,0.f);
            float vs[8] = { a.x, a.y, a.z, a.w, b.x, b.y, b.z, b.w };
            short8 h, l;
#pragma unroll
            for (int j = 0; j < 8; ++j) {
                unsigned short hb = bf16_rne(vs[j]);
                float hf = __uint_as_float((unsigned int)hb << 16);
                h[j] = (short)hb;
                l[j] = (short)bf16_rne(vs[j] - hf);
            }
            int off = row * XP + c * 32 + i * 8;
            *(short8*)&xhi[off] = h;
            *(short8*)&xlo[off] = l;
        }
    }

    // ---- B fragments from global (L2-hot), held in registers ----
    const int wcol0 = wave * 48;
    short8 bh[3][4], bl[3][4];
#pragma unroll
    for (int ct = 0; ct < 3; ++ct) {
        int col = wcol0 + ct * 16 + (lane & 15);
#pragma unroll
        for (int kt = 0; kt < 4; ++kt) {
            int a = col * 128 + kt * 32 + (lane >> 4) * 8;
            bh[ct][kt] = *(const short8*)&wt_hi[a];
            bl[ct][kt] = *(const short8*)&wt_lo[a];
        }
    }

    f32x4 acc[4][3];
#pragma unroll
    for (int rt = 0; rt < 4; ++rt)
#pragma unroll
        for (int ct = 0; ct < 3; ++ct)
            acc[rt][ct] = (f32x4){0.f, 0.f, 0.f, 0.f};

    __syncthreads();

    // ---- MFMA main: rt pairs -> 6 independent acc chains ----
#pragma unroll
    for (int rtp = 0; rtp < 2; ++rtp) {
        short8 ah[2][4], al[2][4];
#pragma unroll
        for (int h = 0; h < 2; ++h) {
            int r = (rtp * 2 + h) * 16 + (lane & 15);
#pragma unroll
            for (int kt = 0; kt < 4; ++kt) {
                int off = r * XP + kt * 32 + (lane >> 4) * 8;
                ah[h][kt] = *(const short8*)&xhi[off];
                al[h][kt] = *(const short8*)&xlo[off];
            }
        }
#pragma unroll
        for (int kt = 0; kt < 4; ++kt) {
#pragma unroll
            for (int h = 0; h < 2; ++h) {
                int rt = rtp * 2 + h;
#pragma unroll
                for (int ct = 0; ct < 3; ++ct) {
                    acc[rt][ct] = __builtin_amdgcn_mfma_f32_16x16x32_bf16(
                        ah[h][kt], bh[ct][kt], acc[rt][ct], 0, 0, 0);
                    acc[rt][ct] = __builtin_amdgcn_mfma_f32_16x16x32_bf16(
                        ah[h][kt], bl[ct][kt], acc[rt][ct], 0, 0, 0);
                    acc[rt][ct] = __builtin_amdgcn_mfma_f32_16x16x32_bf16(
                        al[h][kt], bh[ct][kt], acc[rt][ct], 0, 0, 0);
                }
            }
        }
    }

    // ---- epilogue: bias + store. Q fp32; K -> hi ushort, V -> lo ushort ----
#pragma unroll
    for (int ct = 0; ct < 3; ++ct) {
        int colbase = wcol0 + ct * 16;
        int m  = colbase >> 6;                 // wave-uniform: 0=Q,1=K,2=V
        int lc = (colbase & 63) + (lane & 15);
        const float* bp = (m == 0) ? bq : (m == 1) ? bk : bv;
        float bias = bp[lc];
#pragma unroll
        for (int rt = 0; rt < 4; ++rt) {
#pragma unroll
            for (int reg = 0; reg < 4; ++reg) {
                int node = nb + rt * 16 + (lane >> 4) * 4 + reg;
                if (node >= NN) continue;
                float val = acc[rt][ct][reg] + bias;
                size_t idx = (size_t)node * D64 + lc;
                if (m == 0) {
                    Qo[idx] = val;
                } else {
                    // little-endian: ushort[0]=lo(V), ushort[1]=hi(K)
                    ((unsigned short*)KVb)[idx * 2 + (m == 1 ? 1 : 0)] = bf16_rne(val);
                }
            }
        }
    }
}

// ---------------------------------------------------------------------------
// p1a: per-block bucket histogram (LDS atomics) + deg count.
// ---------------------------------------------------------------------------
__global__ __launch_bounds__(256) void p1a_kernel(const int* __restrict__ ei,
                                                  int* __restrict__ deg,
                                                  int* __restrict__ hist)
{
    __shared__ int lh[NBUCK];
    const int t = threadIdx.x;
    for (int b = t; b < NBUCK; b += 256) lh[b] = 0;
    __syncthreads();

    const int e0 = blockIdx.x * P1_TILE;
#pragma unroll
    for (int j = 0; j < 6; ++j) {
        int e = e0 + j * 256 + t;
        if (e < EE) {
            int d = ei[EE + e];
            atomicAdd(&lh[d >> BSHIFT], 1);
            atomicAdd(&deg[d], 1);
        }
    }
    __syncthreads();
    for (int b = t; b < NBUCK; b += 256)
        hist[blockIdx.x * NBUCK + b] = lh[b];
}

// ---------------------------------------------------------------------------
// Exclusive prefix-sum over deg -> off[0..NN]; 3-kernel scan.
// ---------------------------------------------------------------------------
__global__ __launch_bounds__(256) void scanA_kernel(const int* __restrict__ deg,
                                                    int* __restrict__ bsums)
{
    int base = blockIdx.x * 1024 + threadIdx.x * 4;
    int s = 0;
#pragma unroll
    for (int j = 0; j < 4; ++j) {
        int i = base + j;
        s += (i < NN) ? deg[i] : 0;
    }
    for (int o = 32; o > 0; o >>= 1) s += __shfl_xor(s, o);
    __shared__ int ws[4];
    if ((threadIdx.x & 63) == 0) ws[threadIdx.x >> 6] = s;
    __syncthreads();
    if (threadIdx.x == 0) bsums[blockIdx.x] = ws[0] + ws[1] + ws[2] + ws[3];
}

__global__ __launch_bounds__(128) void scanB_kernel(int* __restrict__ bsums, int nb)
{
    __shared__ int sh[128];
    int t = threadIdx.x;
    int v = (t < nb) ? bsums[t] : 0;
    sh[t] = v;
    __syncthreads();
    for (int o = 1; o < 128; o <<= 1) {
        int add = (t >= o) ? sh[t - o] : 0;
        __syncthreads();
        sh[t] += add;
        __syncthreads();
    }
    if (t < nb) bsums[t] = sh[t] - v;   // exclusive
}

__global__ __launch_bounds__(256) void scanC_kernel(const int* __restrict__ deg,
                                                    const int* __restrict__ bsums,
                                                    int* __restrict__ off)
{
    int t = threadIdx.x;
    int base = blockIdx.x * 1024 + t * 4;
    int L[4]; int s = 0;
#pragma unroll
    for (int j = 0; j < 4; ++j) {
        int i = base + j;
        L[j] = (i < NN) ? deg[i] : 0;
        s += L[j];
    }
    int lane = t & 63, w = t >> 6;
    int incl = s;
    for (int o = 1; o < 64; o <<= 1) {
        int v = __shfl_up(incl, o);
        if (lane >= o) incl += v;
    }
    __shared__ int wsum[4];
    if (lane == 63) wsum[w] = incl;
    __syncthreads();
    int wbase = 0;
#pragma unroll
    for (int i = 0; i < 4; ++i) if (i < w) wbase += wsum[i];
    int run = bsums[blockIdx.x] + wbase + incl - s;
#pragma unroll
    for (int j = 0; j < 4; ++j) {
        int i = base + j;
        if (i <= NN) off[i] = run;
        run += L[j];
    }
}

// ---------------------------------------------------------------------------
// hscan: block b = bucket b; exclusive scan down the block dimension,
// seeded with off[b<<BSHIFT] -> per-(block,bucket) staging cursors.
// ---------------------------------------------------------------------------
__global__ __launch_bounds__(256) void hscan_kernel(int* __restrict__ hist,
                                                    const int* __restrict__ off)
{
    const int b = blockIdx.x;
    const int t = threadIdx.x;
    int L[5]; int s = 0;
#pragma unroll
    for (int j = 0; j < 5; ++j) {
        int blk = t * 5 + j;
        L[j] = (blk < NB_P1) ? hist[blk * NBUCK + b] : 0;
        s += L[j];
    }
    int lane = t & 63, w = t >> 6;
    int incl = s;
    for (int o = 1; o < 64; o <<= 1) {
        int v = __shfl_up(incl, o);
        if (lane >= o) incl += v;
    }
    __shared__ int wsum[4];
    if (lane == 63) wsum[w] = incl;
    __syncthreads();
    int wbase = 0;
#pragma unroll
    for (int i = 0; i < 4; ++i) if (i < w) wbase += wsum[i];
    int run = off[b << BSHIFT] + wbase + incl - s;
#pragma unroll
    for (int j = 0; j < 5; ++j) {
        int blk = t * 5 + j;
        if (blk < NB_P1) hist[blk * NBUCK + b] = run;
        run += L[j];
    }
}

// ---------------------------------------------------------------------------
// p1b: re-read edge tile, LDS-atomic rank within (block,bucket), write
// staging record at exact cursor. Zero global atomics.
// Record = { src | dstlocal<<17, attr }.
// ---------------------------------------------------------------------------
__global__ __launch_bounds__(256) void p1b_kernel(const int* __restrict__ ei,
                                                  const float* __restrict__ ea,
                                                  const int* __restrict__ hist,
                                                  int2* __restrict__ staging)
{
    __shared__ int lr[NBUCK];
    const int t = threadIdx.x;
    for (int b = t; b < NBUCK; b += 256)
        lr[b] = hist[blockIdx.x * NBUCK + b];
    __syncthreads();

    const int e0 = blockIdx.x * P1_TILE;
#pragma unroll
    for (int j = 0; j < 6; ++j) {
        int e = e0 + j * 256 + t;
        if (e < EE) {
            int s = ei[e];
            int d = ei[EE + e];
            int pos = atomicAdd(&lr[d >> BSHIFT], 1);
            staging[pos] = make_int2(s | ((d & 255) << 17), __float_as_int(ea[e]));
        }
    }
}

// ---------------------------------------------------------------------------
// p2: one block per bucket (256 nodes). LDS cursors; reads bucket staging
// once; writes exclusive CSR slice. Zero global atomics.
// ---------------------------------------------------------------------------
__global__ __launch_bounds__(256) void p2_kernel(const int2* __restrict__ staging,
                                                 const int* __restrict__ off,
                                                 int2* __restrict__ epack)
{
    const int bucket = blockIdx.x;
    const int t      = threadIdx.x;
    const int n0     = bucket << BSHIFT;

    __shared__ int lcur[256];
    int node = n0 + t;
    lcur[t] = (node < NN) ? off[node] : 0;
    __syncthreads();

    const int sb = off[n0];
    const int se = off[min(n0 + 256, NN)];

    for (int r = sb + t; r < se; r += 256) {
        int2 rec = staging[r];
        int dl = (rec.x >> 17) & 255;
        int pos = atomicAdd(&lcur[dl], 1);
        epack[pos] = make_int2(rec.x & 0x1FFFF, rec.y);
    }
}

// ---------------------------------------------------------------------------
// Attention: one wave per dst node; lane = h*8+d. ONE packed-bf16 KV load
// per edge per lane (k = hi16, v = lo16), batched-8 with predicated tail.
// ---------------------------------------------------------------------------
__global__ __launch_bounds__(256) void attn_kernel(
    const float* __restrict__ Q, const unsigned int* __restrict__ KVb,
    const int* __restrict__ off, const int2* __restrict__ epack,
    const float* __restrict__ We, const float* __restrict__ be,
    float* __restrict__ out)
{
    const int lane = threadIdx.x & 63;
    const int node = blockIdx.x * 4 + (threadIdx.x >> 6);
    if (node >= NN) return;

    const float we  = We[lane];
    const float beL = be[lane];
    const float q   = Q[node * D64 + lane] * 0.35355339059327373f;  // fold 1/sqrt(8)

    const int i0 = off[node];
    const int i1 = off[node + 1];

    float acc = 0.f, z = 0.f;

    for (int i = i0; i < i1; i += 8) {
        int2 e[8];
#pragma unroll
        for (int u = 0; u < 8; ++u) {
            int idx = i + u;
            e[u] = epack[idx < i1 ? idx : i0];
        }
        unsigned int w[8];
#pragma unroll
        for (int u = 0; u < 8; ++u)
            w[u] = KVb[(size_t)e[u].x * D64 + lane];
        float tt[8];
#pragma unroll
        for (int u = 0; u < 8; ++u) {
            float kf = __uint_as_float(w[u] & 0xFFFF0000u);
            tt[u] = kf * q * fmaf(__int_as_float(e[u].y), we, beL);
        }
#pragma unroll
        for (int u = 0; u < 8; ++u) tt[u] += __shfl_xor(tt[u], 1);
#pragma unroll
        for (int u = 0; u < 8; ++u) tt[u] += __shfl_xor(tt[u], 2);
#pragma unroll
        for (int u = 0; u < 8; ++u) tt[u] += __shfl_xor(tt[u], 4);
#pragma unroll
        for (int u = 0; u < 8; ++u) {
            float tc = fminf(fmaxf(tt[u], -5.f), 5.f);
            float sc = __expf(tc);
            sc = (i + u < i1) ? sc : 0.f;
            float vf = __uint_as_float(w[u] << 16);
            acc = fmaf(vf, sc, acc);
            z  += sc;
        }
    }
    out[node * D64 + lane] = acc / (z + 1e-6f);
}

// ---------------------------------------------------------------------------
// Host launcher
// ---------------------------------------------------------------------------
static inline size_t align256(size_t v) { return (v + 255) & ~(size_t)255; }

extern "C" void kernel_launch(void* const* d_in, const int* in_sizes, int n_in,
                              void* d_out, int out_size, void* d_ws, size_t ws_size,
                              hipStream_t stream)
{
    const float* x  = (const float*)d_in[0];
    const float* ea = (const float*)d_in[1];
    const int*   ei = (const int*)  d_in[2];   // [2][EE]: row0=src, row1=dst
    const float* Wq = (const float*)d_in[3];
    const float* bq = (const float*)d_in[4];
    const float* Wk = (const float*)d_in[5];
    const float* bk = (const float*)d_in[6];
    const float* We = (const float*)d_in[7];
    const float* be = (const float*)d_in[8];
    const float* Wv = (const float*)d_in[9];
    const float* bv = (const float*)d_in[10];
    float* out = (float*)d_out;

    char* ws = (char*)d_ws;
    size_t o = 0;
    float*          Q       = (float*)(ws + o);          o += align256((size_t)NN * D64 * 4);
    unsigned int*   KVb     = (unsigned int*)(ws + o);   o += align256((size_t)NN * D64 * 4);
    int*            deg     = (int*)(ws + o);            o += align256((size_t)NN * 4);
    int*            off     = (int*)(ws + o);            o += align256((size_t)(NN + 1) * 4);
    int*            bsums   = (int*)(ws + o);            o += align256(128 * 4);
    unsigned short* wt_hi   = (unsigned short*)(ws + o); o += align256((size_t)192 * 128 * 2);
    unsigned short* wt_lo   = (unsigned short*)(ws + o); o += align256((size_t)192 * 128 * 2);
    int*            hist    = (int*)(ws + o);            o += align256((size_t)NB_P1 * NBUCK * 4);
    int2*           staging = (int2*)(ws + o);           o += align256((size_t)EE * 8);
    int2*           epack   = (int2*)(ws + o);           o += align256((size_t)EE * 8);
    (void)ws_size; (void)out_size; (void)in_sizes; (void)n_in;

    const int nbScan = (NN + 1 + 1023) / 1024;   // 98

    (void)hipMemsetAsync(deg, 0, (size_t)NN * 4, stream);

    wtrans_kernel<<<96, 256, 0, stream>>>(Wq, Wk, Wv, wt_hi, wt_lo);
    qkv_kernel<<<(NN + 63) / 64, 256, 0, stream>>>(x, wt_hi, wt_lo, bq, bk, bv, Q, KVb);
    p1a_kernel<<<NB_P1, 256, 0, stream>>>(ei, deg, hist);
    scanA_kernel<<<nbScan, 256, 0, stream>>>(deg, bsums);
    scanB_kernel<<<1, 128, 0, stream>>>(bsums, nbScan);
    scanC_kernel<<<nbScan, 256, 0, stream>>>(deg, bsums, off);
    hscan_kernel<<<NBUCK, 256, 0, stream>>>(hist, off);
    p1b_kernel<<<NB_P1, 256, 0, stream>>>(ei, ea, hist, staging);
    p2_kernel<<<NBUCK, 256, 0, stream>>>(staging, off, epack);
    attn_kernel<<<(NN + 3) / 4, 256, 0, stream>>>(Q, KVb, off, epack, We, be, out);
}

// Round 10
// 252.306 us; speedup vs baseline: 5.6078x; 1.0793x over previous
//
#include <hip/hip_runtime.h>
#include <math.h>

#define NN 100000
#define EE 1600000
#define IND 128
#define D64 64    // HEADS*OUT_DIM

#define BSHIFT 8          // bucket = dst >> 8 (256 nodes per bucket)
#define NBUCK 391         // ceil(NN / 256)
#define P1_TILE 1536
#define NB_P1 1042        // ceil(EE / P1_TILE)

typedef __attribute__((ext_vector_type(8))) short  short8;
typedef __attribute__((ext_vector_type(4))) float  f32x4;

// ---------------------------------------------------------------------------
// wtrans: one-shot transpose+split of [Wq|Wk|Wv] (128x192 fp32) into
// wt_hi/wt_lo [col 0..191][k 0..127] bf16 (Markidis hi/lo split).
// ---------------------------------------------------------------------------
__device__ __forceinline__ unsigned short bf16_rne(float v) {
    unsigned int u = __float_as_uint(v);
    return (unsigned short)((u + 0x7FFFu + ((u >> 16) & 1u)) >> 16);
}

__global__ __launch_bounds__(256) void wtrans_kernel(
    const float* __restrict__ Wq, const float* __restrict__ Wk,
    const float* __restrict__ Wv,
    unsigned short* __restrict__ wt_hi, unsigned short* __restrict__ wt_lo)
{
    int idx = blockIdx.x * 256 + threadIdx.x;     // 0..24575
    if (idx >= 192 * 128) return;
    int col = idx >> 7, k = idx & 127;
    const float* W = (col < 64) ? Wq : (col < 128) ? Wk : Wv;
    float v = W[(size_t)k * D64 + (col & 63)];
    unsigned short h = bf16_rne(v);
    float hf = __uint_as_float((unsigned int)h << 16);
    unsigned short l = bf16_rne(v - hf);
    wt_hi[idx] = h;
    wt_lo[idx] = l;
}

// ---------------------------------------------------------------------------
// qkv: C[100000 x 192] = x @ [Wq|Wk|Wv] via bf16 MFMA, 2-term split:
// C = xh@Wh + xh@Wl + xl@Wh  (lo*lo dropped).
// Q written fp32; K/V written PACKED bf16 into KVb: uint = (K<<16)|V.
// Block: 256 thr = 4 waves; BM=64 nodes; wave w owns cols [48w,48w+48).
// ---------------------------------------------------------------------------
#define XP 132   // padded k-stride (ushort) for LDS x tiles

__global__ __launch_bounds__(256) void qkv_kernel(
    const float* __restrict__ x,
    const unsigned short* __restrict__ wt_hi,
    const unsigned short* __restrict__ wt_lo,
    const float* __restrict__ bq, const float* __restrict__ bk,
    const float* __restrict__ bv,
    float* __restrict__ Qo, unsigned int* __restrict__ KVb)
{
    __shared__ unsigned short xhi[64 * XP];   // 16.9 KB
    __shared__ unsigned short xlo[64 * XP];   // 16.9 KB

    const int t    = threadIdx.x;
    const int wave = t >> 6;
    const int lane = t & 63;
    const int nb   = blockIdx.x * 64;

    // ---- stage x tile 64x128 fp32 -> hi/lo bf16 in LDS ----
    {
        const int row = t >> 2;          // 0..63
        const int c   = t & 3;           // k-chunk of 32
        const bool rv = (nb + row) < NN;
        const float* xr = x + (size_t)(nb + row) * IND + c * 32;
#pragma unroll
        for (int i = 0; i < 4; ++i) {
            float4 a = rv ? *(const float4*)(xr + i * 8)     : make_float4(0.f,0.f,0.f,0.f);
            float4 b = rv ? *(const float4*)(xr + i * 8 + 4) : make_float4(0.f,0.f,0.f,0.f);
            float vs[8] = { a.x, a.y, a.z, a.w, b.x, b.y, b.z, b.w };
            short8 h, l;
#pragma unroll
            for (int j = 0; j < 8; ++j) {
                unsigned short hb = bf16_rne(vs[j]);
                float hf = __uint_as_float((unsigned int)hb << 16);
                h[j] = (short)hb;
                l[j] = (short)bf16_rne(vs[j] - hf);
            }
            int off = row * XP + c * 32 + i * 8;
            *(short8*)&xhi[off] = h;
            *(short8*)&xlo[off] = l;
        }
    }

    // ---- B fragments from global (L2-hot), held in registers ----
    const int wcol0 = wave * 48;
    short8 bh[3][4], bl[3][4];
#pragma unroll
    for (int ct = 0; ct < 3; ++ct) {
        int col = wcol0 + ct * 16 + (lane & 15);
#pragma unroll
        for (int kt = 0; kt < 4; ++kt) {
            int a = col * 128 + kt * 32 + (lane >> 4) * 8;
            bh[ct][kt] = *(const short8*)&wt_hi[a];
            bl[ct][kt] = *(const short8*)&wt_lo[a];
        }
    }

    f32x4 acc[4][3];
#pragma unroll
    for (int rt = 0; rt < 4; ++rt)
#pragma unroll
        for (int ct = 0; ct < 3; ++ct)
            acc[rt][ct] = (f32x4){0.f, 0.f, 0.f, 0.f};

    __syncthreads();

    // ---- MFMA main: rt pairs -> 6 independent acc chains ----
#pragma unroll
    for (int rtp = 0; rtp < 2; ++rtp) {
        short8 ah[2][4], al[2][4];
#pragma unroll
        for (int h = 0; h < 2; ++h) {
            int r = (rtp * 2 + h) * 16 + (lane & 15);
#pragma unroll
            for (int kt = 0; kt < 4; ++kt) {
                int off = r * XP + kt * 32 + (lane >> 4) * 8;
                ah[h][kt] = *(const short8*)&xhi[off];
                al[h][kt] = *(const short8*)&xlo[off];
            }
        }
#pragma unroll
        for (int kt = 0; kt < 4; ++kt) {
#pragma unroll
            for (int h = 0; h < 2; ++h) {
                int rt = rtp * 2 + h;
#pragma unroll
                for (int ct = 0; ct < 3; ++ct) {
                    acc[rt][ct] = __builtin_amdgcn_mfma_f32_16x16x32_bf16(
                        ah[h][kt], bh[ct][kt], acc[rt][ct], 0, 0, 0);
                    acc[rt][ct] = __builtin_amdgcn_mfma_f32_16x16x32_bf16(
                        ah[h][kt], bl[ct][kt], acc[rt][ct], 0, 0, 0);
                    acc[rt][ct] = __builtin_amdgcn_mfma_f32_16x16x32_bf16(
                        al[h][kt], bh[ct][kt], acc[rt][ct], 0, 0, 0);
                }
            }
        }
    }

    // ---- epilogue: bias + store. Q fp32; K -> hi ushort, V -> lo ushort ----
#pragma unroll
    for (int ct = 0; ct < 3; ++ct) {
        int colbase = wcol0 + ct * 16;
        int m  = colbase >> 6;                 // wave-uniform: 0=Q,1=K,2=V
        int lc = (colbase & 63) + (lane & 15);
        const float* bp = (m == 0) ? bq : (m == 1) ? bk : bv;
        float bias = bp[lc];
#pragma unroll
        for (int rt = 0; rt < 4; ++rt) {
#pragma unroll
            for (int reg = 0; reg < 4; ++reg) {
                int node = nb + rt * 16 + (lane >> 4) * 4 + reg;
                if (node >= NN) continue;
                float val = acc[rt][ct][reg] + bias;
                size_t idx = (size_t)node * D64 + lc;
                if (m == 0) {
                    Qo[idx] = val;
                } else {
                    // little-endian: ushort[0]=lo(V), ushort[1]=hi(K)
                    ((unsigned short*)KVb)[idx * 2 + (m == 1 ? 1 : 0)] = bf16_rne(val);
                }
            }
        }
    }
}

// ---------------------------------------------------------------------------
// p1a: per-block bucket histogram (LDS atomics) + deg count.
// ---------------------------------------------------------------------------
__global__ __launch_bounds__(256) void p1a_kernel(const int* __restrict__ ei,
                                                  int* __restrict__ deg,
                                                  int* __restrict__ hist)
{
    __shared__ int lh[NBUCK];
    const int t = threadIdx.x;
    for (int b = t; b < NBUCK; b += 256) lh[b] = 0;
    __syncthreads();

    const int e0 = blockIdx.x * P1_TILE;
#pragma unroll
    for (int j = 0; j < 6; ++j) {
        int e = e0 + j * 256 + t;
        if (e < EE) {
            int d = ei[EE + e];
            atomicAdd(&lh[d >> BSHIFT], 1);
            atomicAdd(&deg[d], 1);
        }
    }
    __syncthreads();
    for (int b = t; b < NBUCK; b += 256)
        hist[blockIdx.x * NBUCK + b] = lh[b];
}

// ---------------------------------------------------------------------------
// Exclusive prefix-sum over deg -> off[0..NN]; 3-kernel scan.
// ---------------------------------------------------------------------------
__global__ __launch_bounds__(256) void scanA_kernel(const int* __restrict__ deg,
                                                    int* __restrict__ bsums)
{
    int base = blockIdx.x * 1024 + threadIdx.x * 4;
    int s = 0;
#pragma unroll
    for (int j = 0; j < 4; ++j) {
        int i = base + j;
        s += (i < NN) ? deg[i] : 0;
    }
    for (int o = 32; o > 0; o >>= 1) s += __shfl_xor(s, o);
    __shared__ int ws[4];
    if ((threadIdx.x & 63) == 0) ws[threadIdx.x >> 6] = s;
    __syncthreads();
    if (threadIdx.x == 0) bsums[blockIdx.x] = ws[0] + ws[1] + ws[2] + ws[3];
}

__global__ __launch_bounds__(128) void scanB_kernel(int* __restrict__ bsums, int nb)
{
    __shared__ int sh[128];
    int t = threadIdx.x;
    int v = (t < nb) ? bsums[t] : 0;
    sh[t] = v;
    __syncthreads();
    for (int o = 1; o < 128; o <<= 1) {
        int add = (t >= o) ? sh[t - o] : 0;
        __syncthreads();
        sh[t] += add;
        __syncthreads();
    }
    if (t < nb) bsums[t] = sh[t] - v;   // exclusive
}

__global__ __launch_bounds__(256) void scanC_kernel(const int* __restrict__ deg,
                                                    const int* __restrict__ bsums,
                                                    int* __restrict__ off)
{
    int t = threadIdx.x;
    int base = blockIdx.x * 1024 + t * 4;
    int L[4]; int s = 0;
#pragma unroll
    for (int j = 0; j < 4; ++j) {
        int i = base + j;
        L[j] = (i < NN) ? deg[i] : 0;
        s += L[j];
    }
    int lane = t & 63, w = t >> 6;
    int incl = s;
    for (int o = 1; o < 64; o <<= 1) {
        int v = __shfl_up(incl, o);
        if (lane >= o) incl += v;
    }
    __shared__ int wsum[4];
    if (lane == 63) wsum[w] = incl;
    __syncthreads();
    int wbase = 0;
#pragma unroll
    for (int i = 0; i < 4; ++i) if (i < w) wbase += wsum[i];
    int run = bsums[blockIdx.x] + wbase + incl - s;
#pragma unroll
    for (int j = 0; j < 4; ++j) {
        int i = base + j;
        if (i <= NN) off[i] = run;
        run += L[j];
    }
}

// ---------------------------------------------------------------------------
// hscan: block b = bucket b; exclusive scan down the block dimension,
// seeded with off[b<<BSHIFT] -> per-(block,bucket) staging cursors.
// ---------------------------------------------------------------------------
__global__ __launch_bounds__(256) void hscan_kernel(int* __restrict__ hist,
                                                    const int* __restrict__ off)
{
    const int b = blockIdx.x;
    const int t = threadIdx.x;
    int L[5]; int s = 0;
#pragma unroll
    for (int j = 0; j < 5; ++j) {
        int blk = t * 5 + j;
        L[j] = (blk < NB_P1) ? hist[blk * NBUCK + b] : 0;
        s += L[j];
    }
    int lane = t & 63, w = t >> 6;
    int incl = s;
    for (int o = 1; o < 64; o <<= 1) {
        int v = __shfl_up(incl, o);
        if (lane >= o) incl += v;
    }
    __shared__ int wsum[4];
    if (lane == 63) wsum[w] = incl;
    __syncthreads();
    int wbase = 0;
#pragma unroll
    for (int i = 0; i < 4; ++i) if (i < w) wbase += wsum[i];
    int run = off[b << BSHIFT] + wbase + incl - s;
#pragma unroll
    for (int j = 0; j < 5; ++j) {
        int blk = t * 5 + j;
        if (blk < NB_P1) hist[blk * NBUCK + b] = run;
        run += L[j];
    }
}

// ---------------------------------------------------------------------------
// p1b: re-read edge tile, LDS-atomic rank within (block,bucket), write
// staging record at exact cursor. Zero global atomics.
// Record = { src | dstlocal<<17, attr }.
// ---------------------------------------------------------------------------
__global__ __launch_bounds__(256) void p1b_kernel(const int* __restrict__ ei,
                                                  const float* __restrict__ ea,
                                                  const int* __restrict__ hist,
                                                  int2* __restrict__ staging)
{
    __shared__ int lr[NBUCK];
    const int t = threadIdx.x;
    for (int b = t; b < NBUCK; b += 256)
        lr[b] = hist[blockIdx.x * NBUCK + b];
    __syncthreads();

    const int e0 = blockIdx.x * P1_TILE;
#pragma unroll
    for (int j = 0; j < 6; ++j) {
        int e = e0 + j * 256 + t;
        if (e < EE) {
            int s = ei[e];
            int d = ei[EE + e];
            int pos = atomicAdd(&lr[d >> BSHIFT], 1);
            staging[pos] = make_int2(s | ((d & 255) << 17), __float_as_int(ea[e]));
        }
    }
}

// ---------------------------------------------------------------------------
// p2: one block per bucket (256 nodes). LDS cursors; reads bucket staging
// once; writes exclusive CSR slice. Zero global atomics.
// ---------------------------------------------------------------------------
__global__ __launch_bounds__(256) void p2_kernel(const int2* __restrict__ staging,
                                                 const int* __restrict__ off,
                                                 int2* __restrict__ epack)
{
    const int bucket = blockIdx.x;
    const int t      = threadIdx.x;
    const int n0     = bucket << BSHIFT;

    __shared__ int lcur[256];
    int node = n0 + t;
    lcur[t] = (node < NN) ? off[node] : 0;
    __syncthreads();

    const int sb = off[n0];
    const int se = off[min(n0 + 256, NN)];

    for (int r = sb + t; r < se; r += 256) {
        int2 rec = staging[r];
        int dl = (rec.x >> 17) & 255;
        int pos = atomicAdd(&lcur[dl], 1);
        epack[pos] = make_int2(rec.x & 0x1FFFF, rec.y);
    }
}

// ---------------------------------------------------------------------------
// Attention: one wave per dst node. NEW LAYOUT: lane = e_sub*8 + h
// (8 edges x 8 heads in flight). Each lane computes the full 8-dim dot for
// its (edge, head) in registers from 2 dwordx4 packed-KV loads. Zero
// cross-lane ops per edge; butterfly reduce once per node in the epilogue.
// ---------------------------------------------------------------------------
__global__ __launch_bounds__(256) void attn_kernel(
    const float* __restrict__ Q, const unsigned int* __restrict__ KVb,
    const int* __restrict__ off, const int2* __restrict__ epack,
    const float* __restrict__ We, const float* __restrict__ be,
    float* __restrict__ out)
{
    const int lane = threadIdx.x & 63;
    const int node = blockIdx.x * 4 + (threadIdx.x >> 6);
    if (node >= NN) return;

    const int h  = lane & 7;    // head owned by this lane
    const int es = lane >> 3;   // edge slot 0..7

    // ---- hoist: fold Q, We, be, 1/sqrt(8) into per-d score coefficients ----
    float wq[8], bq[8];
    {
        const float4* qp = (const float4*)&Q[(size_t)node * D64 + h * 8];
        float4 q0 = qp[0], q1 = qp[1];
        const float4* wp = (const float4*)&We[h * 8];
        float4 w0 = wp[0], w1 = wp[1];
        const float4* bp = (const float4*)&be[h * 8];
        float4 b0 = bp[0], b1 = bp[1];
        const float rs = 0.35355339059327373f;
        float qs[8] = { q0.x, q0.y, q0.z, q0.w, q1.x, q1.y, q1.z, q1.w };
        float ws[8] = { w0.x, w0.y, w0.z, w0.w, w1.x, w1.y, w1.z, w1.w };
        float bs[8] = { b0.x, b0.y, b0.z, b0.w, b1.x, b1.y, b1.z, b1.w };
#pragma unroll
        for (int d = 0; d < 8; ++d) {
            float qr = qs[d] * rs;
            wq[d] = ws[d] * qr;
            bq[d] = bs[d] * qr;
        }
    }

    const int i0 = off[node];
    const int i1 = off[node + 1];

    float acc[8];
#pragma unroll
    for (int d = 0; d < 8; ++d) acc[d] = 0.f;
    float z = 0.f;

    for (int i = i0; i < i1; i += 8) {
        int  idx   = i + es;
        bool valid = idx < i1;
        int2 rec   = epack[valid ? idx : i0];
        int   src  = rec.x & 0x1FFFF;
        float attr = __int_as_float(rec.y);

        const unsigned int* kv = &KVb[(size_t)src * D64 + h * 8];
        uint4 wA = *(const uint4*)kv;
        uint4 wB = *(const uint4*)(kv + 4);
        unsigned int wv[8] = { wA.x, wA.y, wA.z, wA.w, wB.x, wB.y, wB.z, wB.w };

        float t = 0.f;
#pragma unroll
        for (int d = 0; d < 8; ++d) {
            float s  = fmaf(attr, wq[d], bq[d]);
            float kf = __uint_as_float(wv[d] & 0xFFFF0000u);
            t = fmaf(kf, s, t);
        }
        t = fminf(fmaxf(t, -5.f), 5.f);
        float sc = __expf(t);
        sc = valid ? sc : 0.f;

#pragma unroll
        for (int d = 0; d < 8; ++d) {
            float vf = __uint_as_float(wv[d] << 16);
            acc[d] = fmaf(vf, sc, acc[d]);
        }
        z += sc;
    }

    // ---- butterfly reduce across edge slots (lanes differing in bits 3..5) ----
#pragma unroll
    for (int m = 8; m <= 32; m <<= 1) {
#pragma unroll
        for (int d = 0; d < 8; ++d) acc[d] += __shfl_xor(acc[d], m);
        z += __shfl_xor(z, m);
    }

    // ---- lane writes out[node][h*8 + es] = acc[es] / (z + eps) ----
    float val = acc[0];
#pragma unroll
    for (int j = 1; j < 8; ++j)
        val = (es == j) ? acc[j] : val;

    out[(size_t)node * D64 + h * 8 + es] = val / (z + 1e-6f);
}

// ---------------------------------------------------------------------------
// Host launcher
// ---------------------------------------------------------------------------
static inline size_t align256(size_t v) { return (v + 255) & ~(size_t)255; }

extern "C" void kernel_launch(void* const* d_in, const int* in_sizes, int n_in,
                              void* d_out, int out_size, void* d_ws, size_t ws_size,
                              hipStream_t stream)
{
    const float* x  = (const float*)d_in[0];
    const float* ea = (const float*)d_in[1];
    const int*   ei = (const int*)  d_in[2];   // [2][EE]: row0=src, row1=dst
    const float* Wq = (const float*)d_in[3];
    const float* bq = (const float*)d_in[4];
    const float* Wk = (const float*)d_in[5];
    const float* bk = (const float*)d_in[6];
    const float* We = (const float*)d_in[7];
    const float* be = (const float*)d_in[8];
    const float* Wv = (const float*)d_in[9];
    const float* bv = (const float*)d_in[10];
    float* out = (float*)d_out;

    char* ws = (char*)d_ws;
    size_t o = 0;
    float*          Q       = (float*)(ws + o);          o += align256((size_t)NN * D64 * 4);
    unsigned int*   KVb     = (unsigned int*)(ws + o);   o += align256((size_t)NN * D64 * 4);
    int*            deg     = (int*)(ws + o);            o += align256((size_t)NN * 4);
    int*            off     = (int*)(ws + o);            o += align256((size_t)(NN + 1) * 4);
    int*            bsums   = (int*)(ws + o);            o += align256(128 * 4);
    unsigned short* wt_hi   = (unsigned short*)(ws + o); o += align256((size_t)192 * 128 * 2);
    unsigned short* wt_lo   = (unsigned short*)(ws + o); o += align256((size_t)192 * 128 * 2);
    int*            hist    = (int*)(ws + o);            o += align256((size_t)NB_P1 * NBUCK * 4);
    int2*           staging = (int2*)(ws + o);           o += align256((size_t)EE * 8);
    int2*           epack   = (int2*)(ws + o);           o += align256((size_t)EE * 8);
    (void)ws_size; (void)out_size; (void)in_sizes; (void)n_in;

    const int nbScan = (NN + 1 + 1023) / 1024;   // 98

    (void)hipMemsetAsync(deg, 0, (size_t)NN * 4, stream);

    wtrans_kernel<<<96, 256, 0, stream>>>(Wq, Wk, Wv, wt_hi, wt_lo);
    qkv_kernel<<<(NN + 63) / 64, 256, 0, stream>>>(x, wt_hi, wt_lo, bq, bk, bv, Q, KVb);
    p1a_kernel<<<NB_P1, 256, 0, stream>>>(ei, deg, hist);
    scanA_kernel<<<nbScan, 256, 0, stream>>>(deg, bsums);
    scanB_kernel<<<1, 128, 0, stream>>>(bsums, nbScan);
    scanC_kernel<<<nbScan, 256, 0, stream>>>(deg, bsums, off);
    hscan_kernel<<<NBUCK, 256, 0, stream>>>(hist, off);
    p1b_kernel<<<NB_P1, 256, 0, stream>>>(ei, ea, hist, staging);
    p2_kernel<<<NBUCK, 256, 0, stream>>>(staging, off, epack);
    attn_kernel<<<(NN + 3) / 4, 256, 0, stream>>>(Q, KVb, off, epack, We, be, out);
}

// Round 11
// 174.602 us; speedup vs baseline: 8.1035x; 1.4450x over previous
//
#include <hip/hip_runtime.h>
#include <math.h>

#define NN 100000
#define EE 1600000
#define IND 128
#define D64 64    // HEADS*OUT_DIM

#define BSHIFT 8          // bucket = dst >> 8 (256 nodes per bucket)
#define NBUCK 391         // ceil(NN / 256)
#define P1_TILE 1536
#define NB_P1 1042        // ceil(EE / P1_TILE)

typedef __attribute__((ext_vector_type(8))) short  short8;
typedef __attribute__((ext_vector_type(4))) float  f32x4;

// ---------------------------------------------------------------------------
// wtrans: one-shot transpose+split of [Wq|Wk|Wv] (128x192 fp32) into
// wt_hi/wt_lo [col 0..191][k 0..127] bf16 (Markidis hi/lo split).
// ---------------------------------------------------------------------------
__device__ __forceinline__ unsigned short bf16_rne(float v) {
    unsigned int u = __float_as_uint(v);
    return (unsigned short)((u + 0x7FFFu + ((u >> 16) & 1u)) >> 16);
}

__global__ __launch_bounds__(256) void wtrans_kernel(
    const float* __restrict__ Wq, const float* __restrict__ Wk,
    const float* __restrict__ Wv,
    unsigned short* __restrict__ wt_hi, unsigned short* __restrict__ wt_lo)
{
    int idx = blockIdx.x * 256 + threadIdx.x;     // 0..24575
    if (idx >= 192 * 128) return;
    int col = idx >> 7, k = idx & 127;
    const float* W = (col < 64) ? Wq : (col < 128) ? Wk : Wv;
    float v = W[(size_t)k * D64 + (col & 63)];
    unsigned short h = bf16_rne(v);
    float hf = __uint_as_float((unsigned int)h << 16);
    unsigned short l = bf16_rne(v - hf);
    wt_hi[idx] = h;
    wt_lo[idx] = l;
}

// ---------------------------------------------------------------------------
// qkv v3: BM=32 (grid 3125, exact), LDS 16.9KB, B-frags STREAMED per kt
// from L2 (low VGPR -> high occupancy). 2-term Markidis split as before.
// Q written fp32; K/V packed bf16 into KVb: uint = (K<<16)|V.
// ---------------------------------------------------------------------------
#define XP 132   // padded k-stride (ushort) for LDS x tiles

__global__ __launch_bounds__(256) void qkv_kernel(
    const float* __restrict__ x,
    const unsigned short* __restrict__ wt_hi,
    const unsigned short* __restrict__ wt_lo,
    const float* __restrict__ bq, const float* __restrict__ bk,
    const float* __restrict__ bv,
    float* __restrict__ Qo, unsigned int* __restrict__ KVb)
{
    __shared__ unsigned short xhi[32 * XP];   // 8448 B
    __shared__ unsigned short xlo[32 * XP];   // 8448 B

    const int t    = threadIdx.x;
    const int wave = t >> 6;
    const int lane = t & 63;
    const int nb   = blockIdx.x * 32;        // 3125 * 32 = 100000 exact

    // ---- stage x tile 32x128 fp32 -> hi/lo bf16 in LDS (16 floats/thread) ----
    {
        const int row = t >> 3;          // 0..31
        const int c   = t & 7;           // 16-float chunk
        const float* xr = x + (size_t)(nb + row) * IND + c * 16;
        float4 a0 = *(const float4*)(xr);
        float4 a1 = *(const float4*)(xr + 4);
        float4 a2 = *(const float4*)(xr + 8);
        float4 a3 = *(const float4*)(xr + 12);
        float vs[16] = { a0.x, a0.y, a0.z, a0.w, a1.x, a1.y, a1.z, a1.w,
                         a2.x, a2.y, a2.z, a2.w, a3.x, a3.y, a3.z, a3.w };
        short8 h0, h1, l0, l1;
#pragma unroll
        for (int j = 0; j < 8; ++j) {
            unsigned short hb = bf16_rne(vs[j]);
            float hf = __uint_as_float((unsigned int)hb << 16);
            h0[j] = (short)hb;
            l0[j] = (short)bf16_rne(vs[j] - hf);
        }
#pragma unroll
        for (int j = 0; j < 8; ++j) {
            unsigned short hb = bf16_rne(vs[8 + j]);
            float hf = __uint_as_float((unsigned int)hb << 16);
            h1[j] = (short)hb;
            l1[j] = (short)bf16_rne(vs[8 + j] - hf);
        }
        int o0 = row * XP + c * 16;
        *(short8*)&xhi[o0]     = h0;
        *(short8*)&xhi[o0 + 8] = h1;
        *(short8*)&xlo[o0]     = l0;
        *(short8*)&xlo[o0 + 8] = l1;
    }
    __syncthreads();

    const int wcol0 = wave * 48;

    f32x4 acc[2][3];
#pragma unroll
    for (int rt = 0; rt < 2; ++rt)
#pragma unroll
        for (int ct = 0; ct < 3; ++ct)
            acc[rt][ct] = (f32x4){0.f, 0.f, 0.f, 0.f};

#pragma unroll
    for (int kt = 0; kt < 4; ++kt) {
        // stream B-fragments for this kt (L2-hot, 6 x dwordx4)
        short8 bh[3], bl[3];
#pragma unroll
        for (int ct = 0; ct < 3; ++ct) {
            int col = wcol0 + ct * 16 + (lane & 15);
            int a = col * 128 + kt * 32 + (lane >> 4) * 8;
            bh[ct] = *(const short8*)&wt_hi[a];
            bl[ct] = *(const short8*)&wt_lo[a];
        }
        // A-fragments from LDS (4 x ds_read_b128)
        short8 ah[2], al[2];
#pragma unroll
        for (int rt = 0; rt < 2; ++rt) {
            int o2 = (rt * 16 + (lane & 15)) * XP + kt * 32 + (lane >> 4) * 8;
            ah[rt] = *(const short8*)&xhi[o2];
            al[rt] = *(const short8*)&xlo[o2];
        }
#pragma unroll
        for (int rt = 0; rt < 2; ++rt) {
#pragma unroll
            for (int ct = 0; ct < 3; ++ct) {
                acc[rt][ct] = __builtin_amdgcn_mfma_f32_16x16x32_bf16(
                    ah[rt], bh[ct], acc[rt][ct], 0, 0, 0);
                acc[rt][ct] = __builtin_amdgcn_mfma_f32_16x16x32_bf16(
                    ah[rt], bl[ct], acc[rt][ct], 0, 0, 0);
                acc[rt][ct] = __builtin_amdgcn_mfma_f32_16x16x32_bf16(
                    al[rt], bh[ct], acc[rt][ct], 0, 0, 0);
            }
        }
    }

    // ---- epilogue: bias + store. Q fp32; K -> hi ushort, V -> lo ushort ----
#pragma unroll
    for (int ct = 0; ct < 3; ++ct) {
        int colbase = wcol0 + ct * 16;
        int m  = colbase >> 6;                 // wave-uniform: 0=Q,1=K,2=V
        int lc = (colbase & 63) + (lane & 15);
        const float* bp = (m == 0) ? bq : (m == 1) ? bk : bv;
        float bias = bp[lc];
#pragma unroll
        for (int rt = 0; rt < 2; ++rt) {
#pragma unroll
            for (int reg = 0; reg < 4; ++reg) {
                int node = nb + rt * 16 + (lane >> 4) * 4 + reg;
                float val = acc[rt][ct][reg] + bias;
                size_t idx = (size_t)node * D64 + lc;
                if (m == 0) {
                    Qo[idx] = val;
                } else {
                    // little-endian: ushort[0]=lo(V), ushort[1]=hi(K)
                    ((unsigned short*)KVb)[idx * 2 + (m == 1 ? 1 : 0)] = bf16_rne(val);
                }
            }
        }
    }
}

// ---------------------------------------------------------------------------
// p1a: per-block bucket histogram ONLY (LDS atomics). deg counting removed.
// ---------------------------------------------------------------------------
__global__ __launch_bounds__(256) void p1a_kernel(const int* __restrict__ ei,
                                                  int* __restrict__ hist)
{
    __shared__ int lh[NBUCK];
    const int t = threadIdx.x;
    for (int b = t; b < NBUCK; b += 256) lh[b] = 0;
    __syncthreads();

    const int e0 = blockIdx.x * P1_TILE;
#pragma unroll
    for (int j = 0; j < 6; ++j) {
        int e = e0 + j * 256 + t;
        if (e < EE) {
            int d = ei[EE + e];
            atomicAdd(&lh[d >> BSHIFT], 1);
        }
    }
    __syncthreads();
    for (int b = t; b < NBUCK; b += 256)
        hist[blockIdx.x * NBUCK + b] = lh[b];
}

// ---------------------------------------------------------------------------
// btot: per-bucket total = sum of hist column.
// ---------------------------------------------------------------------------
__global__ __launch_bounds__(256) void btot_kernel(const int* __restrict__ hist,
                                                   int* __restrict__ btot)
{
    const int b = blockIdx.x;
    const int t = threadIdx.x;
    int s = 0;
#pragma unroll
    for (int j = 0; j < 5; ++j) {
        int blk = t * 5 + j;
        if (blk < NB_P1) s += hist[blk * NBUCK + b];
    }
    for (int o = 32; o > 0; o >>= 1) s += __shfl_xor(s, o);
    __shared__ int ws4[4];
    if ((t & 63) == 0) ws4[t >> 6] = s;
    __syncthreads();
    if (t == 0) btot[b] = ws4[0] + ws4[1] + ws4[2] + ws4[3];
}

// ---------------------------------------------------------------------------
// bscan: exclusive scan of 391 bucket totals -> bbase[0..391] (bbase[391]=EE).
// ---------------------------------------------------------------------------
__global__ __launch_bounds__(256) void bscan_kernel(const int* __restrict__ btot,
                                                    int* __restrict__ bbase)
{
    const int t = threadIdx.x;
    int i0 = 2 * t, i1 = 2 * t + 1;
    int v0 = (i0 < NBUCK) ? btot[i0] : 0;
    int v1 = (i1 < NBUCK) ? btot[i1] : 0;
    int s = v0 + v1;
    int lane = t & 63, w = t >> 6;
    int incl = s;
    for (int o = 1; o < 64; o <<= 1) {
        int v = __shfl_up(incl, o);
        if (lane >= o) incl += v;
    }
    __shared__ int wsum[4];
    if (lane == 63) wsum[w] = incl;
    __syncthreads();
    int wbase = 0;
#pragma unroll
    for (int i = 0; i < 4; ++i) if (i < w) wbase += wsum[i];
    int excl = wbase + incl - s;
    if (i0 <= NBUCK) bbase[i0] = excl;
    if (i1 <= NBUCK) bbase[i1] = excl + v0;
}

// ---------------------------------------------------------------------------
// hscan: block b = bucket b; exclusive scan of hist column down the block
// dimension, seeded with bbase[b] -> per-(block,bucket) staging cursors.
// ---------------------------------------------------------------------------
__global__ __launch_bounds__(256) void hscan_kernel(int* __restrict__ hist,
                                                    const int* __restrict__ bbase)
{
    const int b = blockIdx.x;
    const int t = threadIdx.x;
    int L[5]; int s = 0;
#pragma unroll
    for (int j = 0; j < 5; ++j) {
        int blk = t * 5 + j;
        L[j] = (blk < NB_P1) ? hist[blk * NBUCK + b] : 0;
        s += L[j];
    }
    int lane = t & 63, w = t >> 6;
    int incl = s;
    for (int o = 1; o < 64; o <<= 1) {
        int v = __shfl_up(incl, o);
        if (lane >= o) incl += v;
    }
    __shared__ int wsum[4];
    if (lane == 63) wsum[w] = incl;
    __syncthreads();
    int wbase = 0;
#pragma unroll
    for (int i = 0; i < 4; ++i) if (i < w) wbase += wsum[i];
    int run = bbase[b] + wbase + incl - s;
#pragma unroll
    for (int j = 0; j < 5; ++j) {
        int blk = t * 5 + j;
        if (blk < NB_P1) hist[blk * NBUCK + b] = run;
        run += L[j];
    }
}

// ---------------------------------------------------------------------------
// p1b: re-read edge tile, LDS-atomic rank within (block,bucket), write
// staging record at exact cursor. Zero global atomics.
// Record = { src | dstlocal<<17, attr }.
// ---------------------------------------------------------------------------
__global__ __launch_bounds__(256) void p1b_kernel(const int* __restrict__ ei,
                                                  const float* __restrict__ ea,
                                                  const int* __restrict__ hist,
                                                  int2* __restrict__ staging)
{
    __shared__ int lr[NBUCK];
    const int t = threadIdx.x;
    for (int b = t; b < NBUCK; b += 256)
        lr[b] = hist[blockIdx.x * NBUCK + b];
    __syncthreads();

    const int e0 = blockIdx.x * P1_TILE;
#pragma unroll
    for (int j = 0; j < 6; ++j) {
        int e = e0 + j * 256 + t;
        if (e < EE) {
            int s = ei[e];
            int d = ei[EE + e];
            int pos = atomicAdd(&lr[d >> BSHIFT], 1);
            staging[pos] = make_int2(s | ((d & 255) << 17), __float_as_int(ea[e]));
        }
    }
}

// ---------------------------------------------------------------------------
// p2: one block per bucket. Pass 1: count per-node into LDS; 256-wide scan
// seeded at bbase[bucket] -> writes off[]; pass 2: place records via LDS
// cursors into epack (exclusive CSR slice). Zero global atomics.
// ---------------------------------------------------------------------------
__global__ __launch_bounds__(256) void p2_kernel(const int2* __restrict__ staging,
                                                 const int* __restrict__ bbase,
                                                 int* __restrict__ off,
                                                 int2* __restrict__ epack)
{
    const int bucket = blockIdx.x;
    const int t      = threadIdx.x;
    const int n0     = bucket << BSHIFT;
    const int sb     = bbase[bucket];
    const int se     = bbase[bucket + 1];

    __shared__ int lcnt[256];
    __shared__ int lcur[256];
    __shared__ int wsum[4];
    lcnt[t] = 0;
    __syncthreads();

    for (int r = sb + t; r < se; r += 256)
        atomicAdd(&lcnt[(staging[r].x >> 17) & 255], 1);
    __syncthreads();

    int cnt  = lcnt[t];
    int lane = t & 63, w = t >> 6;
    int incl = cnt;
    for (int o = 1; o < 64; o <<= 1) {
        int v = __shfl_up(incl, o);
        if (lane >= o) incl += v;
    }
    if (lane == 63) wsum[w] = incl;
    __syncthreads();
    int wbase = 0;
#pragma unroll
    for (int i = 0; i < 4; ++i) if (i < w) wbase += wsum[i];
    int ov = sb + wbase + incl - cnt;     // exclusive offset for node n0+t

    int node = n0 + t;
    if (node <= NN) off[node] = ov;
    lcur[t] = ov;
    __syncthreads();

    for (int r = sb + t; r < se; r += 256) {
        int2 rec = staging[r];
        int dl = (rec.x >> 17) & 255;
        int pos = atomicAdd(&lcur[dl], 1);
        epack[pos] = make_int2(rec.x & 0x1FFFF, rec.y);
    }
}

// ---------------------------------------------------------------------------
// Attention: one wave per dst node; lane = e_sub*8 + h (8 edges x 8 heads).
// Each lane computes the full 8-dim dot for its (edge, head) from 2 dwordx4
// packed-KV loads; butterfly reduce once per node in the epilogue.
// ---------------------------------------------------------------------------
__global__ __launch_bounds__(256) void attn_kernel(
    const float* __restrict__ Q, const unsigned int* __restrict__ KVb,
    const int* __restrict__ off, const int2* __restrict__ epack,
    const float* __restrict__ We, const float* __restrict__ be,
    float* __restrict__ out)
{
    const int lane = threadIdx.x & 63;
    const int node = blockIdx.x * 4 + (threadIdx.x >> 6);
    if (node >= NN) return;

    const int h  = lane & 7;    // head owned by this lane
    const int es = lane >> 3;   // edge slot 0..7

    // ---- hoist: fold Q, We, be, 1/sqrt(8) into per-d score coefficients ----
    float wq[8], bq[8];
    {
        const float4* qp = (const float4*)&Q[(size_t)node * D64 + h * 8];
        float4 q0 = qp[0], q1 = qp[1];
        const float4* wp = (const float4*)&We[h * 8];
        float4 w0 = wp[0], w1 = wp[1];
        const float4* bp = (const float4*)&be[h * 8];
        float4 b0 = bp[0], b1 = bp[1];
        const float rs = 0.35355339059327373f;
        float qs[8] = { q0.x, q0.y, q0.z, q0.w, q1.x, q1.y, q1.z, q1.w };
        float ws[8] = { w0.x, w0.y, w0.z, w0.w, w1.x, w1.y, w1.z, w1.w };
        float bs[8] = { b0.x, b0.y, b0.z, b0.w, b1.x, b1.y, b1.z, b1.w };
#pragma unroll
        for (int d = 0; d < 8; ++d) {
            float qr = qs[d] * rs;
            wq[d] = ws[d] * qr;
            bq[d] = bs[d] * qr;
        }
    }

    const int i0 = off[node];
    const int i1 = off[node + 1];

    float acc[8];
#pragma unroll
    for (int d = 0; d < 8; ++d) acc[d] = 0.f;
    float z = 0.f;

    for (int i = i0; i < i1; i += 8) {
        int  idx   = i + es;
        bool valid = idx < i1;
        int2 rec   = epack[valid ? idx : i0];
        int   src  = rec.x & 0x1FFFF;
        float attr = __int_as_float(rec.y);

        const unsigned int* kv = &KVb[(size_t)src * D64 + h * 8];
        uint4 wA = *(const uint4*)kv;
        uint4 wB = *(const uint4*)(kv + 4);
        unsigned int wv[8] = { wA.x, wA.y, wA.z, wA.w, wB.x, wB.y, wB.z, wB.w };

        float t = 0.f;
#pragma unroll
        for (int d = 0; d < 8; ++d) {
            float s  = fmaf(attr, wq[d], bq[d]);
            float kf = __uint_as_float(wv[d] & 0xFFFF0000u);
            t = fmaf(kf, s, t);
        }
        t = fminf(fmaxf(t, -5.f), 5.f);
        float sc = __expf(t);
        sc = valid ? sc : 0.f;

#pragma unroll
        for (int d = 0; d < 8; ++d) {
            float vf = __uint_as_float(wv[d] << 16);
            acc[d] = fmaf(vf, sc, acc[d]);
        }
        z += sc;
    }

    // ---- butterfly reduce across edge slots (lanes differing in bits 3..5) ----
#pragma unroll
    for (int m = 8; m <= 32; m <<= 1) {
#pragma unroll
        for (int d = 0; d < 8; ++d) acc[d] += __shfl_xor(acc[d], m);
        z += __shfl_xor(z, m);
    }

    // ---- lane writes out[node][h*8 + es] = acc[es] / (z + eps) ----
    float val = acc[0];
#pragma unroll
    for (int j = 1; j < 8; ++j)
        val = (es == j) ? acc[j] : val;

    out[(size_t)node * D64 + h * 8 + es] = val / (z + 1e-6f);
}

// ---------------------------------------------------------------------------
// Host launcher
// ---------------------------------------------------------------------------
static inline size_t align256(size_t v) { return (v + 255) & ~(size_t)255; }

extern "C" void kernel_launch(void* const* d_in, const int* in_sizes, int n_in,
                              void* d_out, int out_size, void* d_ws, size_t ws_size,
                              hipStream_t stream)
{
    const float* x  = (const float*)d_in[0];
    const float* ea = (const float*)d_in[1];
    const int*   ei = (const int*)  d_in[2];   // [2][EE]: row0=src, row1=dst
    const float* Wq = (const float*)d_in[3];
    const float* bq = (const float*)d_in[4];
    const float* Wk = (const float*)d_in[5];
    const float* bk = (const float*)d_in[6];
    const float* We = (const float*)d_in[7];
    const float* be = (const float*)d_in[8];
    const float* Wv = (const float*)d_in[9];
    const float* bv = (const float*)d_in[10];
    float* out = (float*)d_out;

    char* ws = (char*)d_ws;
    size_t o = 0;
    float*          Q       = (float*)(ws + o);          o += align256((size_t)NN * D64 * 4);
    unsigned int*   KVb     = (unsigned int*)(ws + o);   o += align256((size_t)NN * D64 * 4);
    int*            off     = (int*)(ws + o);            o += align256((size_t)(NN + 1) * 4);
    unsigned short* wt_hi   = (unsigned short*)(ws + o); o += align256((size_t)192 * 128 * 2);
    unsigned short* wt_lo   = (unsigned short*)(ws + o); o += align256((size_t)192 * 128 * 2);
    int*            hist    = (int*)(ws + o);            o += align256((size_t)NB_P1 * NBUCK * 4);
    int*            btot    = (int*)(ws + o);            o += align256((size_t)NBUCK * 4);
    int*            bbase   = (int*)(ws + o);            o += align256((size_t)(NBUCK + 1) * 4);
    int2*           staging = (int2*)(ws + o);           o += align256((size_t)EE * 8);
    int2*           epack   = (int2*)(ws + o);           o += align256((size_t)EE * 8);
    (void)ws_size; (void)out_size; (void)in_sizes; (void)n_in;

    wtrans_kernel<<<96, 256, 0, stream>>>(Wq, Wk, Wv, wt_hi, wt_lo);
    qkv_kernel<<<NN / 32, 256, 0, stream>>>(x, wt_hi, wt_lo, bq, bk, bv, Q, KVb);
    p1a_kernel<<<NB_P1, 256, 0, stream>>>(ei, hist);
    btot_kernel<<<NBUCK, 256, 0, stream>>>(hist, btot);
    bscan_kernel<<<1, 256, 0, stream>>>(btot, bbase);
    hscan_kernel<<<NBUCK, 256, 0, stream>>>(hist, bbase);
    p1b_kernel<<<NB_P1, 256, 0, stream>>>(ei, ea, hist, staging);
    p2_kernel<<<NBUCK, 256, 0, stream>>>(staging, bbase, off, epack);
    attn_kernel<<<(NN + 3) / 4, 256, 0, stream>>>(Q, KVb, off, epack, We, be, out);
}

// Round 12
// 174.231 us; speedup vs baseline: 8.1208x; 1.0021x over previous
//
#include <hip/hip_runtime.h>
#include <math.h>

#define NN 100000
#define EE 1600000
#define IND 128
#define D64 64    // HEADS*OUT_DIM

#define BSHIFT 8          // bucket = dst >> 8 (256 nodes per bucket)
#define NBUCK 391         // ceil(NN / 256)
#define P1_TILE 1536
#define NB_P1 1042        // ceil(EE / P1_TILE)

typedef __attribute__((ext_vector_type(8))) short  short8;
typedef __attribute__((ext_vector_type(4))) float  f32x4;

// ---------------------------------------------------------------------------
// wtrans: one-shot transpose+split of [Wq|Wk|Wv] (128x192 fp32) into
// wt_hi/wt_lo [col 0..191][k 0..127] bf16 (Markidis hi/lo split).
// ---------------------------------------------------------------------------
__device__ __forceinline__ unsigned short bf16_rne(float v) {
    unsigned int u = __float_as_uint(v);
    return (unsigned short)((u + 0x7FFFu + ((u >> 16) & 1u)) >> 16);
}

__global__ __launch_bounds__(256) void wtrans_kernel(
    const float* __restrict__ Wq, const float* __restrict__ Wk,
    const float* __restrict__ Wv,
    unsigned short* __restrict__ wt_hi, unsigned short* __restrict__ wt_lo)
{
    int idx = blockIdx.x * 256 + threadIdx.x;     // 0..24575
    if (idx >= 192 * 128) return;
    int col = idx >> 7, k = idx & 127;
    const float* W = (col < 64) ? Wq : (col < 128) ? Wk : Wv;
    float v = W[(size_t)k * D64 + (col & 63)];
    unsigned short h = bf16_rne(v);
    float hf = __uint_as_float((unsigned int)h << 16);
    unsigned short l = bf16_rne(v - hf);
    wt_hi[idx] = h;
    wt_lo[idx] = l;
}

// ---------------------------------------------------------------------------
// qkv v3: BM=32 (grid 3125, exact), LDS 16.9KB, B-frags STREAMED per kt
// from L2 (low VGPR -> high occupancy). 2-term Markidis split.
// Q written fp32; K/V packed bf16 into KVb: uint = (K<<16)|V.
// ---------------------------------------------------------------------------
#define XP 132   // padded k-stride (ushort) for LDS x tiles

__global__ __launch_bounds__(256) void qkv_kernel(
    const float* __restrict__ x,
    const unsigned short* __restrict__ wt_hi,
    const unsigned short* __restrict__ wt_lo,
    const float* __restrict__ bq, const float* __restrict__ bk,
    const float* __restrict__ bv,
    float* __restrict__ Qo, unsigned int* __restrict__ KVb)
{
    __shared__ unsigned short xhi[32 * XP];   // 8448 B
    __shared__ unsigned short xlo[32 * XP];   // 8448 B

    const int t    = threadIdx.x;
    const int wave = t >> 6;
    const int lane = t & 63;
    const int nb   = blockIdx.x * 32;        // 3125 * 32 = 100000 exact

    // ---- stage x tile 32x128 fp32 -> hi/lo bf16 in LDS (16 floats/thread) ----
    {
        const int row = t >> 3;          // 0..31
        const int c   = t & 7;           // 16-float chunk
        const float* xr = x + (size_t)(nb + row) * IND + c * 16;
        float4 a0 = *(const float4*)(xr);
        float4 a1 = *(const float4*)(xr + 4);
        float4 a2 = *(const float4*)(xr + 8);
        float4 a3 = *(const float4*)(xr + 12);
        float vs[16] = { a0.x, a0.y, a0.z, a0.w, a1.x, a1.y, a1.z, a1.w,
                         a2.x, a2.y, a2.z, a2.w, a3.x, a3.y, a3.z, a3.w };
        short8 h0, h1, l0, l1;
#pragma unroll
        for (int j = 0; j < 8; ++j) {
            unsigned short hb = bf16_rne(vs[j]);
            float hf = __uint_as_float((unsigned int)hb << 16);
            h0[j] = (short)hb;
            l0[j] = (short)bf16_rne(vs[j] - hf);
        }
#pragma unroll
        for (int j = 0; j < 8; ++j) {
            unsigned short hb = bf16_rne(vs[8 + j]);
            float hf = __uint_as_float((unsigned int)hb << 16);
            h1[j] = (short)hb;
            l1[j] = (short)bf16_rne(vs[8 + j] - hf);
        }
        int o0 = row * XP + c * 16;
        *(short8*)&xhi[o0]     = h0;
        *(short8*)&xhi[o0 + 8] = h1;
        *(short8*)&xlo[o0]     = l0;
        *(short8*)&xlo[o0 + 8] = l1;
    }
    __syncthreads();

    const int wcol0 = wave * 48;

    f32x4 acc[2][3];
#pragma unroll
    for (int rt = 0; rt < 2; ++rt)
#pragma unroll
        for (int ct = 0; ct < 3; ++ct)
            acc[rt][ct] = (f32x4){0.f, 0.f, 0.f, 0.f};

#pragma unroll
    for (int kt = 0; kt < 4; ++kt) {
        // stream B-fragments for this kt (L2-hot, 6 x dwordx4)
        short8 bh[3], bl[3];
#pragma unroll
        for (int ct = 0; ct < 3; ++ct) {
            int col = wcol0 + ct * 16 + (lane & 15);
            int a = col * 128 + kt * 32 + (lane >> 4) * 8;
            bh[ct] = *(const short8*)&wt_hi[a];
            bl[ct] = *(const short8*)&wt_lo[a];
        }
        // A-fragments from LDS (4 x ds_read_b128)
        short8 ah[2], al[2];
#pragma unroll
        for (int rt = 0; rt < 2; ++rt) {
            int o2 = (rt * 16 + (lane & 15)) * XP + kt * 32 + (lane >> 4) * 8;
            ah[rt] = *(const short8*)&xhi[o2];
            al[rt] = *(const short8*)&xlo[o2];
        }
#pragma unroll
        for (int rt = 0; rt < 2; ++rt) {
#pragma unroll
            for (int ct = 0; ct < 3; ++ct) {
                acc[rt][ct] = __builtin_amdgcn_mfma_f32_16x16x32_bf16(
                    ah[rt], bh[ct], acc[rt][ct], 0, 0, 0);
                acc[rt][ct] = __builtin_amdgcn_mfma_f32_16x16x32_bf16(
                    ah[rt], bl[ct], acc[rt][ct], 0, 0, 0);
                acc[rt][ct] = __builtin_amdgcn_mfma_f32_16x16x32_bf16(
                    al[rt], bh[ct], acc[rt][ct], 0, 0, 0);
            }
        }
    }

    // ---- epilogue: bias + store. Q fp32; K -> hi ushort, V -> lo ushort ----
#pragma unroll
    for (int ct = 0; ct < 3; ++ct) {
        int colbase = wcol0 + ct * 16;
        int m  = colbase >> 6;                 // wave-uniform: 0=Q,1=K,2=V
        int lc = (colbase & 63) + (lane & 15);
        const float* bp = (m == 0) ? bq : (m == 1) ? bk : bv;
        float bias = bp[lc];
#pragma unroll
        for (int rt = 0; rt < 2; ++rt) {
#pragma unroll
            for (int reg = 0; reg < 4; ++reg) {
                int node = nb + rt * 16 + (lane >> 4) * 4 + reg;
                float val = acc[rt][ct][reg] + bias;
                size_t idx = (size_t)node * D64 + lc;
                if (m == 0) {
                    Qo[idx] = val;
                } else {
                    // little-endian: ushort[0]=lo(V), ushort[1]=hi(K)
                    ((unsigned short*)KVb)[idx * 2 + (m == 1 ? 1 : 0)] = bf16_rne(val);
                }
            }
        }
    }
}

// ---------------------------------------------------------------------------
// p1a: per-block bucket histogram (LDS atomics).
// ---------------------------------------------------------------------------
__global__ __launch_bounds__(256) void p1a_kernel(const int* __restrict__ ei,
                                                  int* __restrict__ hist)
{
    __shared__ int lh[NBUCK];
    const int t = threadIdx.x;
    for (int b = t; b < NBUCK; b += 256) lh[b] = 0;
    __syncthreads();

    const int e0 = blockIdx.x * P1_TILE;
#pragma unroll
    for (int j = 0; j < 6; ++j) {
        int e = e0 + j * 256 + t;
        if (e < EE) {
            int d = ei[EE + e];
            atomicAdd(&lh[d >> BSHIFT], 1);
        }
    }
    __syncthreads();
    for (int b = t; b < NBUCK; b += 256)
        hist[blockIdx.x * NBUCK + b] = lh[b];
}

// ---------------------------------------------------------------------------
// btot: per-bucket total = sum of hist column.
// ---------------------------------------------------------------------------
__global__ __launch_bounds__(256) void btot_kernel(const int* __restrict__ hist,
                                                   int* __restrict__ btot)
{
    const int b = blockIdx.x;
    const int t = threadIdx.x;
    int s = 0;
#pragma unroll
    for (int j = 0; j < 5; ++j) {
        int blk = t * 5 + j;
        if (blk < NB_P1) s += hist[blk * NBUCK + b];
    }
    for (int o = 32; o > 0; o >>= 1) s += __shfl_xor(s, o);
    __shared__ int ws4[4];
    if ((t & 63) == 0) ws4[t >> 6] = s;
    __syncthreads();
    if (t == 0) btot[b] = ws4[0] + ws4[1] + ws4[2] + ws4[3];
}

// ---------------------------------------------------------------------------
// bscan: exclusive scan of 391 bucket totals -> bbase[0..391].
// ---------------------------------------------------------------------------
__global__ __launch_bounds__(256) void bscan_kernel(const int* __restrict__ btot,
                                                    int* __restrict__ bbase)
{
    const int t = threadIdx.x;
    int i0 = 2 * t, i1 = 2 * t + 1;
    int v0 = (i0 < NBUCK) ? btot[i0] : 0;
    int v1 = (i1 < NBUCK) ? btot[i1] : 0;
    int s = v0 + v1;
    int lane = t & 63, w = t >> 6;
    int incl = s;
    for (int o = 1; o < 64; o <<= 1) {
        int v = __shfl_up(incl, o);
        if (lane >= o) incl += v;
    }
    __shared__ int wsum[4];
    if (lane == 63) wsum[w] = incl;
    __syncthreads();
    int wbase = 0;
#pragma unroll
    for (int i = 0; i < 4; ++i) if (i < w) wbase += wsum[i];
    int excl = wbase + incl - s;
    if (i0 <= NBUCK) bbase[i0] = excl;
    if (i1 <= NBUCK) bbase[i1] = excl + v0;
}

// ---------------------------------------------------------------------------
// hscan: block b = bucket b; exclusive scan of hist column, seeded bbase[b].
// ---------------------------------------------------------------------------
__global__ __launch_bounds__(256) void hscan_kernel(int* __restrict__ hist,
                                                    const int* __restrict__ bbase)
{
    const int b = blockIdx.x;
    const int t = threadIdx.x;
    int L[5]; int s = 0;
#pragma unroll
    for (int j = 0; j < 5; ++j) {
        int blk = t * 5 + j;
        L[j] = (blk < NB_P1) ? hist[blk * NBUCK + b] : 0;
        s += L[j];
    }
    int lane = t & 63, w = t >> 6;
    int incl = s;
    for (int o = 1; o < 64; o <<= 1) {
        int v = __shfl_up(incl, o);
        if (lane >= o) incl += v;
    }
    __shared__ int wsum[4];
    if (lane == 63) wsum[w] = incl;
    __syncthreads();
    int wbase = 0;
#pragma unroll
    for (int i = 0; i < 4; ++i) if (i < w) wbase += wsum[i];
    int run = bbase[b] + wbase + incl - s;
#pragma unroll
    for (int j = 0; j < 5; ++j) {
        int blk = t * 5 + j;
        if (blk < NB_P1) hist[blk * NBUCK + b] = run;
        run += L[j];
    }
}

// ---------------------------------------------------------------------------
// p1b: re-read edge tile, LDS-atomic rank within (block,bucket), write
// staging record at exact cursor. Record = { src | dstlocal<<17, attr }.
// ---------------------------------------------------------------------------
__global__ __launch_bounds__(256) void p1b_kernel(const int* __restrict__ ei,
                                                  const float* __restrict__ ea,
                                                  const int* __restrict__ hist,
                                                  int2* __restrict__ staging)
{
    __shared__ int lr[NBUCK];
    const int t = threadIdx.x;
    for (int b = t; b < NBUCK; b += 256)
        lr[b] = hist[blockIdx.x * NBUCK + b];
    __syncthreads();

    const int e0 = blockIdx.x * P1_TILE;
#pragma unroll
    for (int j = 0; j < 6; ++j) {
        int e = e0 + j * 256 + t;
        if (e < EE) {
            int s = ei[e];
            int d = ei[EE + e];
            int pos = atomicAdd(&lr[d >> BSHIFT], 1);
            staging[pos] = make_int2(s | ((d & 255) << 17), __float_as_int(ea[e]));
        }
    }
}

// ---------------------------------------------------------------------------
// p2: one block per bucket. Count per-node into LDS; 256-wide scan seeded
// at bbase[bucket] -> writes off[]; place records via LDS cursors.
// ---------------------------------------------------------------------------
__global__ __launch_bounds__(256) void p2_kernel(const int2* __restrict__ staging,
                                                 const int* __restrict__ bbase,
                                                 int* __restrict__ off,
                                                 int2* __restrict__ epack)
{
    const int bucket = blockIdx.x;
    const int t      = threadIdx.x;
    const int n0     = bucket << BSHIFT;
    const int sb     = bbase[bucket];
    const int se     = bbase[bucket + 1];

    __shared__ int lcnt[256];
    __shared__ int lcur[256];
    __shared__ int wsum[4];
    lcnt[t] = 0;
    __syncthreads();

    for (int r = sb + t; r < se; r += 256)
        atomicAdd(&lcnt[(staging[r].x >> 17) & 255], 1);
    __syncthreads();

    int cnt  = lcnt[t];
    int lane = t & 63, w = t >> 6;
    int incl = cnt;
    for (int o = 1; o < 64; o <<= 1) {
        int v = __shfl_up(incl, o);
        if (lane >= o) incl += v;
    }
    if (lane == 63) wsum[w] = incl;
    __syncthreads();
    int wbase = 0;
#pragma unroll
    for (int i = 0; i < 4; ++i) if (i < w) wbase += wsum[i];
    int ov = sb + wbase + incl - cnt;     // exclusive offset for node n0+t

    int node = n0 + t;
    if (node <= NN) off[node] = ov;
    lcur[t] = ov;
    __syncthreads();

    for (int r = sb + t; r < se; r += 256) {
        int2 rec = staging[r];
        int dl = (rec.x >> 17) & 255;
        int pos = atomicAdd(&lcur[dl], 1);
        epack[pos] = make_int2(rec.x & 0x1FFFF, rec.y);
    }
}

// ---------------------------------------------------------------------------
// Attention: one wave per dst node; lane = es*8 + h (8 edges x 8 heads).
// Instruction diet: unguarded full steps + single predicated tail step;
// 32-bit byte-offset addressing; exact grid (no node guard).
// ---------------------------------------------------------------------------
__global__ __launch_bounds__(256) void attn_kernel(
    const float* __restrict__ Q, const unsigned int* __restrict__ KVb,
    const int* __restrict__ off, const int2* __restrict__ epack,
    const float* __restrict__ We, const float* __restrict__ be,
    float* __restrict__ out)
{
    const int lane = threadIdx.x & 63;
    const int node = blockIdx.x * 4 + (threadIdx.x >> 6);   // grid exact: < NN

    const int h  = lane & 7;    // head owned by this lane
    const int es = lane >> 3;   // edge slot 0..7

    // ---- hoist: fold Q, We, be, 1/sqrt(8) into per-d score coefficients ----
    float wq[8], bq[8];
    {
        const float4* qp = (const float4*)&Q[(size_t)node * D64 + h * 8];
        float4 q0 = qp[0], q1 = qp[1];
        const float4* wp = (const float4*)&We[h * 8];
        float4 w0 = wp[0], w1 = wp[1];
        const float4* bp = (const float4*)&be[h * 8];
        float4 b0 = bp[0], b1 = bp[1];
        const float rs = 0.35355339059327373f;
        float qs[8] = { q0.x, q0.y, q0.z, q0.w, q1.x, q1.y, q1.z, q1.w };
        float ws[8] = { w0.x, w0.y, w0.z, w0.w, w1.x, w1.y, w1.z, w1.w };
        float bs[8] = { b0.x, b0.y, b0.z, b0.w, b1.x, b1.y, b1.z, b1.w };
#pragma unroll
        for (int d = 0; d < 8; ++d) {
            float qr = qs[d] * rs;
            wq[d] = ws[d] * qr;
            bq[d] = bs[d] * qr;
        }
    }

    const int i0 = off[node];
    const int i1 = off[node + 1];

    float acc[8];
#pragma unroll
    for (int d = 0; d < 8; ++d) acc[d] = 0.f;
    float z = 0.f;

    int i = i0;
    // ---- full steps: no predication anywhere ----
#pragma unroll 2
    for (; i + 8 <= i1; i += 8) {
        int2 rec = epack[i + es];
        unsigned int bo = ((unsigned int)rec.x << 6) + (h << 3);
        float attr = __int_as_float(rec.y);

        uint4 wA = *(const uint4*)(KVb + bo);
        uint4 wB = *(const uint4*)(KVb + bo + 4);
        unsigned int wv[8] = { wA.x, wA.y, wA.z, wA.w, wB.x, wB.y, wB.z, wB.w };

        float tt = 0.f;
#pragma unroll
        for (int d = 0; d < 8; ++d) {
            float s  = fmaf(attr, wq[d], bq[d]);
            float kf = __uint_as_float(wv[d] & 0xFFFF0000u);
            tt = fmaf(kf, s, tt);
        }
        tt = fminf(fmaxf(tt, -5.f), 5.f);
        float sc = __expf(tt);

#pragma unroll
        for (int d = 0; d < 8; ++d) {
            float vf = __uint_as_float(wv[d] << 16);
            acc[d] = fmaf(vf, sc, acc[d]);
        }
        z += sc;
    }

    // ---- tail: one predicated step covers remaining 0..7 edges ----
    if (i < i1) {
        int  idx   = i + es;
        bool valid = idx < i1;
        int2 rec   = epack[valid ? idx : i0];
        unsigned int bo = ((unsigned int)rec.x << 6) + (h << 3);
        float attr = __int_as_float(rec.y);

        uint4 wA = *(const uint4*)(KVb + bo);
        uint4 wB = *(const uint4*)(KVb + bo + 4);
        unsigned int wv[8] = { wA.x, wA.y, wA.z, wA.w, wB.x, wB.y, wB.z, wB.w };

        float tt = 0.f;
#pragma unroll
        for (int d = 0; d < 8; ++d) {
            float s  = fmaf(attr, wq[d], bq[d]);
            float kf = __uint_as_float(wv[d] & 0xFFFF0000u);
            tt = fmaf(kf, s, tt);
        }
        tt = fminf(fmaxf(tt, -5.f), 5.f);
        float sc = __expf(tt);
        sc = valid ? sc : 0.f;

#pragma unroll
        for (int d = 0; d < 8; ++d) {
            float vf = __uint_as_float(wv[d] << 16);
            acc[d] = fmaf(vf, sc, acc[d]);
        }
        z += sc;
    }

    // ---- butterfly reduce across edge slots (lane bits 3..5) ----
#pragma unroll
    for (int m = 8; m <= 32; m <<= 1) {
#pragma unroll
        for (int d = 0; d < 8; ++d) acc[d] += __shfl_xor(acc[d], m);
        z += __shfl_xor(z, m);
    }

    // ---- lane writes out[node][h*8 + es] = acc[es] / (z + eps) ----
    float val = acc[0];
#pragma unroll
    for (int j = 1; j < 8; ++j)
        val = (es == j) ? acc[j] : val;

    out[(size_t)node * D64 + h * 8 + es] = val / (z + 1e-6f);
}

// ---------------------------------------------------------------------------
// Host launcher
// ---------------------------------------------------------------------------
static inline size_t align256(size_t v) { return (v + 255) & ~(size_t)255; }

extern "C" void kernel_launch(void* const* d_in, const int* in_sizes, int n_in,
                              void* d_out, int out_size, void* d_ws, size_t ws_size,
                              hipStream_t stream)
{
    const float* x  = (const float*)d_in[0];
    const float* ea = (const float*)d_in[1];
    const int*   ei = (const int*)  d_in[2];   // [2][EE]: row0=src, row1=dst
    const float* Wq = (const float*)d_in[3];
    const float* bq = (const float*)d_in[4];
    const float* Wk = (const float*)d_in[5];
    const float* bk = (const float*)d_in[6];
    const float* We = (const float*)d_in[7];
    const float* be = (const float*)d_in[8];
    const float* Wv = (const float*)d_in[9];
    const float* bv = (const float*)d_in[10];
    float* out = (float*)d_out;

    char* ws = (char*)d_ws;
    size_t o = 0;
    float*          Q       = (float*)(ws + o);          o += align256((size_t)NN * D64 * 4);
    unsigned int*   KVb     = (unsigned int*)(ws + o);   o += align256((size_t)NN * D64 * 4);
    int*            off     = (int*)(ws + o);            o += align256((size_t)(NN + 1) * 4);
    unsigned short* wt_hi   = (unsigned short*)(ws + o); o += align256((size_t)192 * 128 * 2);
    unsigned short* wt_lo   = (unsigned short*)(ws + o); o += align256((size_t)192 * 128 * 2);
    int*            hist    = (int*)(ws + o);            o += align256((size_t)NB_P1 * NBUCK * 4);
    int*            btot    = (int*)(ws + o);            o += align256((size_t)NBUCK * 4);
    int*            bbase   = (int*)(ws + o);            o += align256((size_t)(NBUCK + 1) * 4);
    int2*           staging = (int2*)(ws + o);           o += align256((size_t)EE * 8);
    int2*           epack   = (int2*)(ws + o);           o += align256((size_t)EE * 8);
    (void)ws_size; (void)out_size; (void)in_sizes; (void)n_in;

    wtrans_kernel<<<96, 256, 0, stream>>>(Wq, Wk, Wv, wt_hi, wt_lo);
    qkv_kernel<<<NN / 32, 256, 0, stream>>>(x, wt_hi, wt_lo, bq, bk, bv, Q, KVb);
    p1a_kernel<<<NB_P1, 256, 0, stream>>>(ei, hist);
    btot_kernel<<<NBUCK, 256, 0, stream>>>(hist, btot);
    bscan_kernel<<<1, 256, 0, stream>>>(btot, bbase);
    hscan_kernel<<<NBUCK, 256, 0, stream>>>(hist, bbase);
    p1b_kernel<<<NB_P1, 256, 0, stream>>>(ei, ea, hist, staging);
    p2_kernel<<<NBUCK, 256, 0, stream>>>(staging, bbase, off, epack);
    attn_kernel<<<NN / 4, 256, 0, stream>>>(Q, KVb, off, epack, We, be, out);
}

// Round 13
// 167.145 us; speedup vs baseline: 8.4650x; 1.0424x over previous
//
#include <hip/hip_runtime.h>
#include <math.h>

#define NN 100000
#define EE 1600000
#define IND 128
#define D64 64    // HEADS*OUT_DIM

#define BSHIFT 8          // bucket = dst >> 8 (256 nodes per bucket)
#define NBUCK 391         // ceil(NN / 256)
#define P1_TILE 3072
#define NB_P1 521         // ceil(EE / P1_TILE)

typedef __attribute__((ext_vector_type(8))) short  short8;
typedef __attribute__((ext_vector_type(4))) float  f32x4;

// ---------------------------------------------------------------------------
// wtrans: one-shot transpose+split of [Wq|Wk|Wv] (128x192 fp32) into
// wt_hi/wt_lo [col 0..191][k 0..127] bf16 (Markidis hi/lo split).
// ---------------------------------------------------------------------------
__device__ __forceinline__ unsigned short bf16_rne(float v) {
    unsigned int u = __float_as_uint(v);
    return (unsigned short)((u + 0x7FFFu + ((u >> 16) & 1u)) >> 16);
}

__global__ __launch_bounds__(256) void wtrans_kernel(
    const float* __restrict__ Wq, const float* __restrict__ Wk,
    const float* __restrict__ Wv,
    unsigned short* __restrict__ wt_hi, unsigned short* __restrict__ wt_lo)
{
    int idx = blockIdx.x * 256 + threadIdx.x;     // 0..24575
    if (idx >= 192 * 128) return;
    int col = idx >> 7, k = idx & 127;
    const float* W = (col < 64) ? Wq : (col < 128) ? Wk : Wv;
    float v = W[(size_t)k * D64 + (col & 63)];
    unsigned short h = bf16_rne(v);
    float hf = __uint_as_float((unsigned int)h << 16);
    unsigned short l = bf16_rne(v - hf);
    wt_hi[idx] = h;
    wt_lo[idx] = l;
}

// ---------------------------------------------------------------------------
// qkv v3: BM=32 (grid 3125, exact), LDS 16.9KB, B-frags STREAMED per kt
// from L2 (low VGPR -> high occupancy). 2-term Markidis split.
// Q written fp32; K/V packed bf16 into KVb: uint = (K<<16)|V.
// ---------------------------------------------------------------------------
#define XP 132   // padded k-stride (ushort) for LDS x tiles

__global__ __launch_bounds__(256) void qkv_kernel(
    const float* __restrict__ x,
    const unsigned short* __restrict__ wt_hi,
    const unsigned short* __restrict__ wt_lo,
    const float* __restrict__ bq, const float* __restrict__ bk,
    const float* __restrict__ bv,
    float* __restrict__ Qo, unsigned int* __restrict__ KVb)
{
    __shared__ unsigned short xhi[32 * XP];   // 8448 B
    __shared__ unsigned short xlo[32 * XP];   // 8448 B

    const int t    = threadIdx.x;
    const int wave = t >> 6;
    const int lane = t & 63;
    const int nb   = blockIdx.x * 32;        // 3125 * 32 = 100000 exact

    // ---- stage x tile 32x128 fp32 -> hi/lo bf16 in LDS (16 floats/thread) ----
    {
        const int row = t >> 3;          // 0..31
        const int c   = t & 7;           // 16-float chunk
        const float* xr = x + (size_t)(nb + row) * IND + c * 16;
        float4 a0 = *(const float4*)(xr);
        float4 a1 = *(const float4*)(xr + 4);
        float4 a2 = *(const float4*)(xr + 8);
        float4 a3 = *(const float4*)(xr + 12);
        float vs[16] = { a0.x, a0.y, a0.z, a0.w, a1.x, a1.y, a1.z, a1.w,
                         a2.x, a2.y, a2.z, a2.w, a3.x, a3.y, a3.z, a3.w };
        short8 h0, h1, l0, l1;
#pragma unroll
        for (int j = 0; j < 8; ++j) {
            unsigned short hb = bf16_rne(vs[j]);
            float hf = __uint_as_float((unsigned int)hb << 16);
            h0[j] = (short)hb;
            l0[j] = (short)bf16_rne(vs[j] - hf);
        }
#pragma unroll
        for (int j = 0; j < 8; ++j) {
            unsigned short hb = bf16_rne(vs[8 + j]);
            float hf = __uint_as_float((unsigned int)hb << 16);
            h1[j] = (short)hb;
            l1[j] = (short)bf16_rne(vs[8 + j] - hf);
        }
        int o0 = row * XP + c * 16;
        *(short8*)&xhi[o0]     = h0;
        *(short8*)&xhi[o0 + 8] = h1;
        *(short8*)&xlo[o0]     = l0;
        *(short8*)&xlo[o0 + 8] = l1;
    }
    __syncthreads();

    const int wcol0 = wave * 48;

    f32x4 acc[2][3];
#pragma unroll
    for (int rt = 0; rt < 2; ++rt)
#pragma unroll
        for (int ct = 0; ct < 3; ++ct)
            acc[rt][ct] = (f32x4){0.f, 0.f, 0.f, 0.f};

#pragma unroll
    for (int kt = 0; kt < 4; ++kt) {
        // stream B-fragments for this kt (L2-hot, 6 x dwordx4)
        short8 bh[3], bl[3];
#pragma unroll
        for (int ct = 0; ct < 3; ++ct) {
            int col = wcol0 + ct * 16 + (lane & 15);
            int a = col * 128 + kt * 32 + (lane >> 4) * 8;
            bh[ct] = *(const short8*)&wt_hi[a];
            bl[ct] = *(const short8*)&wt_lo[a];
        }
        // A-fragments from LDS (4 x ds_read_b128)
        short8 ah[2], al[2];
#pragma unroll
        for (int rt = 0; rt < 2; ++rt) {
            int o2 = (rt * 16 + (lane & 15)) * XP + kt * 32 + (lane >> 4) * 8;
            ah[rt] = *(const short8*)&xhi[o2];
            al[rt] = *(const short8*)&xlo[o2];
        }
#pragma unroll
        for (int rt = 0; rt < 2; ++rt) {
#pragma unroll
            for (int ct = 0; ct < 3; ++ct) {
                acc[rt][ct] = __builtin_amdgcn_mfma_f32_16x16x32_bf16(
                    ah[rt], bh[ct], acc[rt][ct], 0, 0, 0);
                acc[rt][ct] = __builtin_amdgcn_mfma_f32_16x16x32_bf16(
                    ah[rt], bl[ct], acc[rt][ct], 0, 0, 0);
                acc[rt][ct] = __builtin_amdgcn_mfma_f32_16x16x32_bf16(
                    al[rt], bh[ct], acc[rt][ct], 0, 0, 0);
            }
        }
    }

    // ---- epilogue: bias + store. Q fp32; K -> hi ushort, V -> lo ushort ----
#pragma unroll
    for (int ct = 0; ct < 3; ++ct) {
        int colbase = wcol0 + ct * 16;
        int m  = colbase >> 6;                 // wave-uniform: 0=Q,1=K,2=V
        int lc = (colbase & 63) + (lane & 15);
        const float* bp = (m == 0) ? bq : (m == 1) ? bk : bv;
        float bias = bp[lc];
#pragma unroll
        for (int rt = 0; rt < 2; ++rt) {
#pragma unroll
            for (int reg = 0; reg < 4; ++reg) {
                int node = nb + rt * 16 + (lane >> 4) * 4 + reg;
                float val = acc[rt][ct][reg] + bias;
                size_t idx = (size_t)node * D64 + lc;
                if (m == 0) {
                    Qo[idx] = val;
                } else {
                    // little-endian: ushort[0]=lo(V), ushort[1]=hi(K)
                    ((unsigned short*)KVb)[idx * 2 + (m == 1 ? 1 : 0)] = bf16_rne(val);
                }
            }
        }
    }
}

// ---------------------------------------------------------------------------
// p1a: per-block bucket histogram (LDS atomics). 3072 edges per block.
// ---------------------------------------------------------------------------
__global__ __launch_bounds__(256) void p1a_kernel(const int* __restrict__ ei,
                                                  int* __restrict__ hist)
{
    __shared__ int lh[NBUCK];
    const int t = threadIdx.x;
    for (int b = t; b < NBUCK; b += 256) lh[b] = 0;
    __syncthreads();

    const int e0 = blockIdx.x * P1_TILE;
#pragma unroll
    for (int j = 0; j < 12; ++j) {
        int e = e0 + j * 256 + t;
        if (e < EE) {
            int d = ei[EE + e];
            atomicAdd(&lh[d >> BSHIFT], 1);
        }
    }
    __syncthreads();
    for (int b = t; b < NBUCK; b += 256)
        hist[blockIdx.x * NBUCK + b] = lh[b];
}

// ---------------------------------------------------------------------------
// hscanA: block b = bucket b. UNSEEDED exclusive scan of hist column down
// the block dimension (in place) + emits btot[b] (merged old btot+hscan).
// ---------------------------------------------------------------------------
__global__ __launch_bounds__(256) void hscanA_kernel(int* __restrict__ hist,
                                                     int* __restrict__ btot)
{
    const int b = blockIdx.x;
    const int t = threadIdx.x;
    int L[3]; int s = 0;
#pragma unroll
    for (int j = 0; j < 3; ++j) {
        int blk = t * 3 + j;
        L[j] = (blk < NB_P1) ? hist[blk * NBUCK + b] : 0;
        s += L[j];
    }
    int lane = t & 63, w = t >> 6;
    int incl = s;
    for (int o = 1; o < 64; o <<= 1) {
        int v = __shfl_up(incl, o);
        if (lane >= o) incl += v;
    }
    __shared__ int wsum[4];
    if (lane == 63) wsum[w] = incl;
    __syncthreads();
    int wbase = 0;
#pragma unroll
    for (int i = 0; i < 4; ++i) if (i < w) wbase += wsum[i];
    int run = wbase + incl - s;          // unseeded exclusive offset
#pragma unroll
    for (int j = 0; j < 3; ++j) {
        int blk = t * 3 + j;
        if (blk < NB_P1) hist[blk * NBUCK + b] = run;
        run += L[j];
    }
    if (t == 0) btot[b] = wsum[0] + wsum[1] + wsum[2] + wsum[3];
}

// ---------------------------------------------------------------------------
// bscan: exclusive scan of 391 bucket totals -> bbase[0..391].
// ---------------------------------------------------------------------------
__global__ __launch_bounds__(256) void bscan_kernel(const int* __restrict__ btot,
                                                    int* __restrict__ bbase)
{
    const int t = threadIdx.x;
    int i0 = 2 * t, i1 = 2 * t + 1;
    int v0 = (i0 < NBUCK) ? btot[i0] : 0;
    int v1 = (i1 < NBUCK) ? btot[i1] : 0;
    int s = v0 + v1;
    int lane = t & 63, w = t >> 6;
    int incl = s;
    for (int o = 1; o < 64; o <<= 1) {
        int v = __shfl_up(incl, o);
        if (lane >= o) incl += v;
    }
    __shared__ int wsum[4];
    if (lane == 63) wsum[w] = incl;
    __syncthreads();
    int wbase = 0;
#pragma unroll
    for (int i = 0; i < 4; ++i) if (i < w) wbase += wsum[i];
    int excl = wbase + incl - s;
    if (i0 <= NBUCK) bbase[i0] = excl;
    if (i1 <= NBUCK) bbase[i1] = excl + v0;
}

// ---------------------------------------------------------------------------
// p1b: re-read edge tile, LDS-atomic rank within (block,bucket), write
// staging record at exact cursor (bbase seed folded into LDS init).
// Record = { src | dstlocal<<17, attr }. Zero global atomics.
// ---------------------------------------------------------------------------
__global__ __launch_bounds__(256) void p1b_kernel(const int* __restrict__ ei,
                                                  const float* __restrict__ ea,
                                                  const int* __restrict__ hist,
                                                  const int* __restrict__ bbase,
                                                  int2* __restrict__ staging)
{
    __shared__ int lr[NBUCK];
    const int t = threadIdx.x;
    for (int b = t; b < NBUCK; b += 256)
        lr[b] = hist[blockIdx.x * NBUCK + b] + bbase[b];
    __syncthreads();

    const int e0 = blockIdx.x * P1_TILE;
#pragma unroll
    for (int j = 0; j < 12; ++j) {
        int e = e0 + j * 256 + t;
        if (e < EE) {
            int s = ei[e];
            int d = ei[EE + e];
            int pos = atomicAdd(&lr[d >> BSHIFT], 1);
            staging[pos] = make_int2(s | ((d & 255) << 17), __float_as_int(ea[e]));
        }
    }
}

// ---------------------------------------------------------------------------
// p2: one block per bucket. Count per-node into LDS; 256-wide scan seeded
// at bbase[bucket] -> writes off[]; place records via LDS cursors.
// ---------------------------------------------------------------------------
__global__ __launch_bounds__(256) void p2_kernel(const int2* __restrict__ staging,
                                                 const int* __restrict__ bbase,
                                                 int* __restrict__ off,
                                                 int2* __restrict__ epack)
{
    const int bucket = blockIdx.x;
    const int t      = threadIdx.x;
    const int n0     = bucket << BSHIFT;
    const int sb     = bbase[bucket];
    const int se     = bbase[bucket + 1];

    __shared__ int lcnt[256];
    __shared__ int lcur[256];
    __shared__ int wsum[4];
    lcnt[t] = 0;
    __syncthreads();

    for (int r = sb + t; r < se; r += 256)
        atomicAdd(&lcnt[(staging[r].x >> 17) & 255], 1);
    __syncthreads();

    int cnt  = lcnt[t];
    int lane = t & 63, w = t >> 6;
    int incl = cnt;
    for (int o = 1; o < 64; o <<= 1) {
        int v = __shfl_up(incl, o);
        if (lane >= o) incl += v;
    }
    if (lane == 63) wsum[w] = incl;
    __syncthreads();
    int wbase = 0;
#pragma unroll
    for (int i = 0; i < 4; ++i) if (i < w) wbase += wsum[i];
    int ov = sb + wbase + incl - cnt;     // exclusive offset for node n0+t

    int node = n0 + t;
    if (node <= NN) off[node] = ov;
    lcur[t] = ov;
    __syncthreads();

    for (int r = sb + t; r < se; r += 256) {
        int2 rec = staging[r];
        int dl = (rec.x >> 17) & 255;
        int pos = atomicAdd(&lcur[dl], 1);
        epack[pos] = make_int2(rec.x & 0x1FFFF, rec.y);
    }
}

// ---------------------------------------------------------------------------
// Attention: one wave per dst node; lane = es*8 + h (8 edges x 8 heads).
// Unguarded full steps + one predicated tail; 32-bit byte addressing.
// ---------------------------------------------------------------------------
__global__ __launch_bounds__(256) void attn_kernel(
    const float* __restrict__ Q, const unsigned int* __restrict__ KVb,
    const int* __restrict__ off, const int2* __restrict__ epack,
    const float* __restrict__ We, const float* __restrict__ be,
    float* __restrict__ out)
{
    const int lane = threadIdx.x & 63;
    const int node = blockIdx.x * 4 + (threadIdx.x >> 6);   // grid exact: < NN

    const int h  = lane & 7;    // head owned by this lane
    const int es = lane >> 3;   // edge slot 0..7

    // ---- hoist: fold Q, We, be, 1/sqrt(8) into per-d score coefficients ----
    float wq[8], bq[8];
    {
        const float4* qp = (const float4*)&Q[(size_t)node * D64 + h * 8];
        float4 q0 = qp[0], q1 = qp[1];
        const float4* wp = (const float4*)&We[h * 8];
        float4 w0 = wp[0], w1 = wp[1];
        const float4* bp = (const float4*)&be[h * 8];
        float4 b0 = bp[0], b1 = bp[1];
        const float rs = 0.35355339059327373f;
        float qs[8] = { q0.x, q0.y, q0.z, q0.w, q1.x, q1.y, q1.z, q1.w };
        float ws[8] = { w0.x, w0.y, w0.z, w0.w, w1.x, w1.y, w1.z, w1.w };
        float bs[8] = { b0.x, b0.y, b0.z, b0.w, b1.x, b1.y, b1.z, b1.w };
#pragma unroll
        for (int d = 0; d < 8; ++d) {
            float qr = qs[d] * rs;
            wq[d] = ws[d] * qr;
            bq[d] = bs[d] * qr;
        }
    }

    const int i0 = off[node];
    const int i1 = off[node + 1];

    float acc[8];
#pragma unroll
    for (int d = 0; d < 8; ++d) acc[d] = 0.f;
    float z = 0.f;

    int i = i0;
    // ---- full steps: no predication anywhere ----
#pragma unroll 2
    for (; i + 8 <= i1; i += 8) {
        int2 rec = epack[i + es];
        unsigned int bo = ((unsigned int)rec.x << 6) + (h << 3);
        float attr = __int_as_float(rec.y);

        uint4 wA = *(const uint4*)(KVb + bo);
        uint4 wB = *(const uint4*)(KVb + bo + 4);
        unsigned int wv[8] = { wA.x, wA.y, wA.z, wA.w, wB.x, wB.y, wB.z, wB.w };

        float tt = 0.f;
#pragma unroll
        for (int d = 0; d < 8; ++d) {
            float s  = fmaf(attr, wq[d], bq[d]);
            float kf = __uint_as_float(wv[d] & 0xFFFF0000u);
            tt = fmaf(kf, s, tt);
        }
        tt = fminf(fmaxf(tt, -5.f), 5.f);
        float sc = __expf(tt);

#pragma unroll
        for (int d = 0; d < 8; ++d) {
            float vf = __uint_as_float(wv[d] << 16);
            acc[d] = fmaf(vf, sc, acc[d]);
        }
        z += sc;
    }

    // ---- tail: one predicated step covers remaining 0..7 edges ----
    if (i < i1) {
        int  idx   = i + es;
        bool valid = idx < i1;
        int2 rec   = epack[valid ? idx : i0];
        unsigned int bo = ((unsigned int)rec.x << 6) + (h << 3);
        float attr = __int_as_float(rec.y);

        uint4 wA = *(const uint4*)(KVb + bo);
        uint4 wB = *(const uint4*)(KVb + bo + 4);
        unsigned int wv[8] = { wA.x, wA.y, wA.z, wA.w, wB.x, wB.y, wB.z, wB.w };

        float tt = 0.f;
#pragma unroll
        for (int d = 0; d < 8; ++d) {
            float s  = fmaf(attr, wq[d], bq[d]);
            float kf = __uint_as_float(wv[d] & 0xFFFF0000u);
            tt = fmaf(kf, s, tt);
        }
        tt = fminf(fmaxf(tt, -5.f), 5.f);
        float sc = __expf(tt);
        sc = valid ? sc : 0.f;

#pragma unroll
        for (int d = 0; d < 8; ++d) {
            float vf = __uint_as_float(wv[d] << 16);
            acc[d] = fmaf(vf, sc, acc[d]);
        }
        z += sc;
    }

    // ---- butterfly reduce across edge slots (lane bits 3..5) ----
#pragma unroll
    for (int m = 8; m <= 32; m <<= 1) {
#pragma unroll
        for (int d = 0; d < 8; ++d) acc[d] += __shfl_xor(acc[d], m);
        z += __shfl_xor(z, m);
    }

    // ---- lane writes out[node][h*8 + es] = acc[es] / (z + eps) ----
    float val = acc[0];
#pragma unroll
    for (int j = 1; j < 8; ++j)
        val = (es == j) ? acc[j] : val;

    out[(size_t)node * D64 + h * 8 + es] = val / (z + 1e-6f);
}

// ---------------------------------------------------------------------------
// Host launcher
// ---------------------------------------------------------------------------
static inline size_t align256(size_t v) { return (v + 255) & ~(size_t)255; }

extern "C" void kernel_launch(void* const* d_in, const int* in_sizes, int n_in,
                              void* d_out, int out_size, void* d_ws, size_t ws_size,
                              hipStream_t stream)
{
    const float* x  = (const float*)d_in[0];
    const float* ea = (const float*)d_in[1];
    const int*   ei = (const int*)  d_in[2];   // [2][EE]: row0=src, row1=dst
    const float* Wq = (const float*)d_in[3];
    const float* bq = (const float*)d_in[4];
    const float* Wk = (const float*)d_in[5];
    const float* bk = (const float*)d_in[6];
    const float* We = (const float*)d_in[7];
    const float* be = (const float*)d_in[8];
    const float* Wv = (const float*)d_in[9];
    const float* bv = (const float*)d_in[10];
    float* out = (float*)d_out;

    char* ws = (char*)d_ws;
    size_t o = 0;
    float*          Q       = (float*)(ws + o);          o += align256((size_t)NN * D64 * 4);
    unsigned int*   KVb     = (unsigned int*)(ws + o);   o += align256((size_t)NN * D64 * 4);
    int*            off     = (int*)(ws + o);            o += align256((size_t)(NN + 1) * 4);
    unsigned short* wt_hi   = (unsigned short*)(ws + o); o += align256((size_t)192 * 128 * 2);
    unsigned short* wt_lo   = (unsigned short*)(ws + o); o += align256((size_t)192 * 128 * 2);
    int*            hist    = (int*)(ws + o);            o += align256((size_t)NB_P1 * NBUCK * 4);
    int*            btot    = (int*)(ws + o);            o += align256((size_t)NBUCK * 4);
    int*            bbase   = (int*)(ws + o);            o += align256((size_t)(NBUCK + 1) * 4);
    int2*           staging = (int2*)(ws + o);           o += align256((size_t)EE * 8);
    int2*           epack   = (int2*)(ws + o);           o += align256((size_t)EE * 8);
    (void)ws_size; (void)out_size; (void)in_sizes; (void)n_in;

    wtrans_kernel<<<96, 256, 0, stream>>>(Wq, Wk, Wv, wt_hi, wt_lo);
    qkv_kernel<<<NN / 32, 256, 0, stream>>>(x, wt_hi, wt_lo, bq, bk, bv, Q, KVb);
    p1a_kernel<<<NB_P1, 256, 0, stream>>>(ei, hist);
    hscanA_kernel<<<NBUCK, 256, 0, stream>>>(hist, btot);
    bscan_kernel<<<1, 256, 0, stream>>>(btot, bbase);
    p1b_kernel<<<NB_P1, 256, 0, stream>>>(ei, ea, hist, bbase, staging);
    p2_kernel<<<NBUCK, 256, 0, stream>>>(staging, bbase, off, epack);
    attn_kernel<<<NN / 4, 256, 0, stream>>>(Q, KVb, off, epack, We, be, out);
}

// Round 14
// 156.129 us; speedup vs baseline: 9.0623x; 1.0706x over previous
//
#include <hip/hip_runtime.h>
#include <math.h>

#define NN 100000
#define EE 1600000
#define IND 128
#define D64 64    // HEADS*OUT_DIM

#define BSHIFT 8          // bucket = dst >> 8 (256 nodes per bucket)
#define NBUCK 391         // ceil(NN / 256)
#define P1_TILE 3072
#define NB_P1 521         // ceil(EE / P1_TILE)

#define QKV_BLOCKS 3125   // NN / 32
#define WT_BLOCKS 96

typedef __attribute__((ext_vector_type(8))) short  short8;
typedef __attribute__((ext_vector_type(4))) float  f32x4;

__device__ __forceinline__ unsigned short bf16_rne(float v) {
    unsigned int u = __float_as_uint(v);
    return (unsigned short)((u + 0x7FFFu + ((u >> 16) & 1u)) >> 16);
}

// ---------------------------------------------------------------------------
// fusedA: blocks [0,96) = wtrans (transpose+split W into wt_hi/wt_lo);
//         blocks [96, 96+521) = p1a (per-block bucket histogram).
// Independent workloads, one dispatch.
// ---------------------------------------------------------------------------
__global__ __launch_bounds__(256) void fusedA_kernel(
    const float* __restrict__ Wq, const float* __restrict__ Wk,
    const float* __restrict__ Wv,
    unsigned short* __restrict__ wt_hi, unsigned short* __restrict__ wt_lo,
    const int* __restrict__ ei, int* __restrict__ hist)
{
    __shared__ int lh[NBUCK];
    const int t = threadIdx.x;

    if (blockIdx.x < WT_BLOCKS) {
        // ---- wtrans body ----
        int idx = blockIdx.x * 256 + t;           // 0..24575 == 192*128
        int col = idx >> 7, k = idx & 127;
        const float* W = (col < 64) ? Wq : (col < 128) ? Wk : Wv;
        float v = W[(size_t)k * D64 + (col & 63)];
        unsigned short h = bf16_rne(v);
        float hf = __uint_as_float((unsigned int)h << 16);
        unsigned short l = bf16_rne(v - hf);
        wt_hi[idx] = h;
        wt_lo[idx] = l;
        return;
    }

    // ---- p1a body ----
    const int pb = blockIdx.x - WT_BLOCKS;
    for (int b = t; b < NBUCK; b += 256) lh[b] = 0;
    __syncthreads();

    const int e0 = pb * P1_TILE;
#pragma unroll
    for (int j = 0; j < 12; ++j) {
        int e = e0 + j * 256 + t;
        if (e < EE) {
            int d = ei[EE + e];
            atomicAdd(&lh[d >> BSHIFT], 1);
        }
    }
    __syncthreads();
    for (int b = t; b < NBUCK; b += 256)
        hist[pb * NBUCK + b] = lh[b];
}

// ---------------------------------------------------------------------------
// hscanA: block b = bucket b. UNSEEDED exclusive scan of hist column down
// the block dimension (in place) + emits btot[b].
// ---------------------------------------------------------------------------
__global__ __launch_bounds__(256) void hscanA_kernel(int* __restrict__ hist,
                                                     int* __restrict__ btot)
{
    const int b = blockIdx.x;
    const int t = threadIdx.x;
    int L[3]; int s = 0;
#pragma unroll
    for (int j = 0; j < 3; ++j) {
        int blk = t * 3 + j;
        L[j] = (blk < NB_P1) ? hist[blk * NBUCK + b] : 0;
        s += L[j];
    }
    int lane = t & 63, w = t >> 6;
    int incl = s;
    for (int o = 1; o < 64; o <<= 1) {
        int v = __shfl_up(incl, o);
        if (lane >= o) incl += v;
    }
    __shared__ int wsum[4];
    if (lane == 63) wsum[w] = incl;
    __syncthreads();
    int wbase = 0;
#pragma unroll
    for (int i = 0; i < 4; ++i) if (i < w) wbase += wsum[i];
    int run = wbase + incl - s;          // unseeded exclusive offset
#pragma unroll
    for (int j = 0; j < 3; ++j) {
        int blk = t * 3 + j;
        if (blk < NB_P1) hist[blk * NBUCK + b] = run;
        run += L[j];
    }
    if (t == 0) btot[b] = wsum[0] + wsum[1] + wsum[2] + wsum[3];
}

// ---------------------------------------------------------------------------
// bscan: exclusive scan of 391 bucket totals -> bbase[0..391].
// ---------------------------------------------------------------------------
__global__ __launch_bounds__(256) void bscan_kernel(const int* __restrict__ btot,
                                                    int* __restrict__ bbase)
{
    const int t = threadIdx.x;
    int i0 = 2 * t, i1 = 2 * t + 1;
    int v0 = (i0 < NBUCK) ? btot[i0] : 0;
    int v1 = (i1 < NBUCK) ? btot[i1] : 0;
    int s = v0 + v1;
    int lane = t & 63, w = t >> 6;
    int incl = s;
    for (int o = 1; o < 64; o <<= 1) {
        int v = __shfl_up(incl, o);
        if (lane >= o) incl += v;
    }
    __shared__ int wsum[4];
    if (lane == 63) wsum[w] = incl;
    __syncthreads();
    int wbase = 0;
#pragma unroll
    for (int i = 0; i < 4; ++i) if (i < w) wbase += wsum[i];
    int excl = wbase + incl - s;
    if (i0 <= NBUCK) bbase[i0] = excl;
    if (i1 <= NBUCK) bbase[i1] = excl + v0;
}

// ---------------------------------------------------------------------------
// fusedB: blocks [0,3125) = qkv (MFMA projection); blocks [3125,3646) = p1b
// (scatter into bucketed staging). qkv depends only on wtrans; p1b on
// hist/bbase — both ready. p1b hides under qkv. LDS union.
// ---------------------------------------------------------------------------
#define XP 132   // padded k-stride (ushort) for LDS x tiles

__global__ __launch_bounds__(256) void fusedB_kernel(
    const float* __restrict__ x,
    const unsigned short* __restrict__ wt_hi,
    const unsigned short* __restrict__ wt_lo,
    const float* __restrict__ bq, const float* __restrict__ bk,
    const float* __restrict__ bv,
    float* __restrict__ Qo, unsigned int* __restrict__ KVb,
    const int* __restrict__ ei, const float* __restrict__ ea,
    const int* __restrict__ hist, const int* __restrict__ bbase,
    int2* __restrict__ staging)
{
    __shared__ __align__(16) char smem[2 * 32 * XP * 2];   // 16896 B union

    const int t = threadIdx.x;

    if (blockIdx.x >= QKV_BLOCKS) {
        // ---- p1b body ----
        int* lr = (int*)smem;
        const int pb = blockIdx.x - QKV_BLOCKS;
        for (int b = t; b < NBUCK; b += 256)
            lr[b] = hist[pb * NBUCK + b] + bbase[b];
        __syncthreads();

        const int e0 = pb * P1_TILE;
#pragma unroll
        for (int j = 0; j < 12; ++j) {
            int e = e0 + j * 256 + t;
            if (e < EE) {
                int s = ei[e];
                int d = ei[EE + e];
                int pos = atomicAdd(&lr[d >> BSHIFT], 1);
                staging[pos] = make_int2(s | ((d & 255) << 17), __float_as_int(ea[e]));
            }
        }
        return;
    }

    // ---- qkv body ----
    unsigned short* xhi = (unsigned short*)smem;             // 32*XP ushorts
    unsigned short* xlo = (unsigned short*)(smem + 32 * XP * 2);

    const int wave = t >> 6;
    const int lane = t & 63;
    const int nb   = blockIdx.x * 32;        // 3125 * 32 = 100000 exact

    // stage x tile 32x128 fp32 -> hi/lo bf16 in LDS (16 floats/thread)
    {
        const int row = t >> 3;          // 0..31
        const int c   = t & 7;           // 16-float chunk
        const float* xr = x + (size_t)(nb + row) * IND + c * 16;
        float4 a0 = *(const float4*)(xr);
        float4 a1 = *(const float4*)(xr + 4);
        float4 a2 = *(const float4*)(xr + 8);
        float4 a3 = *(const float4*)(xr + 12);
        float vs[16] = { a0.x, a0.y, a0.z, a0.w, a1.x, a1.y, a1.z, a1.w,
                         a2.x, a2.y, a2.z, a2.w, a3.x, a3.y, a3.z, a3.w };
        short8 h0, h1, l0, l1;
#pragma unroll
        for (int j = 0; j < 8; ++j) {
            unsigned short hb = bf16_rne(vs[j]);
            float hf = __uint_as_float((unsigned int)hb << 16);
            h0[j] = (short)hb;
            l0[j] = (short)bf16_rne(vs[j] - hf);
        }
#pragma unroll
        for (int j = 0; j < 8; ++j) {
            unsigned short hb = bf16_rne(vs[8 + j]);
            float hf = __uint_as_float((unsigned int)hb << 16);
            h1[j] = (short)hb;
            l1[j] = (short)bf16_rne(vs[8 + j] - hf);
        }
        int o0 = row * XP + c * 16;
        *(short8*)&xhi[o0]     = h0;
        *(short8*)&xhi[o0 + 8] = h1;
        *(short8*)&xlo[o0]     = l0;
        *(short8*)&xlo[o0 + 8] = l1;
    }
    __syncthreads();

    const int wcol0 = wave * 48;

    f32x4 acc[2][3];
#pragma unroll
    for (int rt = 0; rt < 2; ++rt)
#pragma unroll
        for (int ct = 0; ct < 3; ++ct)
            acc[rt][ct] = (f32x4){0.f, 0.f, 0.f, 0.f};

#pragma unroll
    for (int kt = 0; kt < 4; ++kt) {
        short8 bh[3], bl[3];
#pragma unroll
        for (int ct = 0; ct < 3; ++ct) {
            int col = wcol0 + ct * 16 + (lane & 15);
            int a = col * 128 + kt * 32 + (lane >> 4) * 8;
            bh[ct] = *(const short8*)&wt_hi[a];
            bl[ct] = *(const short8*)&wt_lo[a];
        }
        short8 ah[2], al[2];
#pragma unroll
        for (int rt = 0; rt < 2; ++rt) {
            int o2 = (rt * 16 + (lane & 15)) * XP + kt * 32 + (lane >> 4) * 8;
            ah[rt] = *(const short8*)&xhi[o2];
            al[rt] = *(const short8*)&xlo[o2];
        }
#pragma unroll
        for (int rt = 0; rt < 2; ++rt) {
#pragma unroll
            for (int ct = 0; ct < 3; ++ct) {
                acc[rt][ct] = __builtin_amdgcn_mfma_f32_16x16x32_bf16(
                    ah[rt], bh[ct], acc[rt][ct], 0, 0, 0);
                acc[rt][ct] = __builtin_amdgcn_mfma_f32_16x16x32_bf16(
                    ah[rt], bl[ct], acc[rt][ct], 0, 0, 0);
                acc[rt][ct] = __builtin_amdgcn_mfma_f32_16x16x32_bf16(
                    al[rt], bh[ct], acc[rt][ct], 0, 0, 0);
            }
        }
    }

    // epilogue: bias + store. Q fp32; K -> hi ushort, V -> lo ushort
#pragma unroll
    for (int ct = 0; ct < 3; ++ct) {
        int colbase = wcol0 + ct * 16;
        int m  = colbase >> 6;                 // wave-uniform: 0=Q,1=K,2=V
        int lc = (colbase & 63) + (lane & 15);
        const float* bp = (m == 0) ? bq : (m == 1) ? bk : bv;
        float bias = bp[lc];
#pragma unroll
        for (int rt = 0; rt < 2; ++rt) {
#pragma unroll
            for (int reg = 0; reg < 4; ++reg) {
                int node = nb + rt * 16 + (lane >> 4) * 4 + reg;
                float val = acc[rt][ct][reg] + bias;
                size_t idx = (size_t)node * D64 + lc;
                if (m == 0) {
                    Qo[idx] = val;
                } else {
                    // little-endian: ushort[0]=lo(V), ushort[1]=hi(K)
                    ((unsigned short*)KVb)[idx * 2 + (m == 1 ? 1 : 0)] = bf16_rne(val);
                }
            }
        }
    }
}

// ---------------------------------------------------------------------------
// p2: one block per bucket. Count per-node into LDS; 256-wide scan seeded
// at bbase[bucket] -> writes off[]; place records via LDS cursors.
// ---------------------------------------------------------------------------
__global__ __launch_bounds__(256) void p2_kernel(const int2* __restrict__ staging,
                                                 const int* __restrict__ bbase,
                                                 int* __restrict__ off,
                                                 int2* __restrict__ epack)
{
    const int bucket = blockIdx.x;
    const int t      = threadIdx.x;
    const int n0     = bucket << BSHIFT;
    const int sb     = bbase[bucket];
    const int se     = bbase[bucket + 1];

    __shared__ int lcnt[256];
    __shared__ int lcur[256];
    __shared__ int wsum[4];
    lcnt[t] = 0;
    __syncthreads();

    for (int r = sb + t; r < se; r += 256)
        atomicAdd(&lcnt[(staging[r].x >> 17) & 255], 1);
    __syncthreads();

    int cnt  = lcnt[t];
    int lane = t & 63, w = t >> 6;
    int incl = cnt;
    for (int o = 1; o < 64; o <<= 1) {
        int v = __shfl_up(incl, o);
        if (lane >= o) incl += v;
    }
    if (lane == 63) wsum[w] = incl;
    __syncthreads();
    int wbase = 0;
#pragma unroll
    for (int i = 0; i < 4; ++i) if (i < w) wbase += wsum[i];
    int ov = sb + wbase + incl - cnt;     // exclusive offset for node n0+t

    int node = n0 + t;
    if (node <= NN) off[node] = ov;
    lcur[t] = ov;
    __syncthreads();

    for (int r = sb + t; r < se; r += 256) {
        int2 rec = staging[r];
        int dl = (rec.x >> 17) & 255;
        int pos = atomicAdd(&lcur[dl], 1);
        epack[pos] = make_int2(rec.x & 0x1FFFF, rec.y);
    }
}

// ---------------------------------------------------------------------------
// Attention: one wave per dst node; lane = es*8 + h (8 edges x 8 heads).
// Unguarded full steps + one predicated tail; 32-bit byte addressing.
// ---------------------------------------------------------------------------
__global__ __launch_bounds__(256) void attn_kernel(
    const float* __restrict__ Q, const unsigned int* __restrict__ KVb,
    const int* __restrict__ off, const int2* __restrict__ epack,
    const float* __restrict__ We, const float* __restrict__ be,
    float* __restrict__ out)
{
    const int lane = threadIdx.x & 63;
    const int node = blockIdx.x * 4 + (threadIdx.x >> 6);   // grid exact: < NN

    const int h  = lane & 7;    // head owned by this lane
    const int es = lane >> 3;   // edge slot 0..7

    // ---- hoist: fold Q, We, be, 1/sqrt(8) into per-d score coefficients ----
    float wq[8], bq[8];
    {
        const float4* qp = (const float4*)&Q[(size_t)node * D64 + h * 8];
        float4 q0 = qp[0], q1 = qp[1];
        const float4* wp = (const float4*)&We[h * 8];
        float4 w0 = wp[0], w1 = wp[1];
        const float4* bp = (const float4*)&be[h * 8];
        float4 b0 = bp[0], b1 = bp[1];
        const float rs = 0.35355339059327373f;
        float qs[8] = { q0.x, q0.y, q0.z, q0.w, q1.x, q1.y, q1.z, q1.w };
        float ws[8] = { w0.x, w0.y, w0.z, w0.w, w1.x, w1.y, w1.z, w1.w };
        float bs[8] = { b0.x, b0.y, b0.z, b0.w, b1.x, b1.y, b1.z, b1.w };
#pragma unroll
        for (int d = 0; d < 8; ++d) {
            float qr = qs[d] * rs;
            wq[d] = ws[d] * qr;
            bq[d] = bs[d] * qr;
        }
    }

    const int i0 = off[node];
    const int i1 = off[node + 1];

    float acc[8];
#pragma unroll
    for (int d = 0; d < 8; ++d) acc[d] = 0.f;
    float z = 0.f;

    int i = i0;
    // ---- full steps: no predication anywhere ----
#pragma unroll 2
    for (; i + 8 <= i1; i += 8) {
        int2 rec = epack[i + es];
        unsigned int bo = ((unsigned int)rec.x << 6) + (h << 3);
        float attr = __int_as_float(rec.y);

        uint4 wA = *(const uint4*)(KVb + bo);
        uint4 wB = *(const uint4*)(KVb + bo + 4);
        unsigned int wv[8] = { wA.x, wA.y, wA.z, wA.w, wB.x, wB.y, wB.z, wB.w };

        float tt = 0.f;
#pragma unroll
        for (int d = 0; d < 8; ++d) {
            float s  = fmaf(attr, wq[d], bq[d]);
            float kf = __uint_as_float(wv[d] & 0xFFFF0000u);
            tt = fmaf(kf, s, tt);
        }
        tt = fminf(fmaxf(tt, -5.f), 5.f);
        float sc = __expf(tt);

#pragma unroll
        for (int d = 0; d < 8; ++d) {
            float vf = __uint_as_float(wv[d] << 16);
            acc[d] = fmaf(vf, sc, acc[d]);
        }
        z += sc;
    }

    // ---- tail: one predicated step covers remaining 0..7 edges ----
    if (i < i1) {
        int  idx   = i + es;
        bool valid = idx < i1;
        int2 rec   = epack[valid ? idx : i0];
        unsigned int bo = ((unsigned int)rec.x << 6) + (h << 3);
        float attr = __int_as_float(rec.y);

        uint4 wA = *(const uint4*)(KVb + bo);
        uint4 wB = *(const uint4*)(KVb + bo + 4);
        unsigned int wv[8] = { wA.x, wA.y, wA.z, wA.w, wB.x, wB.y, wB.z, wB.w };

        float tt = 0.f;
#pragma unroll
        for (int d = 0; d < 8; ++d) {
            float s  = fmaf(attr, wq[d], bq[d]);
            float kf = __uint_as_float(wv[d] & 0xFFFF0000u);
            tt = fmaf(kf, s, tt);
        }
        tt = fminf(fmaxf(tt, -5.f), 5.f);
        float sc = __expf(tt);
        sc = valid ? sc : 0.f;

#pragma unroll
        for (int d = 0; d < 8; ++d) {
            float vf = __uint_as_float(wv[d] << 16);
            acc[d] = fmaf(vf, sc, acc[d]);
        }
        z += sc;
    }

    // ---- butterfly reduce across edge slots (lane bits 3..5) ----
#pragma unroll
    for (int m = 8; m <= 32; m <<= 1) {
#pragma unroll
        for (int d = 0; d < 8; ++d) acc[d] += __shfl_xor(acc[d], m);
        z += __shfl_xor(z, m);
    }

    // ---- lane writes out[node][h*8 + es] = acc[es] / (z + eps) ----
    float val = acc[0];
#pragma unroll
    for (int j = 1; j < 8; ++j)
        val = (es == j) ? acc[j] : val;

    out[(size_t)node * D64 + h * 8 + es] = val / (z + 1e-6f);
}

// ---------------------------------------------------------------------------
// Host launcher
// ---------------------------------------------------------------------------
static inline size_t align256(size_t v) { return (v + 255) & ~(size_t)255; }

extern "C" void kernel_launch(void* const* d_in, const int* in_sizes, int n_in,
                              void* d_out, int out_size, void* d_ws, size_t ws_size,
                              hipStream_t stream)
{
    const float* x  = (const float*)d_in[0];
    const float* ea = (const float*)d_in[1];
    const int*   ei = (const int*)  d_in[2];   // [2][EE]: row0=src, row1=dst
    const float* Wq = (const float*)d_in[3];
    const float* bq = (const float*)d_in[4];
    const float* Wk = (const float*)d_in[5];
    const float* bk = (const float*)d_in[6];
    const float* We = (const float*)d_in[7];
    const float* be = (const float*)d_in[8];
    const float* Wv = (const float*)d_in[9];
    const float* bv = (const float*)d_in[10];
    float* out = (float*)d_out;

    char* ws = (char*)d_ws;
    size_t o = 0;
    float*          Q       = (float*)(ws + o);          o += align256((size_t)NN * D64 * 4);
    unsigned int*   KVb     = (unsigned int*)(ws + o);   o += align256((size_t)NN * D64 * 4);
    int*            off     = (int*)(ws + o);            o += align256((size_t)(NN + 1) * 4);
    unsigned short* wt_hi   = (unsigned short*)(ws + o); o += align256((size_t)192 * 128 * 2);
    unsigned short* wt_lo   = (unsigned short*)(ws + o); o += align256((size_t)192 * 128 * 2);
    int*            hist    = (int*)(ws + o);            o += align256((size_t)NB_P1 * NBUCK * 4);
    int*            btot    = (int*)(ws + o);            o += align256((size_t)NBUCK * 4);
    int*            bbase   = (int*)(ws + o);            o += align256((size_t)(NBUCK + 1) * 4);
    int2*           staging = (int2*)(ws + o);           o += align256((size_t)EE * 8);
    int2*           epack   = (int2*)(ws + o);           o += align256((size_t)EE * 8);
    (void)ws_size; (void)out_size; (void)in_sizes; (void)n_in;

    fusedA_kernel<<<WT_BLOCKS + NB_P1, 256, 0, stream>>>(Wq, Wk, Wv, wt_hi, wt_lo, ei, hist);
    hscanA_kernel<<<NBUCK, 256, 0, stream>>>(hist, btot);
    bscan_kernel<<<1, 256, 0, stream>>>(btot, bbase);
    fusedB_kernel<<<QKV_BLOCKS + NB_P1, 256, 0, stream>>>(x, wt_hi, wt_lo, bq, bk, bv,
                                                          Q, KVb, ei, ea, hist, bbase, staging);
    p2_kernel<<<NBUCK, 256, 0, stream>>>(staging, bbase, off, epack);
    attn_kernel<<<NN / 4, 256, 0, stream>>>(Q, KVb, off, epack, We, be, out);
}